// Round 16
// baseline (3843.396 us; speedup 1.0000x reference)
//
#include <hip/hip_runtime.h>
#include <math.h>

constexpr int B = 24, HH = 8;
constexpr int NN = 256, MQ = 64;
constexpr int EC = 364;

#define PI_2 1.5707963267948966f

// stats partials layout: parts[row][4][2], row = b*64+d
__device__ __forceinline__ void combine_stats(const float* __restrict__ parts,
                                              int row, int NT, float Lf,
                                              float& mu, float& inv) {
  float s = 0.f, q = 0.f;
  for (int t = 0; t < NT; ++t) {
    s += parts[((size_t)row * 4 + t) * 2];
    q += parts[((size_t)row * 4 + t) * 2 + 1];
  }
  mu = s / Lf;
  float var = (q - s * mu) / (Lf - 1.f);
  if (var < 0.f) var = 0.f;
  inv = 1.f / (sqrtf(var) + 1e-6f);
}

// ---------------- positional encoding table: tab[d*256+l] ----------------
__global__ void k_postab(float* __restrict__ tab) {
  int d = blockIdx.x, l = threadIdx.x;
  float fr = ((d & 1) == 0) ? powf(10000.f, -(float)d / 64.f)
                            : -powf(10000.f, -(float)(d - 1) / 64.f);
  float ph = (d & 1) ? PI_2 : 0.f;
  tab[d * 256 + l] = sinf(sinf((float)l * fr + ph));
}

// ---- merged one-time weight transposes -----------------------------------
// segments: pwT[12800] | e1pwT[23296] | hlwT[8192] | hgwT[8192] | dwT[5000]
__global__ void k_wT(const float* __restrict__ e2pw, const float* __restrict__ e1pw,
                     const float* __restrict__ hlw, const float* __restrict__ hgw,
                     const float* __restrict__ e2dw,
                     float* __restrict__ pwT, float* __restrict__ e1pwT,
                     float* __restrict__ hlwT, float* __restrict__ hgwT,
                     float* __restrict__ dwT) {
  int i = blockIdx.x * 256 + threadIdx.x;
  if (i < 12800) {
    int ce = i >> 6, o = i & 63;
    pwT[i] = e2pw[o * 200 + ce];
    return;
  }
  i -= 12800;
  if (i < 23296) {
    int c = i >> 6, o = i & 63;
    e1pwT[i] = e1pw[o * EC + c];
    return;
  }
  i -= 23296;
  if (i < 8192) {
    int layer = i >> 12, rem = i & 4095;
    int d = rem >> 6, o = rem & 63;
    hlwT[i] = hlw[layer * 4096 + o * 64 + d];
    return;
  }
  i -= 8192;
  if (i < 8192) {
    int layer = i >> 12, rem = i & 4095;
    int d = rem >> 6, o = rem & 63;
    hgwT[i] = hgw[layer * 4096 + o * 64 + d];
    return;
  }
  i -= 8192;
  if (i < 5000) {
    int t = i / 200, ce = i % 200;
    dwT[i] = e2dw[ce * 25 + t];
  }
}

// ---- X = (COPY? src : X) + tab ; emit per-tile row stats -----------------
template<bool COPY>
__global__ void k_posadd_stats(float* __restrict__ X, const float* __restrict__ src,
                               const float* __restrict__ tab, float* __restrict__ parts,
                               int L) {
  int row = blockIdx.x * 4 + (threadIdx.x >> 6);
  int lane = threadIdx.x & 63;
  int d = row & 63;
  float* xr = X + (size_t)row * L;
  const float* sr = COPY ? (src + (size_t)row * L) : xr;
  int NT = L >> 6;
  for (int t = 0; t < NT; ++t) {
    int l = t * 64 + lane;
    float v = sr[l] + tab[d * 256 + l];
    xr[l] = v;
    float s = v, q = v * v;
#pragma unroll
    for (int o = 32; o > 0; o >>= 1) { s += __shfl_xor(s, o); q += __shfl_xor(q, o); }
    if (lane == 0) {
      parts[((size_t)row * 4 + t) * 2] = s;
      parts[((size_t)row * 4 + t) * 2 + 1] = q;
    }
  }
}

// ---- fused: normalize -> dwconv(K) -> pw matmul -> relu -> +res -> X -----
template<int K>
__global__ __launch_bounds__(256) void k_fconv(
    float* __restrict__ X, const float* __restrict__ dw, const float* __restrict__ pw,
    const float* __restrict__ partsIn, float* __restrict__ partsOut, int L) {
  constexpr int H = K / 2, SW = 64 + 2 * H;
  __shared__ float smu[64], sinv[64];
  __shared__ float sN[64 * SW];
  __shared__ float sD[64 * 65];
  __shared__ __align__(16) float sWt[4096];
  int b = blockIdx.x, lt = blockIdx.y * 64;
  int tid = threadIdx.x;
  int NT = L >> 6;
  if (tid < 64) combine_stats(partsIn, b * 64 + tid, NT, (float)L, smu[tid], sinv[tid]);
  for (int i = tid; i < 1024; i += 256)
    ((float4*)sWt)[i] = ((const float4*)pw)[i];
  __syncthreads();
  float* Xb = X + (size_t)b * 64 * L;
  for (int i = tid; i < 64 * SW; i += 256) {
    int c = i / SW, jj = i % SW;
    int gl = lt + jj - H;
    sN[i] = (gl >= 0 && gl < L) ? (Xb[(size_t)c * L + gl] - smu[c]) * sinv[c] : 0.f;
  }
  __syncthreads();
  for (int i = tid; i < 4096; i += 256) {
    int c = i >> 6, l = i & 63;
    float acc = 0.f;
#pragma unroll
    for (int k = 0; k < K; ++k) acc += sN[c * SW + l + k] * dw[c * K + k];
    sD[c * 65 + l] = acc;
  }
  __syncthreads();
  int l = tid & 63, og = tid >> 6;
  float acc[16];
#pragma unroll
  for (int j = 0; j < 16; ++j) acc[j] = 0.f;
  for (int c = 0; c < 64; ++c) {
    float av = sD[c * 65 + l];
#pragma unroll
    for (int j = 0; j < 16; ++j) acc[j] += sWt[(og * 16 + j) * 64 + c] * av;
  }
  __syncthreads();
#pragma unroll
  for (int j = 0; j < 16; ++j) {
    int o = og * 16 + j;
    float v = Xb[(size_t)o * L + lt + l] + fmaxf(acc[j], 0.f);
    Xb[(size_t)o * L + lt + l] = v;
    sD[o * 65 + l] = v;
  }
  __syncthreads();
  if (tid < 64) {
    int o = tid;
    float s = 0.f, q = 0.f;
    for (int l2 = 0; l2 < 64; ++l2) { float v = sD[o * 65 + l2]; s += v; q += v * v; }
    partsOut[((size_t)(b * 64 + o) * 4 + blockIdx.y) * 2] = s;
    partsOut[((size_t)(b * 64 + o) * 4 + blockIdx.y) * 2 + 1] = q;
  }
}

// ---- generic 64x64 matmul: out = res + act(W . (norm?)A) [+tab] ; stats --
template<bool NORM, bool RELU, bool STATS, bool ADDTAB>
__global__ __launch_bounds__(256) void k_matmul2(
    const float* __restrict__ A, const float* __restrict__ W,
    const float* __restrict__ res, float* __restrict__ out,
    const float* __restrict__ partsIn, float* __restrict__ partsOut,
    const float* __restrict__ tab, int L) {
  __shared__ float sA[64 * 65];
  __shared__ __align__(16) float sW[4096];
  __shared__ float smu[64], sinv[64];
  int b = blockIdx.x, lt = blockIdx.y * 64;
  int tid = threadIdx.x;
  int NT = L >> 6;
  if (NORM && tid < 64) combine_stats(partsIn, b * 64 + tid, NT, (float)L, smu[tid], sinv[tid]);
  const float* Wb = W + (size_t)b * 4096;
  for (int i = tid; i < 1024; i += 256)
    ((float4*)sW)[i] = ((const float4*)Wb)[i];
  if (NORM) __syncthreads();
  const float* Ab = A + (size_t)b * 64 * L;
  for (int i = tid; i < 1024; i += 256) {
    int c = i >> 4, lq = (i & 15) * 4;
    float4 v = *(const float4*)(Ab + (size_t)c * L + lt + lq);
    if (NORM) {
      float mu = smu[c], iv = sinv[c];
      v.x = (v.x - mu) * iv; v.y = (v.y - mu) * iv;
      v.z = (v.z - mu) * iv; v.w = (v.w - mu) * iv;
    }
    sA[c * 65 + lq] = v.x; sA[c * 65 + lq + 1] = v.y;
    sA[c * 65 + lq + 2] = v.z; sA[c * 65 + lq + 3] = v.w;
  }
  __syncthreads();
  int l = tid & 63, og = tid >> 6;
  float acc[16];
#pragma unroll
  for (int j = 0; j < 16; ++j) acc[j] = 0.f;
  for (int c = 0; c < 64; ++c) {
    float av = sA[c * 65 + l];
#pragma unroll
    for (int j = 0; j < 16; ++j) acc[j] += sW[(og * 16 + j) * 64 + c] * av;
  }
  if (STATS) __syncthreads();
#pragma unroll
  for (int j = 0; j < 16; ++j) {
    int o = og * 16 + j;
    float v = acc[j];
    if (RELU) v = fmaxf(v, 0.f);
    size_t idx = ((size_t)b * 64 + o) * L + lt + l;
    v += res[idx];
    if (ADDTAB) v += tab[o * 256 + lt + l];
    out[idx] = v;
    if (STATS) sA[o * 65 + l] = v;
  }
  if (STATS) {
    __syncthreads();
    if (tid < 64) {
      int o = tid;
      float s = 0.f, q = 0.f;
      for (int l2 = 0; l2 < 64; ++l2) { float v = sA[o * 65 + l2]; s += v; q += v * v; }
      partsOut[((size_t)(b * 64 + o) * 4 + blockIdx.y) * 2] = s;
      partsOut[((size_t)(b * 64 + o) * 4 + blockIdx.y) * 2 + 1] = q;
    }
  }
}

// ---- fused resize: M0[b,o,l] = sum_c pw[o,c] * dw5(Xcat)[b,c,l] ----------
__global__ __launch_bounds__(256) void k_resize(
    const float* __restrict__ Xcat, const float* __restrict__ dw,
    const float* __restrict__ pw, float* __restrict__ out) {
  __shared__ float sA[64 * 64];
  int b = blockIdx.x, lt = blockIdx.y * 64;
  int l = threadIdx.x & 63, og = threadIdx.x >> 6;
  float acc[16];
#pragma unroll
  for (int j = 0; j < 16; ++j) acc[j] = 0.f;
  for (int c0 = 0; c0 < 256; c0 += 64) {
    __syncthreads();
    for (int i = threadIdx.x; i < 4096; i += 256) {
      int c = (i >> 6) + c0, ll = (i & 63) + lt;
      const float* xr = Xcat + ((size_t)b * 256 + c) * 256;
      float a = 0.f;
#pragma unroll
      for (int k = 0; k < 5; ++k) {
        int p = ll + k - 2;
        if (p >= 0 && p < 256) a += xr[p] * dw[c * 5 + k];
      }
      sA[i] = a;
    }
    __syncthreads();
    for (int c = 0; c < 64; ++c) {
      float av = sA[c * 64 + l];
#pragma unroll
      for (int j = 0; j < 16; ++j)
        acc[j] += pw[(size_t)(og * 16 + j) * 256 + c0 + c] * av;
    }
  }
#pragma unroll
  for (int j = 0; j < 16; ++j)
    out[((size_t)b * 64 + og * 16 + j) * 256 + lt + l] = acc[j];
}

// ---- self-attention with inline norm, online softmax ---------------------
__global__ __launch_bounds__(256) void k_att(
    const float* __restrict__ X, const float* __restrict__ partsIn,
    const float* __restrict__ wq, const float* __restrict__ wk,
    const float* __restrict__ wv, float* __restrict__ hc, int L) {
  int h = blockIdx.x, b = blockIdx.y;
  __shared__ float smu[64], sinv[64];
  __shared__ float sX[64 * 65];
  __shared__ float sQ[8 * 256], sK8[8 * 256], sV[8 * 256];
  __shared__ float swq[512], swk[512], swv[512];
  int tid = threadIdx.x;
  int NT = L >> 6;
  if (tid < 64) combine_stats(partsIn, b * 64 + tid, NT, (float)L, smu[tid], sinv[tid]);
  size_t woff = (size_t)(h * B + b) * 512;
  for (int i = tid; i < 512; i += 256) {
    swq[i] = wq[woff + i]; swk[i] = wk[woff + i]; swv[i] = wv[woff + i];
  }
  __syncthreads();
  const float* Xb = X + (size_t)b * 64 * L;
  for (int lt = 0; lt < L; lt += 64) {
    for (int i = tid; i < 4096; i += 256) {
      int d = i >> 6, l = i & 63;
      sX[d * 65 + l] = (Xb[(size_t)d * L + lt + l] - smu[d]) * sinv[d];
    }
    __syncthreads();
    for (int i = tid; i < 512; i += 256) {
      int k = i >> 6, l = i & 63;
      float aq = 0.f, ak = 0.f, av = 0.f;
      for (int d = 0; d < 64; ++d) {
        float x = sX[d * 65 + l];
        aq += swq[k * 64 + d] * x;
        ak += swk[k * 64 + d] * x;
        av += swv[k * 64 + d] * x;
      }
      sQ[k * L + lt + l] = aq; sK8[k * L + lt + l] = ak; sV[k * L + lt + l] = av;
    }
    __syncthreads();
  }
  const float scale = 0.35355339059327373f;  // 1/sqrt(8)
  for (int m = tid; m < L; m += 256) {
    float kc[8];
#pragma unroll
    for (int k = 0; k < 8; ++k) kc[k] = sK8[k * L + m];
    float mx = -1e30f, sum = 0.f, acc[8];
#pragma unroll
    for (int v = 0; v < 8; ++v) acc[v] = 0.f;
    for (int l = 0; l < L; ++l) {
      float s = 0.f;
#pragma unroll
      for (int k = 0; k < 8; ++k) s += sQ[k * L + l] * kc[k];
      s *= scale;
      if (s <= mx) {
        float p = __expf(s - mx);
        sum += p;
#pragma unroll
        for (int v = 0; v < 8; ++v) acc[v] += p * sV[v * L + l];
      } else {
        float corr = __expf(mx - s);
        sum = sum * corr + 1.f;
#pragma unroll
        for (int v = 0; v < 8; ++v) acc[v] = acc[v] * corr + sV[v * L + l];
        mx = s;
      }
    }
    float is = 1.f / sum;
    for (int v = 0; v < 8; ++v)
      hc[((size_t)b * 64 + h * 8 + v) * L + m] = acc[v] * is;
  }
}

// ---- merged C+Q char embed: kn-staged LDS tiles (5x fewer gathers) -------
__global__ __launch_bounds__(256) void k_charembed(
    const int* __restrict__ cidC, const int* __restrict__ cidQ,
    const float* __restrict__ ctab, const float* __restrict__ dwT,
    const float* __restrict__ db, const float* __restrict__ pwT,
    const float* __restrict__ pb,
    float* __restrict__ outC, float* __restrict__ outQ) {
  int nx = blockIdx.x, b = blockIdx.y;
  const int* cid; float* out; int Ln, n;
  if (nx < NN) { cid = cidC; out = outC; Ln = NN; n = nx; }
  else         { cid = cidQ; out = outQ; Ln = MQ; n = nx - NN; }
  __shared__ float dwo[16 * 200];   // [cn][ce] accumulator
  __shared__ float tile[16 * 200];  // staged embeddings for one kn position
  __shared__ int sid[5][16];
  __shared__ float red[256];
  int tid = threadIdx.x;
  if (tid < 80) {
    int kn = tid / 16, cn = tid % 16;
    int nn = n + kn - 2;
    sid[kn][cn] = (nn >= 0 && nn < Ln) ? cid[((size_t)b * Ln + nn) * 16 + cn] : -1;
  }
  for (int i = tid; i < 3200; i += 256) dwo[i] = db[i % 200];
  __syncthreads();
  for (int kn = 0; kn < 5; ++kn) {
    for (int i = tid; i < 3200; i += 256) {
      int cn = i / 200, ce = i % 200;
      int id = sid[kn][cn];
      tile[i] = (id >= 0) ? ctab[(size_t)id * 200 + ce] : 0.f;
    }
    __syncthreads();
    for (int i = tid; i < 3200; i += 256) {
      int cn = i / 200, ce = i % 200;
      float acc = dwo[i];
#pragma unroll
      for (int kc = 0; kc < 5; ++kc) {
        int cc = cn + kc - 2;
        float tv = (cc >= 0 && cc < 16) ? tile[cc * 200 + ce] : 0.f;
        acc += tv * dwT[(kn * 5 + kc) * 200 + ce];
      }
      dwo[i] = acc;
    }
    __syncthreads();
  }
  int o = tid & 63, q = tid >> 6;
  float mx = -1e30f;
  for (int cn = q; cn < 16; cn += 4) {
    float acc = pb[o];
    const float* dr = dwo + cn * 200;
    for (int c0 = 0; c0 < 200; c0 += 8) {
      float w8[8];
#pragma unroll
      for (int j = 0; j < 8; ++j) w8[j] = pwT[(c0 + j) * 64 + o];
#pragma unroll
      for (int j = 0; j < 8; ++j) acc += w8[j] * dr[c0 + j];
    }
    mx = fmaxf(mx, acc);
  }
  red[tid] = mx;
  __syncthreads();
  if (q == 0) {
    mx = fmaxf(fmaxf(red[o], red[64 + o]), fmaxf(red[128 + o], red[192 + o]));
    out[((size_t)b * 64 + o) * Ln + n] = fmaxf(mx, 0.f);
  }
}

// ---- merged C+Q emb conv -------------------------------------------------
__global__ void k_embconv(const float* __restrict__ chxC, const float* __restrict__ chxQ,
                          const int* __restrict__ widC, const int* __restrict__ widQ,
                          const float* __restrict__ wtab, const float* __restrict__ dw,
                          const float* __restrict__ db, const float* __restrict__ pwT,
                          const float* __restrict__ pb,
                          float* __restrict__ outC, float* __restrict__ outQ) {
  int nx = blockIdx.x, b = blockIdx.y;
  const float* chx; const int* wid; float* out; int Ln, n;
  if (nx < NN) { chx = chxC; wid = widC; out = outC; Ln = NN; n = nx; }
  else         { chx = chxQ; wid = widQ; out = outQ; Ln = MQ; n = nx - NN; }
  __shared__ float dwc[EC];
  __shared__ int sw[5];
  int tid = threadIdx.x;
  if (tid < 5) {
    int nn = n + tid - 2;
    sw[tid] = (nn >= 0 && nn < Ln) ? wid[(size_t)b * Ln + nn] : -1;
  }
  __syncthreads();
  for (int ch = tid; ch < EC; ch += 64) {
    float r[5];
#pragma unroll
    for (int k = 0; k < 5; ++k) {
      int nn = n + k - 2;
      float v = 0.f;
      if (nn >= 0 && nn < Ln) {
        if (ch < 64) v = chx[((size_t)b * 64 + ch) * Ln + nn];
        else v = wtab[(size_t)sw[k] * 300 + (ch - 64)];
      }
      r[k] = v;
    }
    float acc = db[ch];
#pragma unroll
    for (int k = 0; k < 5; ++k) acc += r[k] * dw[ch * 5 + k];
    dwc[ch] = acc;
  }
  __syncthreads();
  int o = tid;
  float acc = pb[o];
  for (int c0 = 0; c0 < EC; c0 += 4) {
    float w4[4];
#pragma unroll
    for (int j = 0; j < 4; ++j) w4[j] = pwT[(c0 + j) * 64 + o];
#pragma unroll
    for (int j = 0; j < 4; ++j) acc += w4[j] * dwc[c0 + j];
  }
  out[((size_t)b * 64 + o) * Ln + n] = acc;
}

// ---------------- merged C+Q highway --------------------------------------
__global__ void k_highway(const float* __restrict__ inxC, const float* __restrict__ inxQ,
                          const float* __restrict__ lwT, const float* __restrict__ lb,
                          const float* __restrict__ gwT, const float* __restrict__ gb,
                          float* __restrict__ outC, float* __restrict__ outQ) {
  int nx = blockIdx.x, b = blockIdx.y;
  const float* inx; float* out; int Ln, n;
  if (nx < NN) { inx = inxC; out = outC; Ln = NN; n = nx; }
  else         { inx = inxQ; out = outQ; Ln = MQ; n = nx - NN; }
  __shared__ float x[64], xn[64];
  int o = threadIdx.x;
  x[o] = inx[((size_t)b * 64 + o) * Ln + n];
  __syncthreads();
  for (int layer = 0; layer < 2; ++layer) {
    const float* lwr = lwT + layer * 4096;
    const float* gwr = gwT + layer * 4096;
    float gl = gb[layer * 64 + o], nl = lb[layer * 64 + o];
    for (int d0 = 0; d0 < 64; d0 += 8) {
      float g8[8], l8[8];
#pragma unroll
      for (int j = 0; j < 8; ++j) { g8[j] = gwr[(d0 + j) * 64 + o]; l8[j] = lwr[(d0 + j) * 64 + o]; }
#pragma unroll
      for (int j = 0; j < 8; ++j) { gl += g8[j] * x[d0 + j]; nl += l8[j] * x[d0 + j]; }
    }
    float g = 1.f / (1.f + __expf(-gl));
    float r = fmaxf(nl, 0.f);
    xn[o] = g * r + (1.f - g) * x[o];
    __syncthreads();
    x[o] = xn[o];
    __syncthreads();
  }
  out[((size_t)b * 64 + o) * Ln + n] = x[o];
}

// ---------------- context-query attention ---------------------------------
__global__ __launch_bounds__(256) void k_cqS(const float* __restrict__ C,
                                             const float* __restrict__ Q,
                                             const float* __restrict__ w,
                                             float* __restrict__ S,
                                             float* __restrict__ rmax,
                                             float* __restrict__ rsum) {
  int b = blockIdx.x, nt = blockIdx.y * 64;
  __shared__ float sQ[4096], sC[4096], ct[64], qt[64], swb[192];
  const float* Cb = C + (size_t)b * 64 * 256;
  const float* Qb = Q + (size_t)b * 4096;
  const float* wb = w + (size_t)b * 192;
  if (threadIdx.x < 192) swb[threadIdx.x] = wb[threadIdx.x];
  for (int i = threadIdx.x; i < 4096; i += 256) {
    int d = i >> 6, m = i & 63;
    sQ[i] = Qb[d * 64 + m];
    sC[i] = Cb[d * 256 + nt + m];
  }
  __syncthreads();
  if (threadIdx.x < 64) {
    int j = threadIdx.x;
    float a = 0.f, c2 = 0.f;
    for (int d = 0; d < 64; ++d) {
      a += swb[64 + d] * sC[d * 64 + j];
      c2 += swb[d] * sQ[d * 64 + j];
    }
    ct[j] = a; qt[j] = c2;
  }
  __syncthreads();
  int m = threadIdx.x & 63, wv = threadIdx.x >> 6;
  for (int it = 0; it < 16; ++it) {
    int nl = wv + it * 4;
    float acc = ct[nl] + qt[m];
    for (int d = 0; d < 64; ++d)
      acc += sC[d * 64 + nl] * swb[128 + d] * sQ[d * 64 + m];
    S[((size_t)b * 256 + nt + nl) * 64 + m] = acc;
    float mx = acc;
#pragma unroll
    for (int o = 32; o > 0; o >>= 1) mx = fmaxf(mx, __shfl_xor(mx, o));
    float p = __expf(acc - mx);
#pragma unroll
    for (int o = 32; o > 0; o >>= 1) p += __shfl_xor(p, o);
    if (m == 0) { rmax[b * 256 + nt + nl] = mx; rsum[b * 256 + nt + nl] = p; }
  }
}

__global__ void k_cqcol(const float* __restrict__ S, float* __restrict__ cmax,
                        float* __restrict__ csum) {
  int b = blockIdx.x, m = threadIdx.x;
  const float* Sb = S + (size_t)b * 256 * 64;
  float mx = -1e30f;
  for (int n = 0; n < 256; ++n) mx = fmaxf(mx, Sb[n * 64 + m]);
  float s = 0.f;
  for (int n = 0; n < 256; ++n) s += __expf(Sb[n * 64 + m] - mx);
  cmax[b * 64 + m] = mx; csum[b * 64 + m] = s;
}

__global__ __launch_bounds__(256) void k_cqA(
    const float* __restrict__ C, const float* __restrict__ Q,
    const float* __restrict__ S, const float* __restrict__ rmax,
    const float* __restrict__ rsum, float* __restrict__ Xcat) {
  int b = blockIdx.x, nt = blockIdx.y * 64;
  __shared__ float sQ[4096];
  __shared__ float sP[64 * 65];
  const float* Qb = Q + (size_t)b * 4096;
  for (int i = threadIdx.x; i < 4096; i += 256) sQ[i] = Qb[i];
  for (int i = threadIdx.x; i < 4096; i += 256) {
    int nl = i >> 6, m = i & 63;
    int n = nt + nl;
    sP[nl * 65 + m] = __expf(S[((size_t)b * 256 + n) * 64 + m] - rmax[b * 256 + n]) / rsum[b * 256 + n];
  }
  __syncthreads();
  int nl = threadIdx.x & 63, dg = threadIdx.x >> 6;
  int n = nt + nl;
  for (int j = 0; j < 16; ++j) {
    int d = dg * 16 + j;
    float acc = 0.f;
    for (int m = 0; m < 64; ++m) acc += sQ[d * 64 + m] * sP[nl * 65 + m];
    float cv = C[((size_t)b * 64 + d) * 256 + n];
    Xcat[((size_t)b * 256 + d) * 256 + n] = cv;
    Xcat[((size_t)b * 256 + 64 + d) * 256 + n] = acc;
    Xcat[((size_t)b * 256 + 128 + d) * 256 + n] = cv * acc;
  }
}

// CS2[d,m] = sum_n C[d,n] * S2[n,m]
__global__ __launch_bounds__(256) void k_cqCS2(
    const float* __restrict__ C, const float* __restrict__ S,
    const float* __restrict__ cmax, const float* __restrict__ csum,
    float* __restrict__ CS2) {
  int b = blockIdx.x;
  __shared__ float sP[4096], sC[4096];
  int m = threadIdx.x & 63, dg = threadIdx.x >> 6;
  float acc[16];
#pragma unroll
  for (int j = 0; j < 16; ++j) acc[j] = 0.f;
  for (int nt = 0; nt < 4; ++nt) {
    __syncthreads();
    for (int i = threadIdx.x; i < 4096; i += 256) {
      int nl = i >> 6, mm = i & 63;
      int n = nt * 64 + nl;
      sP[i] = __expf(S[((size_t)b * 256 + n) * 64 + mm] - cmax[b * 64 + mm]) / csum[b * 64 + mm];
      int d = i >> 6, nn = i & 63;
      sC[i] = C[((size_t)b * 64 + d) * 256 + nt * 64 + nn];
    }
    __syncthreads();
    for (int nl = 0; nl < 64; ++nl) {
      float p = sP[nl * 64 + m];
#pragma unroll
      for (int j = 0; j < 16; ++j) acc[j] += sC[(dg * 16 + j) * 64 + nl] * p;
    }
  }
  for (int j = 0; j < 16; ++j)
    CS2[((size_t)b * 64 + dg * 16 + j) * 64 + m] = acc[j];
}

// Bm[d,k] = sum_m CS2[d,m] * S1[k,m]
__global__ __launch_bounds__(256) void k_cqBm(
    const float* __restrict__ C, const float* __restrict__ CS2,
    const float* __restrict__ S, const float* __restrict__ rmax,
    const float* __restrict__ rsum, float* __restrict__ Xcat) {
  int b = blockIdx.x, kt = blockIdx.y * 64;
  __shared__ float sW[4096];
  __shared__ float sP[64 * 65];
  for (int i = threadIdx.x; i < 4096; i += 256) sW[i] = CS2[(size_t)b * 4096 + i];
  for (int i = threadIdx.x; i < 4096; i += 256) {
    int kl = i >> 6, m = i & 63;
    int k = kt + kl;
    sP[kl * 65 + m] = __expf(S[((size_t)b * 256 + k) * 64 + m] - rmax[b * 256 + k]) / rsum[b * 256 + k];
  }
  __syncthreads();
  int kl = threadIdx.x & 63, dg = threadIdx.x >> 6;
  int k = kt + kl;
  for (int j = 0; j < 16; ++j) {
    int d = dg * 16 + j;
    float acc = 0.f;
    for (int m = 0; m < 64; ++m) acc += sW[d * 64 + m] * sP[kl * 65 + m];
    float cv = C[((size_t)b * 64 + d) * 256 + k];
    Xcat[((size_t)b * 256 + 192 + d) * 256 + k] = cv * acc;
  }
}

// ---- both pointers in one launch: grid (B, 2) ----------------------------
__global__ void k_pointer2(const float* __restrict__ M0, const float* __restrict__ M1,
                           const float* __restrict__ M2, const float* __restrict__ w0,
                           const float* __restrict__ w1, float* __restrict__ out) {
  int b = blockIdx.x, sel = blockIdx.y, n = threadIdx.x;
  const float* wb = (sel ? w1 : w0) + b * 128;
  const float* Mb = sel ? M2 : M1;
  float y = 0.f;
  for (int d = 0; d < 64; ++d) {
    y += wb[d] * M0[((size_t)b * 64 + d) * 256 + n];
    y += wb[64 + d] * Mb[((size_t)b * 64 + d) * 256 + n];
  }
  __shared__ float wred[4], wsum[4];
  int lane = n & 63, wid = n >> 6;
  float mx = y;
#pragma unroll
  for (int o = 32; o > 0; o >>= 1) mx = fmaxf(mx, __shfl_xor(mx, o));
  if (lane == 0) wred[wid] = mx;
  __syncthreads();
  mx = fmaxf(fmaxf(wred[0], wred[1]), fmaxf(wred[2], wred[3]));
  float e = __expf(y - mx);
  float s = e;
#pragma unroll
  for (int o = 32; o > 0; o >>= 1) s += __shfl_xor(s, o);
  if (lane == 0) wsum[wid] = s;
  __syncthreads();
  s = wsum[0] + wsum[1] + wsum[2] + wsum[3];
  out[sel * 6144 + b * 256 + n] = e / s;
}

// ===========================================================================
extern "C" void kernel_launch(void* const* d_in, const int* in_sizes, int n_in,
                              void* d_out, int out_size, void* d_ws, size_t ws_size,
                              hipStream_t stream) {
  const float* word_table = (const float*)d_in[0];
  const float* char_table = (const float*)d_in[1];
  const float* e2dw = (const float*)d_in[2];
  const float* e2db = (const float*)d_in[3];
  const float* e2pw = (const float*)d_in[4];
  const float* e2pb = (const float*)d_in[5];
  const float* e1dw = (const float*)d_in[6];
  const float* e1db = (const float*)d_in[7];
  const float* e1pw = (const float*)d_in[8];
  const float* e1pb = (const float*)d_in[9];
  const float* hlw = (const float*)d_in[10];
  const float* hlb = (const float*)d_in[11];
  const float* hgw = (const float*)d_in[12];
  const float* hgb = (const float*)d_in[13];
  const float *enc_dw[5], *enc_pw[5], *enc_wq[5], *enc_wk[5], *enc_wv[5], *enc_wo[5], *enc_w[5];
  for (int p = 0; p < 5; ++p) {
    enc_dw[p] = (const float*)d_in[14 + 7 * p + 0];
    enc_pw[p] = (const float*)d_in[14 + 7 * p + 1];
    enc_wq[p] = (const float*)d_in[14 + 7 * p + 2];
    enc_wk[p] = (const float*)d_in[14 + 7 * p + 3];
    enc_wv[p] = (const float*)d_in[14 + 7 * p + 4];
    enc_wo[p] = (const float*)d_in[14 + 7 * p + 5];
    enc_w[p]  = (const float*)d_in[14 + 7 * p + 6];
  }
  const float* cq_w  = (const float*)d_in[49];
  const float* rs_dw = (const float*)d_in[50];
  const float* rs_pw = (const float*)d_in[51];
  const float* p_w0  = (const float*)d_in[52];
  const float* p_w1  = (const float*)d_in[53];
  const int* Cwid = (const int*)d_in[54];
  const int* Ccid = (const int*)d_in[55];
  const int* Qwid = (const int*)d_in[56];
  const int* Qcid = (const int*)d_in[57];
  float* out = (float*)d_out;

  // ---- workspace (floats), ~12.3 MB --------------------------------------
  float* ws = (float*)d_ws;
  float* postab = ws;                  // 16384
  float* U    = ws + 16384;            // 393216  (att head out)
  float* Xcat = ws + 409600;           // 1572864 ; M2 aliases; emb scratch
  float* CX   = ws + 1982464;          // 393216  ; M0 aliases
  float* Sb   = ws + 2375680;          // 393216  ; M1 aliases
  float* QX   = ws + 2768896;          // 98304
  float* CS2  = ws + 2867200;          // 98304
  float* rmax = ws + 2965504;          // 6144
  float* rsum = ws + 2971648;          // 6144
  float* cmax = ws + 2977792;          // 1536
  float* csum = ws + 2979328;          // 1536
  float* P0   = ws + 2980864;          // 12288
  float* P1   = ws + 2993152;          // 12288
  float* pwT  = ws + 3005440;          // 12800
  float* e1pwT= ws + 3018240;          // 23296
  float* hlwT = ws + 3041536;          // 8192
  float* hgwT = ws + 3049728;          // 8192
  float* dwT  = ws + 3057920;          // 5000 -> ends 3062920
  float* M0 = CX; float* M1 = Sb; float* M2 = Xcat;
  // embedding scratch inside Xcat (dead before cq writes Xcat):
  float* E1C = Xcat;              // 393216
  float* E1Q = Xcat + 393216;     // 98304
  float* E2C = Xcat + 491520;     // 393216
  float* E2Q = Xcat + 884736;     // 98304 -> 983040 < 1572864
  (void)out_size; (void)in_sizes; (void)n_in; (void)ws_size;

  auto run_enc = [&](float* X, const float* src, int L, int cnum, int K, int p, int reps) {
    int NB = B * 64 / 4;
    if (src)
      hipLaunchKernelGGL((k_posadd_stats<true>), dim3(NB), dim3(256), 0, stream, X, src, postab, P0, L);
    else
      hipLaunchKernelGGL((k_posadd_stats<false>), dim3(NB), dim3(256), 0, stream, X, (const float*)nullptr, postab, P0, L);
    for (int rep = 0; rep < reps; ++rep) {
      float* pin = P0; float* pout = P1;
      for (int i = 0; i < cnum; ++i) {
        if (K == 7)
          hipLaunchKernelGGL((k_fconv<7>), dim3(B, L / 64), dim3(256), 0, stream,
                             X, enc_dw[p] + i * 64 * 7, enc_pw[p] + (size_t)i * 4096, pin, pout, L);
        else
          hipLaunchKernelGGL((k_fconv<5>), dim3(B, L / 64), dim3(256), 0, stream,
                             X, enc_dw[p] + i * 64 * 5, enc_pw[p] + (size_t)i * 4096, pin, pout, L);
        float* t = pin; pin = pout; pout = t;
      }
      k_att<<<dim3(HH, B), 256, 0, stream>>>(X, pin, enc_wq[p], enc_wk[p], enc_wv[p], U, L);
      hipLaunchKernelGGL((k_matmul2<false, false, true, false>), dim3(B, L / 64), dim3(256), 0, stream,
                         U, enc_wo[p], (const float*)X, X, (const float*)nullptr, pout,
                         (const float*)nullptr, L);
      if (rep + 1 < reps)
        hipLaunchKernelGGL((k_matmul2<true, true, true, true>), dim3(B, L / 64), dim3(256), 0, stream,
                           X, enc_w[p], (const float*)X, X, pout, P0, (const float*)postab, L);
      else
        hipLaunchKernelGGL((k_matmul2<true, true, false, false>), dim3(B, L / 64), dim3(256), 0, stream,
                           X, enc_w[p], (const float*)X, X, pout, (float*)nullptr,
                           (const float*)nullptr, L);
    }
  };

  k_postab<<<64, 256, 0, stream>>>(postab);
  k_wT<<<225, 256, 0, stream>>>(e2pw, e1pw, hlw, hgw, e2dw, pwT, e1pwT, hlwT, hgwT, dwT);
  // ---- embeddings (C and Q merged per stage) ----
  k_charembed<<<dim3(NN + MQ, B), 256, 0, stream>>>(Ccid, Qcid, char_table, dwT, e2db, pwT, e2pb, E1C, E1Q);
  k_embconv<<<dim3(NN + MQ, B), 64, 0, stream>>>(E1C, E1Q, Cwid, Qwid, word_table, e1dw, e1db, e1pwT, e1pb, E2C, E2Q);
  k_highway<<<dim3(NN + MQ, B), 64, 0, stream>>>(E2C, E2Q, hlwT, hlb, hgwT, hgb, CX, QX);
  // ---- embedding encoders ----
  run_enc(CX, nullptr, 256, 4, 7, 0, 1);
  run_enc(QX, nullptr, 64, 4, 7, 1, 1);
  // ---- context-query attention ----
  k_cqS<<<dim3(B, 4), 256, 0, stream>>>(CX, QX, cq_w, Sb, rmax, rsum);
  k_cqcol<<<B, 64, 0, stream>>>(Sb, cmax, csum);
  k_cqA<<<dim3(B, 4), 256, 0, stream>>>(CX, QX, Sb, rmax, rsum, Xcat);
  k_cqCS2<<<B, 256, 0, stream>>>(CX, Sb, cmax, csum, CS2);
  k_cqBm<<<dim3(B, 4), 256, 0, stream>>>(CX, CS2, Sb, rmax, rsum, Xcat);
  // ---- resize -> M0 ----
  k_resize<<<dim3(B, 4), 256, 0, stream>>>(Xcat, rs_dw, rs_pw, M0);
  // ---- model encoders ----
  run_enc(M0, nullptr, 256, 2, 5, 2, 7);
  run_enc(M1, M0, 256, 2, 5, 3, 7);
  run_enc(M2, M1, 256, 2, 5, 4, 7);
  // ---- pointers ----
  k_pointer2<<<dim3(B, 2), 256, 0, stream>>>(M0, M1, M2, p_w0, p_w1, out);
}

// Round 17
// 3749.363 us; speedup vs baseline: 1.0251x; 1.0251x over previous
//
#include <hip/hip_runtime.h>
#include <math.h>

constexpr int B = 24, HH = 8;
constexpr int NN = 256, MQ = 64;
constexpr int EC = 364;

#define PI_2 1.5707963267948966f

// stats partials layout: parts[row][4][2], row = b*64+d
__device__ __forceinline__ void combine_stats(const float* __restrict__ parts,
                                              int row, int NT, float Lf,
                                              float& mu, float& inv) {
  float s = 0.f, q = 0.f;
  for (int t = 0; t < NT; ++t) {
    s += parts[((size_t)row * 4 + t) * 2];
    q += parts[((size_t)row * 4 + t) * 2 + 1];
  }
  mu = s / Lf;
  float var = (q - s * mu) / (Lf - 1.f);
  if (var < 0.f) var = 0.f;
  inv = 1.f / (sqrtf(var) + 1e-6f);
}

// ---------------- positional encoding table: tab[d*256+l] ----------------
__global__ void k_postab(float* __restrict__ tab) {
  int d = blockIdx.x, l = threadIdx.x;
  float fr = ((d & 1) == 0) ? powf(10000.f, -(float)d / 64.f)
                            : -powf(10000.f, -(float)(d - 1) / 64.f);
  float ph = (d & 1) ? PI_2 : 0.f;
  tab[d * 256 + l] = sinf(sinf((float)l * fr + ph));
}

// ---- merged one-time weight transposes -----------------------------------
__global__ void k_wT(const float* __restrict__ e2pw, const float* __restrict__ e1pw,
                     const float* __restrict__ hlw, const float* __restrict__ hgw,
                     const float* __restrict__ e2dw,
                     float* __restrict__ pwT, float* __restrict__ e1pwT,
                     float* __restrict__ hlwT, float* __restrict__ hgwT,
                     float* __restrict__ dwT) {
  int i = blockIdx.x * 256 + threadIdx.x;
  if (i < 12800) {
    int ce = i >> 6, o = i & 63;
    pwT[i] = e2pw[o * 200 + ce];
    return;
  }
  i -= 12800;
  if (i < 23296) {
    int c = i >> 6, o = i & 63;
    e1pwT[i] = e1pw[o * EC + c];
    return;
  }
  i -= 23296;
  if (i < 8192) {
    int layer = i >> 12, rem = i & 4095;
    int d = rem >> 6, o = rem & 63;
    hlwT[i] = hlw[layer * 4096 + o * 64 + d];
    return;
  }
  i -= 8192;
  if (i < 8192) {
    int layer = i >> 12, rem = i & 4095;
    int d = rem >> 6, o = rem & 63;
    hgwT[i] = hgw[layer * 4096 + o * 64 + d];
    return;
  }
  i -= 8192;
  if (i < 5000) {
    int t = i / 200, ce = i % 200;
    dwT[i] = e2dw[ce * 25 + t];
  }
}

// ---- X = (COPY? src : X) + tab ; emit per-tile row stats -----------------
template<bool COPY>
__global__ void k_posadd_stats(float* __restrict__ X, const float* __restrict__ src,
                               const float* __restrict__ tab, float* __restrict__ parts,
                               int L) {
  int row = blockIdx.x * 4 + (threadIdx.x >> 6);
  int lane = threadIdx.x & 63;
  int d = row & 63;
  float* xr = X + (size_t)row * L;
  const float* sr = COPY ? (src + (size_t)row * L) : xr;
  int NT = L >> 6;
  for (int t = 0; t < NT; ++t) {
    int l = t * 64 + lane;
    float v = sr[l] + tab[d * 256 + l];
    xr[l] = v;
    float s = v, q = v * v;
#pragma unroll
    for (int o = 32; o > 0; o >>= 1) { s += __shfl_xor(s, o); q += __shfl_xor(q, o); }
    if (lane == 0) {
      parts[((size_t)row * 4 + t) * 2] = s;
      parts[((size_t)row * 4 + t) * 2 + 1] = q;
    }
  }
}

// ---- fused: normalize -> dwconv(K) -> pw matmul -> relu -> +res -> X -----
template<int K>
__global__ __launch_bounds__(256) void k_fconv(
    float* __restrict__ X, const float* __restrict__ dw, const float* __restrict__ pw,
    const float* __restrict__ partsIn, float* __restrict__ partsOut, int L) {
  constexpr int H = K / 2, SW = 64 + 2 * H;
  __shared__ float smu[64], sinv[64];
  __shared__ float sN[64 * SW];
  __shared__ float sD[64 * 65];
  __shared__ __align__(16) float sWt[4096];
  int b = blockIdx.x, lt = blockIdx.y * 64;
  int tid = threadIdx.x;
  int NT = L >> 6;
  if (tid < 64) combine_stats(partsIn, b * 64 + tid, NT, (float)L, smu[tid], sinv[tid]);
  for (int i = tid; i < 1024; i += 256)
    ((float4*)sWt)[i] = ((const float4*)pw)[i];
  __syncthreads();
  float* Xb = X + (size_t)b * 64 * L;
  for (int i = tid; i < 64 * SW; i += 256) {
    int c = i / SW, jj = i % SW;
    int gl = lt + jj - H;
    sN[i] = (gl >= 0 && gl < L) ? (Xb[(size_t)c * L + gl] - smu[c]) * sinv[c] : 0.f;
  }
  __syncthreads();
  for (int i = tid; i < 4096; i += 256) {
    int c = i >> 6, l = i & 63;
    float acc = 0.f;
#pragma unroll
    for (int k = 0; k < K; ++k) acc += sN[c * SW + l + k] * dw[c * K + k];
    sD[c * 65 + l] = acc;
  }
  __syncthreads();
  int l = tid & 63, og = tid >> 6;
  float acc[16];
#pragma unroll
  for (int j = 0; j < 16; ++j) acc[j] = 0.f;
  for (int c = 0; c < 64; ++c) {
    float av = sD[c * 65 + l];
#pragma unroll
    for (int j = 0; j < 16; ++j) acc[j] += sWt[(og * 16 + j) * 64 + c] * av;
  }
  __syncthreads();
#pragma unroll
  for (int j = 0; j < 16; ++j) {
    int o = og * 16 + j;
    float v = Xb[(size_t)o * L + lt + l] + fmaxf(acc[j], 0.f);
    Xb[(size_t)o * L + lt + l] = v;
    sD[o * 65 + l] = v;
  }
  __syncthreads();
  if (tid < 64) {
    int o = tid;
    float s = 0.f, q = 0.f;
    for (int l2 = 0; l2 < 64; ++l2) { float v = sD[o * 65 + l2]; s += v; q += v * v; }
    partsOut[((size_t)(b * 64 + o) * 4 + blockIdx.y) * 2] = s;
    partsOut[((size_t)(b * 64 + o) * 4 + blockIdx.y) * 2 + 1] = q;
  }
}

// ---- generic 64x64 matmul: out = res + act(W . (norm?)A) [+tab] ; stats --
template<bool NORM, bool RELU, bool STATS, bool ADDTAB>
__global__ __launch_bounds__(256) void k_matmul2(
    const float* __restrict__ A, const float* __restrict__ W,
    const float* __restrict__ res, float* __restrict__ out,
    const float* __restrict__ partsIn, float* __restrict__ partsOut,
    const float* __restrict__ tab, int L) {
  __shared__ float sA[64 * 65];
  __shared__ __align__(16) float sW[4096];
  __shared__ float smu[64], sinv[64];
  int b = blockIdx.x, lt = blockIdx.y * 64;
  int tid = threadIdx.x;
  int NT = L >> 6;
  if (NORM && tid < 64) combine_stats(partsIn, b * 64 + tid, NT, (float)L, smu[tid], sinv[tid]);
  const float* Wb = W + (size_t)b * 4096;
  for (int i = tid; i < 1024; i += 256)
    ((float4*)sW)[i] = ((const float4*)Wb)[i];
  if (NORM) __syncthreads();
  const float* Ab = A + (size_t)b * 64 * L;
  for (int i = tid; i < 1024; i += 256) {
    int c = i >> 4, lq = (i & 15) * 4;
    float4 v = *(const float4*)(Ab + (size_t)c * L + lt + lq);
    if (NORM) {
      float mu = smu[c], iv = sinv[c];
      v.x = (v.x - mu) * iv; v.y = (v.y - mu) * iv;
      v.z = (v.z - mu) * iv; v.w = (v.w - mu) * iv;
    }
    sA[c * 65 + lq] = v.x; sA[c * 65 + lq + 1] = v.y;
    sA[c * 65 + lq + 2] = v.z; sA[c * 65 + lq + 3] = v.w;
  }
  __syncthreads();
  int l = tid & 63, og = tid >> 6;
  float acc[16];
#pragma unroll
  for (int j = 0; j < 16; ++j) acc[j] = 0.f;
  for (int c = 0; c < 64; ++c) {
    float av = sA[c * 65 + l];
#pragma unroll
    for (int j = 0; j < 16; ++j) acc[j] += sW[(og * 16 + j) * 64 + c] * av;
  }
  if (STATS) __syncthreads();
#pragma unroll
  for (int j = 0; j < 16; ++j) {
    int o = og * 16 + j;
    float v = acc[j];
    if (RELU) v = fmaxf(v, 0.f);
    size_t idx = ((size_t)b * 64 + o) * L + lt + l;
    v += res[idx];
    if (ADDTAB) v += tab[o * 256 + lt + l];
    out[idx] = v;
    if (STATS) sA[o * 65 + l] = v;
  }
  if (STATS) {
    __syncthreads();
    if (tid < 64) {
      int o = tid;
      float s = 0.f, q = 0.f;
      for (int l2 = 0; l2 < 64; ++l2) { float v = sA[o * 65 + l2]; s += v; q += v * v; }
      partsOut[((size_t)(b * 64 + o) * 4 + blockIdx.y) * 2] = s;
      partsOut[((size_t)(b * 64 + o) * 4 + blockIdx.y) * 2 + 1] = q;
    }
  }
}

// ---- fused resize: M0[b,o,l] = sum_c pw[o,c] * dw5(Xcat)[b,c,l] ----------
__global__ __launch_bounds__(256) void k_resize(
    const float* __restrict__ Xcat, const float* __restrict__ dw,
    const float* __restrict__ pw, float* __restrict__ out) {
  __shared__ float sA[64 * 64];
  int b = blockIdx.x, lt = blockIdx.y * 64;
  int l = threadIdx.x & 63, og = threadIdx.x >> 6;
  float acc[16];
#pragma unroll
  for (int j = 0; j < 16; ++j) acc[j] = 0.f;
  for (int c0 = 0; c0 < 256; c0 += 64) {
    __syncthreads();
    for (int i = threadIdx.x; i < 4096; i += 256) {
      int c = (i >> 6) + c0, ll = (i & 63) + lt;
      const float* xr = Xcat + ((size_t)b * 256 + c) * 256;
      float a = 0.f;
#pragma unroll
      for (int k = 0; k < 5; ++k) {
        int p = ll + k - 2;
        if (p >= 0 && p < 256) a += xr[p] * dw[c * 5 + k];
      }
      sA[i] = a;
    }
    __syncthreads();
    for (int c = 0; c < 64; ++c) {
      float av = sA[c * 64 + l];
#pragma unroll
      for (int j = 0; j < 16; ++j)
        acc[j] += pw[(size_t)(og * 16 + j) * 256 + c0 + c] * av;
    }
  }
#pragma unroll
  for (int j = 0; j < 16; ++j)
    out[((size_t)b * 64 + og * 16 + j) * 256 + lt + l] = acc[j];
}

// ---- self-attention with inline norm, online softmax ---------------------
__global__ __launch_bounds__(256) void k_att(
    const float* __restrict__ X, const float* __restrict__ partsIn,
    const float* __restrict__ wq, const float* __restrict__ wk,
    const float* __restrict__ wv, float* __restrict__ hc, int L) {
  int h = blockIdx.x, b = blockIdx.y;
  __shared__ float smu[64], sinv[64];
  __shared__ float sX[64 * 65];
  __shared__ float sQ[8 * 256], sK8[8 * 256], sV[8 * 256];
  __shared__ float swq[512], swk[512], swv[512];
  int tid = threadIdx.x;
  int NT = L >> 6;
  if (tid < 64) combine_stats(partsIn, b * 64 + tid, NT, (float)L, smu[tid], sinv[tid]);
  size_t woff = (size_t)(h * B + b) * 512;
  for (int i = tid; i < 512; i += 256) {
    swq[i] = wq[woff + i]; swk[i] = wk[woff + i]; swv[i] = wv[woff + i];
  }
  __syncthreads();
  const float* Xb = X + (size_t)b * 64 * L;
  for (int lt = 0; lt < L; lt += 64) {
    for (int i = tid; i < 4096; i += 256) {
      int d = i >> 6, l = i & 63;
      sX[d * 65 + l] = (Xb[(size_t)d * L + lt + l] - smu[d]) * sinv[d];
    }
    __syncthreads();
    for (int i = tid; i < 512; i += 256) {
      int k = i >> 6, l = i & 63;
      float aq = 0.f, ak = 0.f, av = 0.f;
      for (int d = 0; d < 64; ++d) {
        float x = sX[d * 65 + l];
        aq += swq[k * 64 + d] * x;
        ak += swk[k * 64 + d] * x;
        av += swv[k * 64 + d] * x;
      }
      sQ[k * L + lt + l] = aq; sK8[k * L + lt + l] = ak; sV[k * L + lt + l] = av;
    }
    __syncthreads();
  }
  const float scale = 0.35355339059327373f;  // 1/sqrt(8)
  for (int m = tid; m < L; m += 256) {
    float kc[8];
#pragma unroll
    for (int k = 0; k < 8; ++k) kc[k] = sK8[k * L + m];
    float mx = -1e30f, sum = 0.f, acc[8];
#pragma unroll
    for (int v = 0; v < 8; ++v) acc[v] = 0.f;
    for (int l = 0; l < L; ++l) {
      float s = 0.f;
#pragma unroll
      for (int k = 0; k < 8; ++k) s += sQ[k * L + l] * kc[k];
      s *= scale;
      if (s <= mx) {
        float p = __expf(s - mx);
        sum += p;
#pragma unroll
        for (int v = 0; v < 8; ++v) acc[v] += p * sV[v * L + l];
      } else {
        float corr = __expf(mx - s);
        sum = sum * corr + 1.f;
#pragma unroll
        for (int v = 0; v < 8; ++v) acc[v] = acc[v] * corr + sV[v * L + l];
        mx = s;
      }
    }
    float is = 1.f / sum;
    for (int v = 0; v < 8; ++v)
      hc[((size_t)b * 64 + h * 8 + v) * L + m] = acc[v] * is;
  }
}

// ---- merged C+Q char embed: register-staged taps (R15 body) --------------
__global__ __launch_bounds__(256) void k_charembed(
    const int* __restrict__ cidC, const int* __restrict__ cidQ,
    const float* __restrict__ ctab, const float* __restrict__ dwT,
    const float* __restrict__ db, const float* __restrict__ pwT,
    const float* __restrict__ pb,
    float* __restrict__ outC, float* __restrict__ outQ) {
  int nx = blockIdx.x, b = blockIdx.y;
  const int* cid; float* out; int Ln, n;
  if (nx < NN) { cid = cidC; out = outC; Ln = NN; n = nx; }
  else         { cid = cidQ; out = outQ; Ln = MQ; n = nx - NN; }
  __shared__ float dwo[16 * 200];   // [cn][ce]
  __shared__ int sid[5][16];
  __shared__ float red[256];
  int tid = threadIdx.x;
  if (tid < 80) {
    int kn = tid / 16, cn = tid % 16;
    int nn = n + kn - 2;
    sid[kn][cn] = (nn >= 0 && nn < Ln) ? cid[((size_t)b * Ln + nn) * 16 + cn] : -1;
  }
  __syncthreads();
  for (int i = tid; i < 16 * 200; i += 256) {
    int cn = i / 200, ce = i % 200;
    float r[25];
#pragma unroll
    for (int kn = 0; kn < 5; ++kn) {
#pragma unroll
      for (int kc = 0; kc < 5; ++kc) {
        int cc = cn + kc - 2;
        int id = (cc >= 0 && cc < 16) ? sid[kn][cc] : -1;
        r[kn * 5 + kc] = (id >= 0) ? ctab[(size_t)id * 200 + ce] : 0.f;
      }
    }
    float acc = db[ce];
#pragma unroll
    for (int t = 0; t < 25; ++t) acc += r[t] * dwT[t * 200 + ce];
    dwo[cn * 200 + ce] = acc;
  }
  __syncthreads();
  int o = tid & 63, q = tid >> 6;
  float mx = -1e30f;
  for (int cn = q; cn < 16; cn += 4) {
    float acc = pb[o];
    const float* dr = dwo + cn * 200;
    for (int c0 = 0; c0 < 200; c0 += 8) {
      float w8[8];
#pragma unroll
      for (int j = 0; j < 8; ++j) w8[j] = pwT[(c0 + j) * 64 + o];
#pragma unroll
      for (int j = 0; j < 8; ++j) acc += w8[j] * dr[c0 + j];
    }
    mx = fmaxf(mx, acc);
  }
  red[tid] = mx;
  __syncthreads();
  if (q == 0) {
    mx = fmaxf(fmaxf(red[o], red[64 + o]), fmaxf(red[128 + o], red[192 + o]));
    out[((size_t)b * 64 + o) * Ln + n] = fmaxf(mx, 0.f);
  }
}

// ---- merged C+Q emb conv -------------------------------------------------
__global__ void k_embconv(const float* __restrict__ chxC, const float* __restrict__ chxQ,
                          const int* __restrict__ widC, const int* __restrict__ widQ,
                          const float* __restrict__ wtab, const float* __restrict__ dw,
                          const float* __restrict__ db, const float* __restrict__ pwT,
                          const float* __restrict__ pb,
                          float* __restrict__ outC, float* __restrict__ outQ) {
  int nx = blockIdx.x, b = blockIdx.y;
  const float* chx; const int* wid; float* out; int Ln, n;
  if (nx < NN) { chx = chxC; wid = widC; out = outC; Ln = NN; n = nx; }
  else         { chx = chxQ; wid = widQ; out = outQ; Ln = MQ; n = nx - NN; }
  __shared__ float dwc[EC];
  __shared__ int sw[5];
  int tid = threadIdx.x;
  if (tid < 5) {
    int nn = n + tid - 2;
    sw[tid] = (nn >= 0 && nn < Ln) ? wid[(size_t)b * Ln + nn] : -1;
  }
  __syncthreads();
  for (int ch = tid; ch < EC; ch += 64) {
    float r[5];
#pragma unroll
    for (int k = 0; k < 5; ++k) {
      int nn = n + k - 2;
      float v = 0.f;
      if (nn >= 0 && nn < Ln) {
        if (ch < 64) v = chx[((size_t)b * 64 + ch) * Ln + nn];
        else v = wtab[(size_t)sw[k] * 300 + (ch - 64)];
      }
      r[k] = v;
    }
    float acc = db[ch];
#pragma unroll
    for (int k = 0; k < 5; ++k) acc += r[k] * dw[ch * 5 + k];
    dwc[ch] = acc;
  }
  __syncthreads();
  int o = tid;
  float acc = pb[o];
  for (int c0 = 0; c0 < EC; c0 += 4) {
    float w4[4];
#pragma unroll
    for (int j = 0; j < 4; ++j) w4[j] = pwT[(c0 + j) * 64 + o];
#pragma unroll
    for (int j = 0; j < 4; ++j) acc += w4[j] * dwc[c0 + j];
  }
  out[((size_t)b * 64 + o) * Ln + n] = acc;
}

// ---------------- merged C+Q highway --------------------------------------
__global__ void k_highway(const float* __restrict__ inxC, const float* __restrict__ inxQ,
                          const float* __restrict__ lwT, const float* __restrict__ lb,
                          const float* __restrict__ gwT, const float* __restrict__ gb,
                          float* __restrict__ outC, float* __restrict__ outQ) {
  int nx = blockIdx.x, b = blockIdx.y;
  const float* inx; float* out; int Ln, n;
  if (nx < NN) { inx = inxC; out = outC; Ln = NN; n = nx; }
  else         { inx = inxQ; out = outQ; Ln = MQ; n = nx - NN; }
  __shared__ float x[64], xn[64];
  int o = threadIdx.x;
  x[o] = inx[((size_t)b * 64 + o) * Ln + n];
  __syncthreads();
  for (int layer = 0; layer < 2; ++layer) {
    const float* lwr = lwT + layer * 4096;
    const float* gwr = gwT + layer * 4096;
    float gl = gb[layer * 64 + o], nl = lb[layer * 64 + o];
    for (int d0 = 0; d0 < 64; d0 += 8) {
      float g8[8], l8[8];
#pragma unroll
      for (int j = 0; j < 8; ++j) { g8[j] = gwr[(d0 + j) * 64 + o]; l8[j] = lwr[(d0 + j) * 64 + o]; }
#pragma unroll
      for (int j = 0; j < 8; ++j) { gl += g8[j] * x[d0 + j]; nl += l8[j] * x[d0 + j]; }
    }
    float g = 1.f / (1.f + __expf(-gl));
    float r = fmaxf(nl, 0.f);
    xn[o] = g * r + (1.f - g) * x[o];
    __syncthreads();
    x[o] = xn[o];
    __syncthreads();
  }
  out[((size_t)b * 64 + o) * Ln + n] = x[o];
}

// ---------------- context-query attention ---------------------------------
__global__ __launch_bounds__(256) void k_cqS(const float* __restrict__ C,
                                             const float* __restrict__ Q,
                                             const float* __restrict__ w,
                                             float* __restrict__ S,
                                             float* __restrict__ rmax,
                                             float* __restrict__ rsum) {
  int b = blockIdx.x, nt = blockIdx.y * 64;
  __shared__ float sQ[4096], sC[4096], ct[64], qt[64], swb[192];
  const float* Cb = C + (size_t)b * 64 * 256;
  const float* Qb = Q + (size_t)b * 4096;
  const float* wb = w + (size_t)b * 192;
  if (threadIdx.x < 192) swb[threadIdx.x] = wb[threadIdx.x];
  for (int i = threadIdx.x; i < 4096; i += 256) {
    int d = i >> 6, m = i & 63;
    sQ[i] = Qb[d * 64 + m];
    sC[i] = Cb[d * 256 + nt + m];
  }
  __syncthreads();
  if (threadIdx.x < 64) {
    int j = threadIdx.x;
    float a = 0.f, c2 = 0.f;
    for (int d = 0; d < 64; ++d) {
      a += swb[64 + d] * sC[d * 64 + j];
      c2 += swb[d] * sQ[d * 64 + j];
    }
    ct[j] = a; qt[j] = c2;
  }
  __syncthreads();
  int m = threadIdx.x & 63, wv = threadIdx.x >> 6;
  for (int it = 0; it < 16; ++it) {
    int nl = wv + it * 4;
    float acc = ct[nl] + qt[m];
    for (int d = 0; d < 64; ++d)
      acc += sC[d * 64 + nl] * swb[128 + d] * sQ[d * 64 + m];
    S[((size_t)b * 256 + nt + nl) * 64 + m] = acc;
    float mx = acc;
#pragma unroll
    for (int o = 32; o > 0; o >>= 1) mx = fmaxf(mx, __shfl_xor(mx, o));
    float p = __expf(acc - mx);
#pragma unroll
    for (int o = 32; o > 0; o >>= 1) p += __shfl_xor(p, o);
    if (m == 0) { rmax[b * 256 + nt + nl] = mx; rsum[b * 256 + nt + nl] = p; }
  }
}

__global__ void k_cqcol(const float* __restrict__ S, float* __restrict__ cmax,
                        float* __restrict__ csum) {
  int b = blockIdx.x, m = threadIdx.x;
  const float* Sb = S + (size_t)b * 256 * 64;
  float mx = -1e30f;
  for (int n = 0; n < 256; ++n) mx = fmaxf(mx, Sb[n * 64 + m]);
  float s = 0.f;
  for (int n = 0; n < 256; ++n) s += __expf(Sb[n * 64 + m] - mx);
  cmax[b * 64 + m] = mx; csum[b * 64 + m] = s;
}

__global__ __launch_bounds__(256) void k_cqA(
    const float* __restrict__ C, const float* __restrict__ Q,
    const float* __restrict__ S, const float* __restrict__ rmax,
    const float* __restrict__ rsum, float* __restrict__ Xcat) {
  int b = blockIdx.x, nt = blockIdx.y * 64;
  __shared__ float sQ[4096];
  __shared__ float sP[64 * 65];
  const float* Qb = Q + (size_t)b * 4096;
  for (int i = threadIdx.x; i < 4096; i += 256) sQ[i] = Qb[i];
  for (int i = threadIdx.x; i < 4096; i += 256) {
    int nl = i >> 6, m = i & 63;
    int n = nt + nl;
    sP[nl * 65 + m] = __expf(S[((size_t)b * 256 + n) * 64 + m] - rmax[b * 256 + n]) / rsum[b * 256 + n];
  }
  __syncthreads();
  int nl = threadIdx.x & 63, dg = threadIdx.x >> 6;
  int n = nt + nl;
  for (int j = 0; j < 16; ++j) {
    int d = dg * 16 + j;
    float acc = 0.f;
    for (int m = 0; m < 64; ++m) acc += sQ[d * 64 + m] * sP[nl * 65 + m];
    float cv = C[((size_t)b * 64 + d) * 256 + n];
    Xcat[((size_t)b * 256 + d) * 256 + n] = cv;
    Xcat[((size_t)b * 256 + 64 + d) * 256 + n] = acc;
    Xcat[((size_t)b * 256 + 128 + d) * 256 + n] = cv * acc;
  }
}

// CS2[d,m] = sum_n C[d,n] * S2[n,m]
__global__ __launch_bounds__(256) void k_cqCS2(
    const float* __restrict__ C, const float* __restrict__ S,
    const float* __restrict__ cmax, const float* __restrict__ csum,
    float* __restrict__ CS2) {
  int b = blockIdx.x;
  __shared__ float sP[4096], sC[4096];
  int m = threadIdx.x & 63, dg = threadIdx.x >> 6;
  float acc[16];
#pragma unroll
  for (int j = 0; j < 16; ++j) acc[j] = 0.f;
  for (int nt = 0; nt < 4; ++nt) {
    __syncthreads();
    for (int i = threadIdx.x; i < 4096; i += 256) {
      int nl = i >> 6, mm = i & 63;
      int n = nt * 64 + nl;
      sP[i] = __expf(S[((size_t)b * 256 + n) * 64 + mm] - cmax[b * 64 + mm]) / csum[b * 64 + mm];
      int d = i >> 6, nn = i & 63;
      sC[i] = C[((size_t)b * 64 + d) * 256 + nt * 64 + nn];
    }
    __syncthreads();
    for (int nl = 0; nl < 64; ++nl) {
      float p = sP[nl * 64 + m];
#pragma unroll
      for (int j = 0; j < 16; ++j) acc[j] += sC[(dg * 16 + j) * 64 + nl] * p;
    }
  }
  for (int j = 0; j < 16; ++j)
    CS2[((size_t)b * 64 + dg * 16 + j) * 64 + m] = acc[j];
}

// Bm[d,k] = sum_m CS2[d,m] * S1[k,m]
__global__ __launch_bounds__(256) void k_cqBm(
    const float* __restrict__ C, const float* __restrict__ CS2,
    const float* __restrict__ S, const float* __restrict__ rmax,
    const float* __restrict__ rsum, float* __restrict__ Xcat) {
  int b = blockIdx.x, kt = blockIdx.y * 64;
  __shared__ float sW[4096];
  __shared__ float sP[64 * 65];
  for (int i = threadIdx.x; i < 4096; i += 256) sW[i] = CS2[(size_t)b * 4096 + i];
  for (int i = threadIdx.x; i < 4096; i += 256) {
    int kl = i >> 6, m = i & 63;
    int k = kt + kl;
    sP[kl * 65 + m] = __expf(S[((size_t)b * 256 + k) * 64 + m] - rmax[b * 256 + k]) / rsum[b * 256 + k];
  }
  __syncthreads();
  int kl = threadIdx.x & 63, dg = threadIdx.x >> 6;
  int k = kt + kl;
  for (int j = 0; j < 16; ++j) {
    int d = dg * 16 + j;
    float acc = 0.f;
    for (int m = 0; m < 64; ++m) acc += sW[d * 64 + m] * sP[kl * 65 + m];
    float cv = C[((size_t)b * 64 + d) * 256 + k];
    Xcat[((size_t)b * 256 + 192 + d) * 256 + k] = cv * acc;
  }
}

// ---- both pointers in one launch: grid (B, 2) ----------------------------
__global__ void k_pointer2(const float* __restrict__ M0, const float* __restrict__ M1,
                           const float* __restrict__ M2, const float* __restrict__ w0,
                           const float* __restrict__ w1, float* __restrict__ out) {
  int b = blockIdx.x, sel = blockIdx.y, n = threadIdx.x;
  const float* wb = (sel ? w1 : w0) + b * 128;
  const float* Mb = sel ? M2 : M1;
  float y = 0.f;
  for (int d = 0; d < 64; ++d) {
    y += wb[d] * M0[((size_t)b * 64 + d) * 256 + n];
    y += wb[64 + d] * Mb[((size_t)b * 64 + d) * 256 + n];
  }
  __shared__ float wred[4], wsum[4];
  int lane = n & 63, wid = n >> 6;
  float mx = y;
#pragma unroll
  for (int o = 32; o > 0; o >>= 1) mx = fmaxf(mx, __shfl_xor(mx, o));
  if (lane == 0) wred[wid] = mx;
  __syncthreads();
  mx = fmaxf(fmaxf(wred[0], wred[1]), fmaxf(wred[2], wred[3]));
  float e = __expf(y - mx);
  float s = e;
#pragma unroll
  for (int o = 32; o > 0; o >>= 1) s += __shfl_xor(s, o);
  if (lane == 0) wsum[wid] = s;
  __syncthreads();
  s = wsum[0] + wsum[1] + wsum[2] + wsum[3];
  out[sel * 6144 + b * 256 + n] = e / s;
}

// ===========================================================================
extern "C" void kernel_launch(void* const* d_in, const int* in_sizes, int n_in,
                              void* d_out, int out_size, void* d_ws, size_t ws_size,
                              hipStream_t stream) {
  const float* word_table = (const float*)d_in[0];
  const float* char_table = (const float*)d_in[1];
  const float* e2dw = (const float*)d_in[2];
  const float* e2db = (const float*)d_in[3];
  const float* e2pw = (const float*)d_in[4];
  const float* e2pb = (const float*)d_in[5];
  const float* e1dw = (const float*)d_in[6];
  const float* e1db = (const float*)d_in[7];
  const float* e1pw = (const float*)d_in[8];
  const float* e1pb = (const float*)d_in[9];
  const float* hlw = (const float*)d_in[10];
  const float* hlb = (const float*)d_in[11];
  const float* hgw = (const float*)d_in[12];
  const float* hgb = (const float*)d_in[13];
  const float *enc_dw[5], *enc_pw[5], *enc_wq[5], *enc_wk[5], *enc_wv[5], *enc_wo[5], *enc_w[5];
  for (int p = 0; p < 5; ++p) {
    enc_dw[p] = (const float*)d_in[14 + 7 * p + 0];
    enc_pw[p] = (const float*)d_in[14 + 7 * p + 1];
    enc_wq[p] = (const float*)d_in[14 + 7 * p + 2];
    enc_wk[p] = (const float*)d_in[14 + 7 * p + 3];
    enc_wv[p] = (const float*)d_in[14 + 7 * p + 4];
    enc_wo[p] = (const float*)d_in[14 + 7 * p + 5];
    enc_w[p]  = (const float*)d_in[14 + 7 * p + 6];
  }
  const float* cq_w  = (const float*)d_in[49];
  const float* rs_dw = (const float*)d_in[50];
  const float* rs_pw = (const float*)d_in[51];
  const float* p_w0  = (const float*)d_in[52];
  const float* p_w1  = (const float*)d_in[53];
  const int* Cwid = (const int*)d_in[54];
  const int* Ccid = (const int*)d_in[55];
  const int* Qwid = (const int*)d_in[56];
  const int* Qcid = (const int*)d_in[57];
  float* out = (float*)d_out;

  // ---- workspace (floats), ~12.3 MB --------------------------------------
  float* ws = (float*)d_ws;
  float* postab = ws;                  // 16384
  float* U    = ws + 16384;            // 393216  (att head out)
  float* Xcat = ws + 409600;           // 1572864 ; M2 aliases; emb scratch
  float* CX   = ws + 1982464;          // 393216  ; M0 aliases
  float* Sb   = ws + 2375680;          // 393216  ; M1 aliases
  float* QX   = ws + 2768896;          // 98304
  float* CS2  = ws + 2867200;          // 98304
  float* rmax = ws + 2965504;          // 6144
  float* rsum = ws + 2971648;          // 6144
  float* cmax = ws + 2977792;          // 1536
  float* csum = ws + 2979328;          // 1536
  float* P0   = ws + 2980864;          // 12288
  float* P1   = ws + 2993152;          // 12288
  float* pwT  = ws + 3005440;          // 12800
  float* e1pwT= ws + 3018240;          // 23296
  float* hlwT = ws + 3041536;          // 8192
  float* hgwT = ws + 3049728;          // 8192
  float* dwT  = ws + 3057920;          // 5000 -> ends 3062920
  float* M0 = CX; float* M1 = Sb; float* M2 = Xcat;
  float* E1C = Xcat;              // 393216
  float* E1Q = Xcat + 393216;     // 98304
  float* E2C = Xcat + 491520;     // 393216
  float* E2Q = Xcat + 884736;     // 98304 -> 983040 < 1572864
  (void)out_size; (void)in_sizes; (void)n_in; (void)ws_size;

  auto run_enc = [&](float* X, const float* src, int L, int cnum, int K, int p, int reps) {
    int NB = B * 64 / 4;
    if (src)
      hipLaunchKernelGGL((k_posadd_stats<true>), dim3(NB), dim3(256), 0, stream, X, src, postab, P0, L);
    else
      hipLaunchKernelGGL((k_posadd_stats<false>), dim3(NB), dim3(256), 0, stream, X, (const float*)nullptr, postab, P0, L);
    for (int rep = 0; rep < reps; ++rep) {
      float* pin = P0; float* pout = P1;
      for (int i = 0; i < cnum; ++i) {
        if (K == 7)
          hipLaunchKernelGGL((k_fconv<7>), dim3(B, L / 64), dim3(256), 0, stream,
                             X, enc_dw[p] + i * 64 * 7, enc_pw[p] + (size_t)i * 4096, pin, pout, L);
        else
          hipLaunchKernelGGL((k_fconv<5>), dim3(B, L / 64), dim3(256), 0, stream,
                             X, enc_dw[p] + i * 64 * 5, enc_pw[p] + (size_t)i * 4096, pin, pout, L);
        float* t = pin; pin = pout; pout = t;
      }
      k_att<<<dim3(HH, B), 256, 0, stream>>>(X, pin, enc_wq[p], enc_wk[p], enc_wv[p], U, L);
      hipLaunchKernelGGL((k_matmul2<false, false, true, false>), dim3(B, L / 64), dim3(256), 0, stream,
                         U, enc_wo[p], (const float*)X, X, (const float*)nullptr, pout,
                         (const float*)nullptr, L);
      if (rep + 1 < reps)
        hipLaunchKernelGGL((k_matmul2<true, true, true, true>), dim3(B, L / 64), dim3(256), 0, stream,
                           X, enc_w[p], (const float*)X, X, pout, P0, (const float*)postab, L);
      else
        hipLaunchKernelGGL((k_matmul2<true, true, false, false>), dim3(B, L / 64), dim3(256), 0, stream,
                           X, enc_w[p], (const float*)X, X, pout, (float*)nullptr,
                           (const float*)nullptr, L);
    }
  };

  k_postab<<<64, 256, 0, stream>>>(postab);
  k_wT<<<225, 256, 0, stream>>>(e2pw, e1pw, hlw, hgw, e2dw, pwT, e1pwT, hlwT, hgwT, dwT);
  // ---- embeddings (C and Q merged per stage) ----
  k_charembed<<<dim3(NN + MQ, B), 256, 0, stream>>>(Ccid, Qcid, char_table, dwT, e2db, pwT, e2pb, E1C, E1Q);
  k_embconv<<<dim3(NN + MQ, B), 64, 0, stream>>>(E1C, E1Q, Cwid, Qwid, word_table, e1dw, e1db, e1pwT, e1pb, E2C, E2Q);
  k_highway<<<dim3(NN + MQ, B), 64, 0, stream>>>(E2C, E2Q, hlwT, hlb, hgwT, hgb, CX, QX);
  // ---- embedding encoders ----
  run_enc(CX, nullptr, 256, 4, 7, 0, 1);
  run_enc(QX, nullptr, 64, 4, 7, 1, 1);
  // ---- context-query attention ----
  k_cqS<<<dim3(B, 4), 256, 0, stream>>>(CX, QX, cq_w, Sb, rmax, rsum);
  k_cqcol<<<B, 64, 0, stream>>>(Sb, cmax, csum);
  k_cqA<<<dim3(B, 4), 256, 0, stream>>>(CX, QX, Sb, rmax, rsum, Xcat);
  k_cqCS2<<<B, 256, 0, stream>>>(CX, Sb, cmax, csum, CS2);
  k_cqBm<<<dim3(B, 4), 256, 0, stream>>>(CX, CS2, Sb, rmax, rsum, Xcat);
  // ---- resize -> M0 ----
  k_resize<<<dim3(B, 4), 256, 0, stream>>>(Xcat, rs_dw, rs_pw, M0);
  // ---- model encoders ----
  run_enc(M0, nullptr, 256, 2, 5, 2, 7);
  run_enc(M1, M0, 256, 2, 5, 3, 7);
  run_enc(M2, M1, 256, 2, 5, 4, 7);
  // ---- pointers ----
  k_pointer2<<<dim3(B, 2), 256, 0, stream>>>(M0, M1, M2, p_w0, p_w1, out);
}

// Round 18
// 3321.004 us; speedup vs baseline: 1.1573x; 1.1290x over previous
//
#include <hip/hip_runtime.h>
#include <math.h>

constexpr int B = 24, HH = 8;
constexpr int NN = 256, MQ = 64;
constexpr int EC = 364;

#define PI_2 1.5707963267948966f

// stats partials layout: parts[row][4][2], row = b*64+d
__device__ __forceinline__ void combine_stats(const float* __restrict__ parts,
                                              int row, int NT, float Lf,
                                              float& mu, float& inv) {
  float s = 0.f, q = 0.f;
  for (int t = 0; t < NT; ++t) {
    s += parts[((size_t)row * 4 + t) * 2];
    q += parts[((size_t)row * 4 + t) * 2 + 1];
  }
  mu = s / Lf;
  float var = (q - s * mu) / (Lf - 1.f);
  if (var < 0.f) var = 0.f;
  inv = 1.f / (sqrtf(var) + 1e-6f);
}

// ---------------- positional encoding table: tab[d*256+l] ----------------
__global__ void k_postab(float* __restrict__ tab) {
  int d = blockIdx.x, l = threadIdx.x;
  float fr = ((d & 1) == 0) ? powf(10000.f, -(float)d / 64.f)
                            : -powf(10000.f, -(float)(d - 1) / 64.f);
  float ph = (d & 1) ? PI_2 : 0.f;
  tab[d * 256 + l] = sinf(sinf((float)l * fr + ph));
}

// ---- merged one-time weight transposes -----------------------------------
__global__ void k_wT(const float* __restrict__ e2pw, const float* __restrict__ e1pw,
                     const float* __restrict__ hlw, const float* __restrict__ hgw,
                     const float* __restrict__ e2dw,
                     float* __restrict__ pwT, float* __restrict__ e1pwT,
                     float* __restrict__ hlwT, float* __restrict__ hgwT,
                     float* __restrict__ dwT) {
  int i = blockIdx.x * 256 + threadIdx.x;
  if (i < 12800) {
    int ce = i >> 6, o = i & 63;
    pwT[i] = e2pw[o * 200 + ce];
    return;
  }
  i -= 12800;
  if (i < 23296) {
    int c = i >> 6, o = i & 63;
    e1pwT[i] = e1pw[o * EC + c];
    return;
  }
  i -= 23296;
  if (i < 8192) {
    int layer = i >> 12, rem = i & 4095;
    int d = rem >> 6, o = rem & 63;
    hlwT[i] = hlw[layer * 4096 + o * 64 + d];
    return;
  }
  i -= 8192;
  if (i < 8192) {
    int layer = i >> 12, rem = i & 4095;
    int d = rem >> 6, o = rem & 63;
    hgwT[i] = hgw[layer * 4096 + o * 64 + d];
    return;
  }
  i -= 8192;
  if (i < 5000) {
    int t = i / 200, ce = i % 200;
    dwT[i] = e2dw[ce * 25 + t];
  }
}

// ---- X = (COPY? src : X) + tab ; emit per-tile row stats -----------------
template<bool COPY>
__global__ void k_posadd_stats(float* __restrict__ X, const float* __restrict__ src,
                               const float* __restrict__ tab, float* __restrict__ parts,
                               int L) {
  int row = blockIdx.x * 4 + (threadIdx.x >> 6);
  int lane = threadIdx.x & 63;
  int d = row & 63;
  float* xr = X + (size_t)row * L;
  const float* sr = COPY ? (src + (size_t)row * L) : xr;
  int NT = L >> 6;
  for (int t = 0; t < NT; ++t) {
    int l = t * 64 + lane;
    float v = sr[l] + tab[d * 256 + l];
    xr[l] = v;
    float s = v, q = v * v;
#pragma unroll
    for (int o = 32; o > 0; o >>= 1) { s += __shfl_xor(s, o); q += __shfl_xor(q, o); }
    if (lane == 0) {
      parts[((size_t)row * 4 + t) * 2] = s;
      parts[((size_t)row * 4 + t) * 2 + 1] = q;
    }
  }
}

// ---- fused: normalize -> dwconv(K) -> pw matmul -> relu -> +res -> X -----
// 512 threads: 8 waves/block, each og-group owns 8 outputs.
template<int K>
__global__ __launch_bounds__(512) void k_fconv(
    float* __restrict__ X, const float* __restrict__ dw, const float* __restrict__ pw,
    const float* __restrict__ partsIn, float* __restrict__ partsOut, int L) {
  constexpr int H = K / 2, SW = 64 + 2 * H;
  __shared__ float smu[64], sinv[64];
  __shared__ float sN[64 * SW];
  __shared__ float sD[64 * 65];
  __shared__ __align__(16) float sWt[4096];
  int b = blockIdx.x, lt = blockIdx.y * 64;
  int tid = threadIdx.x;
  int NT = L >> 6;
  if (tid < 64) combine_stats(partsIn, b * 64 + tid, NT, (float)L, smu[tid], sinv[tid]);
  for (int i = tid; i < 1024; i += 512)
    ((float4*)sWt)[i] = ((const float4*)pw)[i];
  __syncthreads();
  float* Xb = X + (size_t)b * 64 * L;
  for (int i = tid; i < 64 * SW; i += 512) {
    int c = i / SW, jj = i % SW;
    int gl = lt + jj - H;
    sN[i] = (gl >= 0 && gl < L) ? (Xb[(size_t)c * L + gl] - smu[c]) * sinv[c] : 0.f;
  }
  __syncthreads();
  for (int i = tid; i < 4096; i += 512) {
    int c = i >> 6, l = i & 63;
    float acc = 0.f;
#pragma unroll
    for (int k = 0; k < K; ++k) acc += sN[c * SW + l + k] * dw[c * K + k];
    sD[c * 65 + l] = acc;
  }
  __syncthreads();
  int l = tid & 63, og = tid >> 6;   // og in 0..7
  float acc[8];
#pragma unroll
  for (int j = 0; j < 8; ++j) acc[j] = 0.f;
  for (int c = 0; c < 64; ++c) {
    float av = sD[c * 65 + l];
#pragma unroll
    for (int j = 0; j < 8; ++j) acc[j] += sWt[(og * 8 + j) * 64 + c] * av;
  }
  __syncthreads();
#pragma unroll
  for (int j = 0; j < 8; ++j) {
    int o = og * 8 + j;
    float v = Xb[(size_t)o * L + lt + l] + fmaxf(acc[j], 0.f);
    Xb[(size_t)o * L + lt + l] = v;
    sD[o * 65 + l] = v;
  }
  __syncthreads();
  if (tid < 64) {
    int o = tid;
    float s = 0.f, q = 0.f;
    for (int l2 = 0; l2 < 64; ++l2) { float v = sD[o * 65 + l2]; s += v; q += v * v; }
    partsOut[((size_t)(b * 64 + o) * 4 + blockIdx.y) * 2] = s;
    partsOut[((size_t)(b * 64 + o) * 4 + blockIdx.y) * 2 + 1] = q;
  }
}

// ---- generic 64x64 matmul: out = res + act(W . (norm?)A) [+tab] ; stats --
// 512 threads: 8 waves/block.
template<bool NORM, bool RELU, bool STATS, bool ADDTAB>
__global__ __launch_bounds__(512) void k_matmul2(
    const float* __restrict__ A, const float* __restrict__ W,
    const float* __restrict__ res, float* __restrict__ out,
    const float* __restrict__ partsIn, float* __restrict__ partsOut,
    const float* __restrict__ tab, int L) {
  __shared__ float sA[64 * 65];
  __shared__ __align__(16) float sW[4096];
  __shared__ float smu[64], sinv[64];
  int b = blockIdx.x, lt = blockIdx.y * 64;
  int tid = threadIdx.x;
  int NT = L >> 6;
  if (NORM && tid < 64) combine_stats(partsIn, b * 64 + tid, NT, (float)L, smu[tid], sinv[tid]);
  const float* Wb = W + (size_t)b * 4096;
  for (int i = tid; i < 1024; i += 512)
    ((float4*)sW)[i] = ((const float4*)Wb)[i];
  if (NORM) __syncthreads();
  const float* Ab = A + (size_t)b * 64 * L;
  for (int i = tid; i < 1024; i += 512) {
    int c = i >> 4, lq = (i & 15) * 4;
    float4 v = *(const float4*)(Ab + (size_t)c * L + lt + lq);
    if (NORM) {
      float mu = smu[c], iv = sinv[c];
      v.x = (v.x - mu) * iv; v.y = (v.y - mu) * iv;
      v.z = (v.z - mu) * iv; v.w = (v.w - mu) * iv;
    }
    sA[c * 65 + lq] = v.x; sA[c * 65 + lq + 1] = v.y;
    sA[c * 65 + lq + 2] = v.z; sA[c * 65 + lq + 3] = v.w;
  }
  __syncthreads();
  int l = tid & 63, og = tid >> 6;   // og in 0..7
  float acc[8];
#pragma unroll
  for (int j = 0; j < 8; ++j) acc[j] = 0.f;
  for (int c = 0; c < 64; ++c) {
    float av = sA[c * 65 + l];
#pragma unroll
    for (int j = 0; j < 8; ++j) acc[j] += sW[(og * 8 + j) * 64 + c] * av;
  }
  if (STATS) __syncthreads();
#pragma unroll
  for (int j = 0; j < 8; ++j) {
    int o = og * 8 + j;
    float v = acc[j];
    if (RELU) v = fmaxf(v, 0.f);
    size_t idx = ((size_t)b * 64 + o) * L + lt + l;
    v += res[idx];
    if (ADDTAB) v += tab[o * 256 + lt + l];
    out[idx] = v;
    if (STATS) sA[o * 65 + l] = v;
  }
  if (STATS) {
    __syncthreads();
    if (tid < 64) {
      int o = tid;
      float s = 0.f, q = 0.f;
      for (int l2 = 0; l2 < 64; ++l2) { float v = sA[o * 65 + l2]; s += v; q += v * v; }
      partsOut[((size_t)(b * 64 + o) * 4 + blockIdx.y) * 2] = s;
      partsOut[((size_t)(b * 64 + o) * 4 + blockIdx.y) * 2 + 1] = q;
    }
  }
}

// ---- fused resize: M0[b,o,l] = sum_c pw[o,c] * dw5(Xcat)[b,c,l] ----------
__global__ __launch_bounds__(256) void k_resize(
    const float* __restrict__ Xcat, const float* __restrict__ dw,
    const float* __restrict__ pw, float* __restrict__ out) {
  __shared__ float sA[64 * 64];
  int b = blockIdx.x, lt = blockIdx.y * 64;
  int l = threadIdx.x & 63, og = threadIdx.x >> 6;
  float acc[16];
#pragma unroll
  for (int j = 0; j < 16; ++j) acc[j] = 0.f;
  for (int c0 = 0; c0 < 256; c0 += 64) {
    __syncthreads();
    for (int i = threadIdx.x; i < 4096; i += 256) {
      int c = (i >> 6) + c0, ll = (i & 63) + lt;
      const float* xr = Xcat + ((size_t)b * 256 + c) * 256;
      float a = 0.f;
#pragma unroll
      for (int k = 0; k < 5; ++k) {
        int p = ll + k - 2;
        if (p >= 0 && p < 256) a += xr[p] * dw[c * 5 + k];
      }
      sA[i] = a;
    }
    __syncthreads();
    for (int c = 0; c < 64; ++c) {
      float av = sA[c * 64 + l];
#pragma unroll
      for (int j = 0; j < 16; ++j)
        acc[j] += pw[(size_t)(og * 16 + j) * 256 + c0 + c] * av;
    }
  }
#pragma unroll
  for (int j = 0; j < 16; ++j)
    out[((size_t)b * 64 + og * 16 + j) * 256 + lt + l] = acc[j];
}

// ---- self-attention with inline norm, online softmax ---------------------
__global__ __launch_bounds__(256) void k_att(
    const float* __restrict__ X, const float* __restrict__ partsIn,
    const float* __restrict__ wq, const float* __restrict__ wk,
    const float* __restrict__ wv, float* __restrict__ hc, int L) {
  int h = blockIdx.x, b = blockIdx.y;
  __shared__ float smu[64], sinv[64];
  __shared__ float sX[64 * 65];
  __shared__ float sQ[8 * 256], sK8[8 * 256], sV[8 * 256];
  __shared__ float swq[512], swk[512], swv[512];
  int tid = threadIdx.x;
  int NT = L >> 6;
  if (tid < 64) combine_stats(partsIn, b * 64 + tid, NT, (float)L, smu[tid], sinv[tid]);
  size_t woff = (size_t)(h * B + b) * 512;
  for (int i = tid; i < 512; i += 256) {
    swq[i] = wq[woff + i]; swk[i] = wk[woff + i]; swv[i] = wv[woff + i];
  }
  __syncthreads();
  const float* Xb = X + (size_t)b * 64 * L;
  for (int lt = 0; lt < L; lt += 64) {
    for (int i = tid; i < 4096; i += 256) {
      int d = i >> 6, l = i & 63;
      sX[d * 65 + l] = (Xb[(size_t)d * L + lt + l] - smu[d]) * sinv[d];
    }
    __syncthreads();
    for (int i = tid; i < 512; i += 256) {
      int k = i >> 6, l = i & 63;
      float aq = 0.f, ak = 0.f, av = 0.f;
      for (int d = 0; d < 64; ++d) {
        float x = sX[d * 65 + l];
        aq += swq[k * 64 + d] * x;
        ak += swk[k * 64 + d] * x;
        av += swv[k * 64 + d] * x;
      }
      sQ[k * L + lt + l] = aq; sK8[k * L + lt + l] = ak; sV[k * L + lt + l] = av;
    }
    __syncthreads();
  }
  const float scale = 0.35355339059327373f;  // 1/sqrt(8)
  for (int m = tid; m < L; m += 256) {
    float kc[8];
#pragma unroll
    for (int k = 0; k < 8; ++k) kc[k] = sK8[k * L + m];
    float mx = -1e30f, sum = 0.f, acc[8];
#pragma unroll
    for (int v = 0; v < 8; ++v) acc[v] = 0.f;
    for (int l = 0; l < L; ++l) {
      float s = 0.f;
#pragma unroll
      for (int k = 0; k < 8; ++k) s += sQ[k * L + l] * kc[k];
      s *= scale;
      if (s <= mx) {
        float p = __expf(s - mx);
        sum += p;
#pragma unroll
        for (int v = 0; v < 8; ++v) acc[v] += p * sV[v * L + l];
      } else {
        float corr = __expf(mx - s);
        sum = sum * corr + 1.f;
#pragma unroll
        for (int v = 0; v < 8; ++v) acc[v] = acc[v] * corr + sV[v * L + l];
        mx = s;
      }
    }
    float is = 1.f / sum;
    for (int v = 0; v < 8; ++v)
      hc[((size_t)b * 64 + h * 8 + v) * L + m] = acc[v] * is;
  }
}

// ---- merged C+Q char embed: register-staged taps + hoisted pwT -----------
__global__ __launch_bounds__(256) void k_charembed(
    const int* __restrict__ cidC, const int* __restrict__ cidQ,
    const float* __restrict__ ctab, const float* __restrict__ dwT,
    const float* __restrict__ db, const float* __restrict__ pwT,
    const float* __restrict__ pb,
    float* __restrict__ outC, float* __restrict__ outQ) {
  int nx = blockIdx.x, b = blockIdx.y;
  const int* cid; float* out; int Ln, n;
  if (nx < NN) { cid = cidC; out = outC; Ln = NN; n = nx; }
  else         { cid = cidQ; out = outQ; Ln = MQ; n = nx - NN; }
  __shared__ float dwo[16 * 200];   // [cn][ce]
  __shared__ int sid[5][16];
  __shared__ float red[256];
  int tid = threadIdx.x;
  if (tid < 80) {
    int kn = tid / 16, cn = tid % 16;
    int nn = n + kn - 2;
    sid[kn][cn] = (nn >= 0 && nn < Ln) ? cid[((size_t)b * Ln + nn) * 16 + cn] : -1;
  }
  __syncthreads();
  for (int i = tid; i < 16 * 200; i += 256) {
    int cn = i / 200, ce = i % 200;
    float r[25];
#pragma unroll
    for (int kn = 0; kn < 5; ++kn) {
#pragma unroll
      for (int kc = 0; kc < 5; ++kc) {
        int cc = cn + kc - 2;
        int id = (cc >= 0 && cc < 16) ? sid[kn][cc] : -1;
        r[kn * 5 + kc] = (id >= 0) ? ctab[(size_t)id * 200 + ce] : 0.f;
      }
    }
    float acc = db[ce];
#pragma unroll
    for (int t = 0; t < 25; ++t) acc += r[t] * dwT[t * 200 + ce];
    dwo[cn * 200 + ce] = acc;
  }
  __syncthreads();
  int o = tid & 63, q = tid >> 6;
  // phase 2: c0 outer, 4 cn accumulators share each w8 load (4x fewer loads)
  float acc4[4];
#pragma unroll
  for (int k = 0; k < 4; ++k) acc4[k] = pb[o];
  for (int c0 = 0; c0 < 200; c0 += 8) {
    float w8[8];
#pragma unroll
    for (int j = 0; j < 8; ++j) w8[j] = pwT[(c0 + j) * 64 + o];
#pragma unroll
    for (int k = 0; k < 4; ++k) {
      const float* dr = dwo + (q + k * 4) * 200 + c0;
#pragma unroll
      for (int j = 0; j < 8; ++j) acc4[k] += w8[j] * dr[j];
    }
  }
  float mx = -1e30f;
#pragma unroll
  for (int k = 0; k < 4; ++k) mx = fmaxf(mx, acc4[k]);
  red[tid] = mx;
  __syncthreads();
  if (q == 0) {
    mx = fmaxf(fmaxf(red[o], red[64 + o]), fmaxf(red[128 + o], red[192 + o]));
    out[((size_t)b * 64 + o) * Ln + n] = fmaxf(mx, 0.f);
  }
}

// ---- merged C+Q emb conv -------------------------------------------------
__global__ void k_embconv(const float* __restrict__ chxC, const float* __restrict__ chxQ,
                          const int* __restrict__ widC, const int* __restrict__ widQ,
                          const float* __restrict__ wtab, const float* __restrict__ dw,
                          const float* __restrict__ db, const float* __restrict__ pwT,
                          const float* __restrict__ pb,
                          float* __restrict__ outC, float* __restrict__ outQ) {
  int nx = blockIdx.x, b = blockIdx.y;
  const float* chx; const int* wid; float* out; int Ln, n;
  if (nx < NN) { chx = chxC; wid = widC; out = outC; Ln = NN; n = nx; }
  else         { chx = chxQ; wid = widQ; out = outQ; Ln = MQ; n = nx - NN; }
  __shared__ float dwc[EC];
  __shared__ int sw[5];
  int tid = threadIdx.x;
  if (tid < 5) {
    int nn = n + tid - 2;
    sw[tid] = (nn >= 0 && nn < Ln) ? wid[(size_t)b * Ln + nn] : -1;
  }
  __syncthreads();
  for (int ch = tid; ch < EC; ch += 64) {
    float r[5];
#pragma unroll
    for (int k = 0; k < 5; ++k) {
      int nn = n + k - 2;
      float v = 0.f;
      if (nn >= 0 && nn < Ln) {
        if (ch < 64) v = chx[((size_t)b * 64 + ch) * Ln + nn];
        else v = wtab[(size_t)sw[k] * 300 + (ch - 64)];
      }
      r[k] = v;
    }
    float acc = db[ch];
#pragma unroll
    for (int k = 0; k < 5; ++k) acc += r[k] * dw[ch * 5 + k];
    dwc[ch] = acc;
  }
  __syncthreads();
  int o = tid;
  float acc = pb[o];
  for (int c0 = 0; c0 < EC; c0 += 4) {
    float w4[4];
#pragma unroll
    for (int j = 0; j < 4; ++j) w4[j] = pwT[(c0 + j) * 64 + o];
#pragma unroll
    for (int j = 0; j < 4; ++j) acc += w4[j] * dwc[c0 + j];
  }
  out[((size_t)b * 64 + o) * Ln + n] = acc;
}

// ---------------- merged C+Q highway --------------------------------------
__global__ void k_highway(const float* __restrict__ inxC, const float* __restrict__ inxQ,
                          const float* __restrict__ lwT, const float* __restrict__ lb,
                          const float* __restrict__ gwT, const float* __restrict__ gb,
                          float* __restrict__ outC, float* __restrict__ outQ) {
  int nx = blockIdx.x, b = blockIdx.y;
  const float* inx; float* out; int Ln, n;
  if (nx < NN) { inx = inxC; out = outC; Ln = NN; n = nx; }
  else         { inx = inxQ; out = outQ; Ln = MQ; n = nx - NN; }
  __shared__ float x[64], xn[64];
  int o = threadIdx.x;
  x[o] = inx[((size_t)b * 64 + o) * Ln + n];
  __syncthreads();
  for (int layer = 0; layer < 2; ++layer) {
    const float* lwr = lwT + layer * 4096;
    const float* gwr = gwT + layer * 4096;
    float gl = gb[layer * 64 + o], nl = lb[layer * 64 + o];
    for (int d0 = 0; d0 < 64; d0 += 8) {
      float g8[8], l8[8];
#pragma unroll
      for (int j = 0; j < 8; ++j) { g8[j] = gwr[(d0 + j) * 64 + o]; l8[j] = lwr[(d0 + j) * 64 + o]; }
#pragma unroll
      for (int j = 0; j < 8; ++j) { gl += g8[j] * x[d0 + j]; nl += l8[j] * x[d0 + j]; }
    }
    float g = 1.f / (1.f + __expf(-gl));
    float r = fmaxf(nl, 0.f);
    xn[o] = g * r + (1.f - g) * x[o];
    __syncthreads();
    x[o] = xn[o];
    __syncthreads();
  }
  out[((size_t)b * 64 + o) * Ln + n] = x[o];
}

// ---------------- context-query attention ---------------------------------
__global__ __launch_bounds__(256) void k_cqS(const float* __restrict__ C,
                                             const float* __restrict__ Q,
                                             const float* __restrict__ w,
                                             float* __restrict__ S,
                                             float* __restrict__ rmax,
                                             float* __restrict__ rsum) {
  int b = blockIdx.x, nt = blockIdx.y * 64;
  __shared__ float sQ[4096], sC[4096], ct[64], qt[64], swb[192];
  const float* Cb = C + (size_t)b * 64 * 256;
  const float* Qb = Q + (size_t)b * 4096;
  const float* wb = w + (size_t)b * 192;
  if (threadIdx.x < 192) swb[threadIdx.x] = wb[threadIdx.x];
  for (int i = threadIdx.x; i < 4096; i += 256) {
    int d = i >> 6, m = i & 63;
    sQ[i] = Qb[d * 64 + m];
    sC[i] = Cb[d * 256 + nt + m];
  }
  __syncthreads();
  if (threadIdx.x < 64) {
    int j = threadIdx.x;
    float a = 0.f, c2 = 0.f;
    for (int d = 0; d < 64; ++d) {
      a += swb[64 + d] * sC[d * 64 + j];
      c2 += swb[d] * sQ[d * 64 + j];
    }
    ct[j] = a; qt[j] = c2;
  }
  __syncthreads();
  int m = threadIdx.x & 63, wv = threadIdx.x >> 6;
  for (int it = 0; it < 16; ++it) {
    int nl = wv + it * 4;
    float acc = ct[nl] + qt[m];
    for (int d = 0; d < 64; ++d)
      acc += sC[d * 64 + nl] * swb[128 + d] * sQ[d * 64 + m];
    S[((size_t)b * 256 + nt + nl) * 64 + m] = acc;
    float mx = acc;
#pragma unroll
    for (int o = 32; o > 0; o >>= 1) mx = fmaxf(mx, __shfl_xor(mx, o));
    float p = __expf(acc - mx);
#pragma unroll
    for (int o = 32; o > 0; o >>= 1) p += __shfl_xor(p, o);
    if (m == 0) { rmax[b * 256 + nt + nl] = mx; rsum[b * 256 + nt + nl] = p; }
  }
}

__global__ void k_cqcol(const float* __restrict__ S, float* __restrict__ cmax,
                        float* __restrict__ csum) {
  int b = blockIdx.x, m = threadIdx.x;
  const float* Sb = S + (size_t)b * 256 * 64;
  float mx = -1e30f;
  for (int n = 0; n < 256; ++n) mx = fmaxf(mx, Sb[n * 64 + m]);
  float s = 0.f;
  for (int n = 0; n < 256; ++n) s += __expf(Sb[n * 64 + m] - mx);
  cmax[b * 64 + m] = mx; csum[b * 64 + m] = s;
}

__global__ __launch_bounds__(256) void k_cqA(
    const float* __restrict__ C, const float* __restrict__ Q,
    const float* __restrict__ S, const float* __restrict__ rmax,
    const float* __restrict__ rsum, float* __restrict__ Xcat) {
  int b = blockIdx.x, nt = blockIdx.y * 64;
  __shared__ float sQ[4096];
  __shared__ float sP[64 * 65];
  const float* Qb = Q + (size_t)b * 4096;
  for (int i = threadIdx.x; i < 4096; i += 256) sQ[i] = Qb[i];
  for (int i = threadIdx.x; i < 4096; i += 256) {
    int nl = i >> 6, m = i & 63;
    int n = nt + nl;
    sP[nl * 65 + m] = __expf(S[((size_t)b * 256 + n) * 64 + m] - rmax[b * 256 + n]) / rsum[b * 256 + n];
  }
  __syncthreads();
  int nl = threadIdx.x & 63, dg = threadIdx.x >> 6;
  int n = nt + nl;
  for (int j = 0; j < 16; ++j) {
    int d = dg * 16 + j;
    float acc = 0.f;
    for (int m = 0; m < 64; ++m) acc += sQ[d * 64 + m] * sP[nl * 65 + m];
    float cv = C[((size_t)b * 64 + d) * 256 + n];
    Xcat[((size_t)b * 256 + d) * 256 + n] = cv;
    Xcat[((size_t)b * 256 + 64 + d) * 256 + n] = acc;
    Xcat[((size_t)b * 256 + 128 + d) * 256 + n] = cv * acc;
  }
}

// CS2[d,m] = sum_n C[d,n] * S2[n,m]
__global__ __launch_bounds__(256) void k_cqCS2(
    const float* __restrict__ C, const float* __restrict__ S,
    const float* __restrict__ cmax, const float* __restrict__ csum,
    float* __restrict__ CS2) {
  int b = blockIdx.x;
  __shared__ float sP[4096], sC[4096];
  int m = threadIdx.x & 63, dg = threadIdx.x >> 6;
  float acc[16];
#pragma unroll
  for (int j = 0; j < 16; ++j) acc[j] = 0.f;
  for (int nt = 0; nt < 4; ++nt) {
    __syncthreads();
    for (int i = threadIdx.x; i < 4096; i += 256) {
      int nl = i >> 6, mm = i & 63;
      int n = nt * 64 + nl;
      sP[i] = __expf(S[((size_t)b * 256 + n) * 64 + mm] - cmax[b * 64 + mm]) / csum[b * 64 + mm];
      int d = i >> 6, nn = i & 63;
      sC[i] = C[((size_t)b * 64 + d) * 256 + nt * 64 + nn];
    }
    __syncthreads();
    for (int nl = 0; nl < 64; ++nl) {
      float p = sP[nl * 64 + m];
#pragma unroll
      for (int j = 0; j < 16; ++j) acc[j] += sC[(dg * 16 + j) * 64 + nl] * p;
    }
  }
  for (int j = 0; j < 16; ++j)
    CS2[((size_t)b * 64 + dg * 16 + j) * 64 + m] = acc[j];
}

// Bm[d,k] = sum_m CS2[d,m] * S1[k,m]
__global__ __launch_bounds__(256) void k_cqBm(
    const float* __restrict__ C, const float* __restrict__ CS2,
    const float* __restrict__ S, const float* __restrict__ rmax,
    const float* __restrict__ rsum, float* __restrict__ Xcat) {
  int b = blockIdx.x, kt = blockIdx.y * 64;
  __shared__ float sW[4096];
  __shared__ float sP[64 * 65];
  for (int i = threadIdx.x; i < 4096; i += 256) sW[i] = CS2[(size_t)b * 4096 + i];
  for (int i = threadIdx.x; i < 4096; i += 256) {
    int kl = i >> 6, m = i & 63;
    int k = kt + kl;
    sP[kl * 65 + m] = __expf(S[((size_t)b * 256 + k) * 64 + m] - rmax[b * 256 + k]) / rsum[b * 256 + k];
  }
  __syncthreads();
  int kl = threadIdx.x & 63, dg = threadIdx.x >> 6;
  int k = kt + kl;
  for (int j = 0; j < 16; ++j) {
    int d = dg * 16 + j;
    float acc = 0.f;
    for (int m = 0; m < 64; ++m) acc += sW[d * 64 + m] * sP[kl * 65 + m];
    float cv = C[((size_t)b * 64 + d) * 256 + k];
    Xcat[((size_t)b * 256 + 192 + d) * 256 + k] = cv * acc;
  }
}

// ---- both pointers in one launch: grid (B, 2) ----------------------------
__global__ void k_pointer2(const float* __restrict__ M0, const float* __restrict__ M1,
                           const float* __restrict__ M2, const float* __restrict__ w0,
                           const float* __restrict__ w1, float* __restrict__ out) {
  int b = blockIdx.x, sel = blockIdx.y, n = threadIdx.x;
  const float* wb = (sel ? w1 : w0) + b * 128;
  const float* Mb = sel ? M2 : M1;
  float y = 0.f;
  for (int d = 0; d < 64; ++d) {
    y += wb[d] * M0[((size_t)b * 64 + d) * 256 + n];
    y += wb[64 + d] * Mb[((size_t)b * 64 + d) * 256 + n];
  }
  __shared__ float wred[4], wsum[4];
  int lane = n & 63, wid = n >> 6;
  float mx = y;
#pragma unroll
  for (int o = 32; o > 0; o >>= 1) mx = fmaxf(mx, __shfl_xor(mx, o));
  if (lane == 0) wred[wid] = mx;
  __syncthreads();
  mx = fmaxf(fmaxf(wred[0], wred[1]), fmaxf(wred[2], wred[3]));
  float e = __expf(y - mx);
  float s = e;
#pragma unroll
  for (int o = 32; o > 0; o >>= 1) s += __shfl_xor(s, o);
  if (lane == 0) wsum[wid] = s;
  __syncthreads();
  s = wsum[0] + wsum[1] + wsum[2] + wsum[3];
  out[sel * 6144 + b * 256 + n] = e / s;
}

// ===========================================================================
extern "C" void kernel_launch(void* const* d_in, const int* in_sizes, int n_in,
                              void* d_out, int out_size, void* d_ws, size_t ws_size,
                              hipStream_t stream) {
  const float* word_table = (const float*)d_in[0];
  const float* char_table = (const float*)d_in[1];
  const float* e2dw = (const float*)d_in[2];
  const float* e2db = (const float*)d_in[3];
  const float* e2pw = (const float*)d_in[4];
  const float* e2pb = (const float*)d_in[5];
  const float* e1dw = (const float*)d_in[6];
  const float* e1db = (const float*)d_in[7];
  const float* e1pw = (const float*)d_in[8];
  const float* e1pb = (const float*)d_in[9];
  const float* hlw = (const float*)d_in[10];
  const float* hlb = (const float*)d_in[11];
  const float* hgw = (const float*)d_in[12];
  const float* hgb = (const float*)d_in[13];
  const float *enc_dw[5], *enc_pw[5], *enc_wq[5], *enc_wk[5], *enc_wv[5], *enc_wo[5], *enc_w[5];
  for (int p = 0; p < 5; ++p) {
    enc_dw[p] = (const float*)d_in[14 + 7 * p + 0];
    enc_pw[p] = (const float*)d_in[14 + 7 * p + 1];
    enc_wq[p] = (const float*)d_in[14 + 7 * p + 2];
    enc_wk[p] = (const float*)d_in[14 + 7 * p + 3];
    enc_wv[p] = (const float*)d_in[14 + 7 * p + 4];
    enc_wo[p] = (const float*)d_in[14 + 7 * p + 5];
    enc_w[p]  = (const float*)d_in[14 + 7 * p + 6];
  }
  const float* cq_w  = (const float*)d_in[49];
  const float* rs_dw = (const float*)d_in[50];
  const float* rs_pw = (const float*)d_in[51];
  const float* p_w0  = (const float*)d_in[52];
  const float* p_w1  = (const float*)d_in[53];
  const int* Cwid = (const int*)d_in[54];
  const int* Ccid = (const int*)d_in[55];
  const int* Qwid = (const int*)d_in[56];
  const int* Qcid = (const int*)d_in[57];
  float* out = (float*)d_out;

  // ---- workspace (floats), ~12.3 MB --------------------------------------
  float* ws = (float*)d_ws;
  float* postab = ws;                  // 16384
  float* U    = ws + 16384;            // 393216  (att head out)
  float* Xcat = ws + 409600;           // 1572864 ; M2 aliases; emb scratch
  float* CX   = ws + 1982464;          // 393216  ; M0 aliases
  float* Sb   = ws + 2375680;          // 393216  ; M1 aliases
  float* QX   = ws + 2768896;          // 98304
  float* CS2  = ws + 2867200;          // 98304
  float* rmax = ws + 2965504;          // 6144
  float* rsum = ws + 2971648;          // 6144
  float* cmax = ws + 2977792;          // 1536
  float* csum = ws + 2979328;          // 1536
  float* P0   = ws + 2980864;          // 12288
  float* P1   = ws + 2993152;          // 12288
  float* pwT  = ws + 3005440;          // 12800
  float* e1pwT= ws + 3018240;          // 23296
  float* hlwT = ws + 3041536;          // 8192
  float* hgwT = ws + 3049728;          // 8192
  float* dwT  = ws + 3057920;          // 5000 -> ends 3062920
  float* M0 = CX; float* M1 = Sb; float* M2 = Xcat;
  float* E1C = Xcat;              // 393216
  float* E1Q = Xcat + 393216;     // 98304
  float* E2C = Xcat + 491520;     // 393216
  float* E2Q = Xcat + 884736;     // 98304 -> 983040 < 1572864
  (void)out_size; (void)in_sizes; (void)n_in; (void)ws_size;

  auto run_enc = [&](float* X, const float* src, int L, int cnum, int K, int p, int reps) {
    int NB = B * 64 / 4;
    if (src)
      hipLaunchKernelGGL((k_posadd_stats<true>), dim3(NB), dim3(256), 0, stream, X, src, postab, P0, L);
    else
      hipLaunchKernelGGL((k_posadd_stats<false>), dim3(NB), dim3(256), 0, stream, X, (const float*)nullptr, postab, P0, L);
    for (int rep = 0; rep < reps; ++rep) {
      float* pin = P0; float* pout = P1;
      for (int i = 0; i < cnum; ++i) {
        if (K == 7)
          hipLaunchKernelGGL((k_fconv<7>), dim3(B, L / 64), dim3(512), 0, stream,
                             X, enc_dw[p] + i * 64 * 7, enc_pw[p] + (size_t)i * 4096, pin, pout, L);
        else
          hipLaunchKernelGGL((k_fconv<5>), dim3(B, L / 64), dim3(512), 0, stream,
                             X, enc_dw[p] + i * 64 * 5, enc_pw[p] + (size_t)i * 4096, pin, pout, L);
        float* t = pin; pin = pout; pout = t;
      }
      k_att<<<dim3(HH, B), 256, 0, stream>>>(X, pin, enc_wq[p], enc_wk[p], enc_wv[p], U, L);
      hipLaunchKernelGGL((k_matmul2<false, false, true, false>), dim3(B, L / 64), dim3(512), 0, stream,
                         U, enc_wo[p], (const float*)X, X, (const float*)nullptr, pout,
                         (const float*)nullptr, L);
      if (rep + 1 < reps)
        hipLaunchKernelGGL((k_matmul2<true, true, true, true>), dim3(B, L / 64), dim3(512), 0, stream,
                           X, enc_w[p], (const float*)X, X, pout, P0, (const float*)postab, L);
      else
        hipLaunchKernelGGL((k_matmul2<true, true, false, false>), dim3(B, L / 64), dim3(512), 0, stream,
                           X, enc_w[p], (const float*)X, X, pout, (float*)nullptr,
                           (const float*)nullptr, L);
    }
  };

  k_postab<<<64, 256, 0, stream>>>(postab);
  k_wT<<<225, 256, 0, stream>>>(e2pw, e1pw, hlw, hgw, e2dw, pwT, e1pwT, hlwT, hgwT, dwT);
  // ---- embeddings (C and Q merged per stage) ----
  k_charembed<<<dim3(NN + MQ, B), 256, 0, stream>>>(Ccid, Qcid, char_table, dwT, e2db, pwT, e2pb, E1C, E1Q);
  k_embconv<<<dim3(NN + MQ, B), 64, 0, stream>>>(E1C, E1Q, Cwid, Qwid, word_table, e1dw, e1db, e1pwT, e1pb, E2C, E2Q);
  k_highway<<<dim3(NN + MQ, B), 64, 0, stream>>>(E2C, E2Q, hlwT, hlb, hgwT, hgb, CX, QX);
  // ---- embedding encoders ----
  run_enc(CX, nullptr, 256, 4, 7, 0, 1);
  run_enc(QX, nullptr, 64, 4, 7, 1, 1);
  // ---- context-query attention ----
  k_cqS<<<dim3(B, 4), 256, 0, stream>>>(CX, QX, cq_w, Sb, rmax, rsum);
  k_cqcol<<<B, 64, 0, stream>>>(Sb, cmax, csum);
  k_cqA<<<dim3(B, 4), 256, 0, stream>>>(CX, QX, Sb, rmax, rsum, Xcat);
  k_cqCS2<<<B, 256, 0, stream>>>(CX, Sb, cmax, csum, CS2);
  k_cqBm<<<dim3(B, 4), 256, 0, stream>>>(CX, CS2, Sb, rmax, rsum, Xcat);
  // ---- resize -> M0 ----
  k_resize<<<dim3(B, 4), 256, 0, stream>>>(Xcat, rs_dw, rs_pw, M0);
  // ---- model encoders ----
  run_enc(M0, nullptr, 256, 2, 5, 2, 7);
  run_enc(M1, M0, 256, 2, 5, 3, 7);
  run_enc(M2, M1, 256, 2, 5, 4, 7);
  // ---- pointers ----
  k_pointer2<<<dim3(B, 2), 256, 0, stream>>>(M0, M1, M2, p_w0, p_w1, out);
}

// Round 19
// 2543.596 us; speedup vs baseline: 1.5110x; 1.3056x over previous
//
#include <hip/hip_runtime.h>
#include <math.h>

constexpr int B = 24, HH = 8;
constexpr int NN = 256, MQ = 64;
constexpr int EC = 364;

#define PI_2 1.5707963267948966f

// stats partials layout: parts[row][4][2], row = b*64+d
__device__ __forceinline__ void combine_stats(const float* __restrict__ parts,
                                              int row, int NT, float Lf,
                                              float& mu, float& inv) {
  float s = 0.f, q = 0.f;
  for (int t = 0; t < NT; ++t) {
    s += parts[((size_t)row * 4 + t) * 2];
    q += parts[((size_t)row * 4 + t) * 2 + 1];
  }
  mu = s / Lf;
  float var = (q - s * mu) / (Lf - 1.f);
  if (var < 0.f) var = 0.f;
  inv = 1.f / (sqrtf(var) + 1e-6f);
}

// ---------------- positional encoding table: tab[d*256+l] ----------------
__global__ void k_postab(float* __restrict__ tab) {
  int d = blockIdx.x, l = threadIdx.x;
  float fr = ((d & 1) == 0) ? powf(10000.f, -(float)d / 64.f)
                            : -powf(10000.f, -(float)(d - 1) / 64.f);
  float ph = (d & 1) ? PI_2 : 0.f;
  tab[d * 256 + l] = sinf(sinf((float)l * fr + ph));
}

// ---- merged one-time weight transposes -----------------------------------
__global__ void k_wT(const float* __restrict__ e2pw, const float* __restrict__ e1pw,
                     const float* __restrict__ hlw, const float* __restrict__ hgw,
                     const float* __restrict__ e2dw,
                     float* __restrict__ pwT, float* __restrict__ e1pwT,
                     float* __restrict__ hlwT, float* __restrict__ hgwT,
                     float* __restrict__ dwT) {
  int i = blockIdx.x * 256 + threadIdx.x;
  if (i < 12800) {
    int ce = i >> 6, o = i & 63;
    pwT[i] = e2pw[o * 200 + ce];
    return;
  }
  i -= 12800;
  if (i < 23296) {
    int c = i >> 6, o = i & 63;
    e1pwT[i] = e1pw[o * EC + c];
    return;
  }
  i -= 23296;
  if (i < 8192) {
    int layer = i >> 12, rem = i & 4095;
    int d = rem >> 6, o = rem & 63;
    hlwT[i] = hlw[layer * 4096 + o * 64 + d];
    return;
  }
  i -= 8192;
  if (i < 8192) {
    int layer = i >> 12, rem = i & 4095;
    int d = rem >> 6, o = rem & 63;
    hgwT[i] = hgw[layer * 4096 + o * 64 + d];
    return;
  }
  i -= 8192;
  if (i < 5000) {
    int t = i / 200, ce = i % 200;
    dwT[i] = e2dw[ce * 25 + t];
  }
}

// ---- X = (COPY? src : X) + tab ; emit per-tile row stats -----------------
template<bool COPY>
__global__ void k_posadd_stats(float* __restrict__ X, const float* __restrict__ src,
                               const float* __restrict__ tab, float* __restrict__ parts,
                               int L) {
  int row = blockIdx.x * 4 + (threadIdx.x >> 6);
  int lane = threadIdx.x & 63;
  int d = row & 63;
  float* xr = X + (size_t)row * L;
  const float* sr = COPY ? (src + (size_t)row * L) : xr;
  int NT = L >> 6;
  for (int t = 0; t < NT; ++t) {
    int l = t * 64 + lane;
    float v = sr[l] + tab[d * 256 + l];
    xr[l] = v;
    float s = v, q = v * v;
#pragma unroll
    for (int o = 32; o > 0; o >>= 1) { s += __shfl_xor(s, o); q += __shfl_xor(q, o); }
    if (lane == 0) {
      parts[((size_t)row * 4 + t) * 2] = s;
      parts[((size_t)row * 4 + t) * 2 + 1] = q;
    }
  }
}

// ---- fused: normalize -> dwconv(K) -> pw matmul -> relu -> +res ----------
// ping-pong Xin -> Xout (no halo race); 512 threads.
template<int K>
__global__ __launch_bounds__(512) void k_fconv(
    const float* __restrict__ Xin, float* __restrict__ Xout,
    const float* __restrict__ dw, const float* __restrict__ pw,
    const float* __restrict__ partsIn, float* __restrict__ partsOut, int L) {
  constexpr int H = K / 2, SW = 64 + 2 * H;
  __shared__ float smu[64], sinv[64];
  __shared__ float sN[64 * SW];
  __shared__ float sD[64 * 65];
  __shared__ __align__(16) float sWt[4096];
  int b = blockIdx.x, lt = blockIdx.y * 64;
  int tid = threadIdx.x;
  int NT = L >> 6;
  if (tid < 64) combine_stats(partsIn, b * 64 + tid, NT, (float)L, smu[tid], sinv[tid]);
  for (int i = tid; i < 1024; i += 512)
    ((float4*)sWt)[i] = ((const float4*)pw)[i];
  const float* Xb = Xin + (size_t)b * 64 * L;
  int l = tid & 63, og = tid >> 6;
  float rres[8];
#pragma unroll
  for (int j = 0; j < 8; ++j)
    rres[j] = Xb[(size_t)(og * 8 + j) * L + lt + l];
  __syncthreads();
  for (int i = tid; i < 64 * SW; i += 512) {
    int c = i / SW, jj = i % SW;
    int gl = lt + jj - H;
    sN[i] = (gl >= 0 && gl < L) ? (Xb[(size_t)c * L + gl] - smu[c]) * sinv[c] : 0.f;
  }
  __syncthreads();
  for (int i = tid; i < 4096; i += 512) {
    int c = i >> 6, ll = i & 63;
    float acc = 0.f;
#pragma unroll
    for (int k = 0; k < K; ++k) acc += sN[c * SW + ll + k] * dw[c * K + k];
    sD[c * 65 + ll] = acc;
  }
  __syncthreads();
  float acc[8];
#pragma unroll
  for (int j = 0; j < 8; ++j) acc[j] = 0.f;
  for (int c = 0; c < 64; ++c) {
    float av = sD[c * 65 + l];
#pragma unroll
    for (int j = 0; j < 8; ++j) acc[j] += sWt[(og * 8 + j) * 64 + c] * av;
  }
  __syncthreads();
  float* Ob = Xout + (size_t)b * 64 * L;
#pragma unroll
  for (int j = 0; j < 8; ++j) {
    int o = og * 8 + j;
    float v = rres[j] + fmaxf(acc[j], 0.f);
    Ob[(size_t)o * L + lt + l] = v;
    sD[o * 65 + l] = v;
  }
  __syncthreads();
  if (tid < 64) {
    int o = tid;
    float s = 0.f, q = 0.f;
    for (int l2 = 0; l2 < 64; ++l2) { float v = sD[o * 65 + l2]; s += v; q += v * v; }
    partsOut[((size_t)(b * 64 + o) * 4 + blockIdx.y) * 2] = s;
    partsOut[((size_t)(b * 64 + o) * 4 + blockIdx.y) * 2 + 1] = q;
  }
}

// ---- generic 64x64 matmul: out = res + act(W . (norm?)A) [+tab] ; stats --
template<bool NORM, bool RELU, bool STATS, bool ADDTAB>
__global__ __launch_bounds__(512) void k_matmul2(
    const float* __restrict__ A, const float* __restrict__ W,
    const float* __restrict__ res, float* __restrict__ out,
    const float* __restrict__ partsIn, float* __restrict__ partsOut,
    const float* __restrict__ tab, int L) {
  __shared__ float sA[64 * 65];
  __shared__ __align__(16) float sW[4096];
  __shared__ float smu[64], sinv[64];
  int b = blockIdx.x, lt = blockIdx.y * 64;
  int tid = threadIdx.x;
  int NT = L >> 6;
  if (NORM && tid < 64) combine_stats(partsIn, b * 64 + tid, NT, (float)L, smu[tid], sinv[tid]);
  const float* Wb = W + (size_t)b * 4096;
  for (int i = tid; i < 1024; i += 512)
    ((float4*)sW)[i] = ((const float4*)Wb)[i];
  int l = tid & 63, og = tid >> 6;
  float rres[8], rtab[8];
#pragma unroll
  for (int j = 0; j < 8; ++j) {
    int o = og * 8 + j;
    rres[j] = res[((size_t)b * 64 + o) * L + lt + l];
    if (ADDTAB) rtab[j] = tab[o * 256 + lt + l];
  }
  if (NORM) __syncthreads();
  const float* Ab = A + (size_t)b * 64 * L;
  for (int i = tid; i < 1024; i += 512) {
    int c = i >> 4, lq = (i & 15) * 4;
    float4 v = *(const float4*)(Ab + (size_t)c * L + lt + lq);
    if (NORM) {
      float mu = smu[c], iv = sinv[c];
      v.x = (v.x - mu) * iv; v.y = (v.y - mu) * iv;
      v.z = (v.z - mu) * iv; v.w = (v.w - mu) * iv;
    }
    sA[c * 65 + lq] = v.x; sA[c * 65 + lq + 1] = v.y;
    sA[c * 65 + lq + 2] = v.z; sA[c * 65 + lq + 3] = v.w;
  }
  __syncthreads();
  float acc[8];
#pragma unroll
  for (int j = 0; j < 8; ++j) acc[j] = 0.f;
  for (int c = 0; c < 64; ++c) {
    float av = sA[c * 65 + l];
#pragma unroll
    for (int j = 0; j < 8; ++j) acc[j] += sW[(og * 8 + j) * 64 + c] * av;
  }
  if (STATS) __syncthreads();
#pragma unroll
  for (int j = 0; j < 8; ++j) {
    int o = og * 8 + j;
    float v = acc[j];
    if (RELU) v = fmaxf(v, 0.f);
    v += rres[j];
    if (ADDTAB) v += rtab[j];
    out[((size_t)b * 64 + o) * L + lt + l] = v;
    if (STATS) sA[o * 65 + l] = v;
  }
  if (STATS) {
    __syncthreads();
    if (tid < 64) {
      int o = tid;
      float s = 0.f, q = 0.f;
      for (int l2 = 0; l2 < 64; ++l2) { float v = sA[o * 65 + l2]; s += v; q += v * v; }
      partsOut[((size_t)(b * 64 + o) * 4 + blockIdx.y) * 2] = s;
      partsOut[((size_t)(b * 64 + o) * 4 + blockIdx.y) * 2 + 1] = q;
    }
  }
}

// ---- fused resize: M0[b,o,l] = sum_c pw[o,c] * dw5(Xcat)[b,c,l] ----------
__global__ __launch_bounds__(256) void k_resize(
    const float* __restrict__ Xcat, const float* __restrict__ dw,
    const float* __restrict__ pw, float* __restrict__ out) {
  __shared__ float sA[64 * 64];
  int b = blockIdx.x, lt = blockIdx.y * 64;
  int l = threadIdx.x & 63, og = threadIdx.x >> 6;
  float acc[16];
#pragma unroll
  for (int j = 0; j < 16; ++j) acc[j] = 0.f;
  for (int c0 = 0; c0 < 256; c0 += 64) {
    __syncthreads();
    for (int i = threadIdx.x; i < 4096; i += 256) {
      int c = (i >> 6) + c0, ll = (i & 63) + lt;
      const float* xr = Xcat + ((size_t)b * 256 + c) * 256;
      float a = 0.f;
#pragma unroll
      for (int k = 0; k < 5; ++k) {
        int p = ll + k - 2;
        if (p >= 0 && p < 256) a += xr[p] * dw[c * 5 + k];
      }
      sA[i] = a;
    }
    __syncthreads();
    for (int c = 0; c < 64; ++c) {
      float av = sA[c * 64 + l];
#pragma unroll
      for (int j = 0; j < 16; ++j)
        acc[j] += pw[(size_t)(og * 16 + j) * 256 + c0 + c] * av;
    }
  }
#pragma unroll
  for (int j = 0; j < 16; ++j)
    out[((size_t)b * 64 + og * 16 + j) * 256 + lt + l] = acc[j];
}

// ---- self-attention: 512 thr, inline norm, split-l online softmax --------
__global__ __launch_bounds__(512) void k_att(
    const float* __restrict__ X, const float* __restrict__ partsIn,
    const float* __restrict__ wq, const float* __restrict__ wk,
    const float* __restrict__ wv, float* __restrict__ hc, int L) {
  int h = blockIdx.x, b = blockIdx.y;
  __shared__ float smu[64], sinv[64];
  __shared__ float sX[64 * 65];      // staging; reused as pacc[512][8]
  __shared__ float sQ[2048], sK8[2048], sV[2048];
  __shared__ float swq[512], swk[512], swv[512];  // later: pmx, psum
  int tid = threadIdx.x;
  int NT = L >> 6;
  if (tid < 64) combine_stats(partsIn, b * 64 + tid, NT, (float)L, smu[tid], sinv[tid]);
  size_t woff = (size_t)(h * B + b) * 512;
  swq[tid] = wq[woff + tid];
  swk[tid] = wk[woff + tid];
  swv[tid] = wv[woff + tid];
  __syncthreads();
  const float* Xb = X + (size_t)b * 64 * L;
  for (int lt = 0; lt < L; lt += 64) {
    for (int i = tid; i < 4096; i += 512) {
      int d = i >> 6, l = i & 63;
      sX[d * 65 + l] = (Xb[(size_t)d * L + lt + l] - smu[d]) * sinv[d];
    }
    __syncthreads();
    {
      int k = tid >> 6, l = tid & 63;   // 512 items exactly
      float aq = 0.f, ak = 0.f, av = 0.f;
      for (int d = 0; d < 64; ++d) {
        float x = sX[d * 65 + l];
        aq += swq[k * 64 + d] * x;
        ak += swk[k * 64 + d] * x;
        av += swv[k * 64 + d] * x;
      }
      sQ[k * L + lt + l] = aq; sK8[k * L + lt + l] = ak; sV[k * L + lt + l] = av;
    }
    __syncthreads();
  }
  const float scale = 0.35355339059327373f;  // 1/sqrt(8)
  int m = tid & 255, half = tid >> 8;
  int L2 = L >> 1;
  float mx = -1e30f, sum = 0.f, acc[8];
#pragma unroll
  for (int v = 0; v < 8; ++v) acc[v] = 0.f;
  if (m < L) {
    float kc[8];
#pragma unroll
    for (int k = 0; k < 8; ++k) kc[k] = sK8[k * L + m];
    int l0 = half * L2, l1 = l0 + L2;
    for (int l = l0; l < l1; ++l) {
      float s = 0.f;
#pragma unroll
      for (int k = 0; k < 8; ++k) s += sQ[k * L + l] * kc[k];
      s *= scale;
      if (s <= mx) {
        float p = __expf(s - mx);
        sum += p;
#pragma unroll
        for (int v = 0; v < 8; ++v) acc[v] += p * sV[v * L + l];
      } else {
        float corr = __expf(mx - s);
        sum = sum * corr + 1.f;
#pragma unroll
        for (int v = 0; v < 8; ++v) acc[v] = acc[v] * corr + sV[v * L + l];
        mx = s;
      }
    }
  }
  // partials: pmx=swq, psum=swk, pacc=sX (all dead after QKV phase)
  swq[tid] = mx;
  swk[tid] = sum;
  float* pacc = sX;
#pragma unroll
  for (int v = 0; v < 8; ++v) pacc[tid * 8 + v] = acc[v];
  __syncthreads();
  if (half == 0 && m < L) {
    float m0 = swq[m], m1 = swq[256 + m];
    float mT = fmaxf(m0, m1);
    float c0 = __expf(m0 - mT), c1 = __expf(m1 - mT);
    float s = swk[m] * c0 + swk[256 + m] * c1;
    float is = 1.f / s;
#pragma unroll
    for (int v = 0; v < 8; ++v) {
      float a = pacc[m * 8 + v] * c0 + pacc[(256 + m) * 8 + v] * c1;
      hc[((size_t)b * 64 + h * 8 + v) * L + m] = a * is;
    }
  }
}

// ---- merged C+Q char embed: register-staged taps + hoisted pwT -----------
__global__ __launch_bounds__(256) void k_charembed(
    const int* __restrict__ cidC, const int* __restrict__ cidQ,
    const float* __restrict__ ctab, const float* __restrict__ dwT,
    const float* __restrict__ db, const float* __restrict__ pwT,
    const float* __restrict__ pb,
    float* __restrict__ outC, float* __restrict__ outQ) {
  int nx = blockIdx.x, b = blockIdx.y;
  const int* cid; float* out; int Ln, n;
  if (nx < NN) { cid = cidC; out = outC; Ln = NN; n = nx; }
  else         { cid = cidQ; out = outQ; Ln = MQ; n = nx - NN; }
  __shared__ float dwo[16 * 200];   // [cn][ce]
  __shared__ int sid[5][16];
  __shared__ float red[256];
  int tid = threadIdx.x;
  if (tid < 80) {
    int kn = tid / 16, cn = tid % 16;
    int nn = n + kn - 2;
    sid[kn][cn] = (nn >= 0 && nn < Ln) ? cid[((size_t)b * Ln + nn) * 16 + cn] : -1;
  }
  __syncthreads();
  for (int i = tid; i < 16 * 200; i += 256) {
    int cn = i / 200, ce = i % 200;
    float r[25];
#pragma unroll
    for (int kn = 0; kn < 5; ++kn) {
#pragma unroll
      for (int kc = 0; kc < 5; ++kc) {
        int cc = cn + kc - 2;
        int id = (cc >= 0 && cc < 16) ? sid[kn][cc] : -1;
        r[kn * 5 + kc] = (id >= 0) ? ctab[(size_t)id * 200 + ce] : 0.f;
      }
    }
    float acc = db[ce];
#pragma unroll
    for (int t = 0; t < 25; ++t) acc += r[t] * dwT[t * 200 + ce];
    dwo[cn * 200 + ce] = acc;
  }
  __syncthreads();
  int o = tid & 63, q = tid >> 6;
  float acc4[4];
#pragma unroll
  for (int k = 0; k < 4; ++k) acc4[k] = pb[o];
  for (int c0 = 0; c0 < 200; c0 += 8) {
    float w8[8];
#pragma unroll
    for (int j = 0; j < 8; ++j) w8[j] = pwT[(c0 + j) * 64 + o];
#pragma unroll
    for (int k = 0; k < 4; ++k) {
      const float* dr = dwo + (q + k * 4) * 200 + c0;
#pragma unroll
      for (int j = 0; j < 8; ++j) acc4[k] += w8[j] * dr[j];
    }
  }
  float mx = -1e30f;
#pragma unroll
  for (int k = 0; k < 4; ++k) mx = fmaxf(mx, acc4[k]);
  red[tid] = mx;
  __syncthreads();
  if (q == 0) {
    mx = fmaxf(fmaxf(red[o], red[64 + o]), fmaxf(red[128 + o], red[192 + o]));
    out[((size_t)b * 64 + o) * Ln + n] = fmaxf(mx, 0.f);
  }
}

// ---- merged C+Q emb conv -------------------------------------------------
__global__ void k_embconv(const float* __restrict__ chxC, const float* __restrict__ chxQ,
                          const int* __restrict__ widC, const int* __restrict__ widQ,
                          const float* __restrict__ wtab, const float* __restrict__ dw,
                          const float* __restrict__ db, const float* __restrict__ pwT,
                          const float* __restrict__ pb,
                          float* __restrict__ outC, float* __restrict__ outQ) {
  int nx = blockIdx.x, b = blockIdx.y;
  const float* chx; const int* wid; float* out; int Ln, n;
  if (nx < NN) { chx = chxC; wid = widC; out = outC; Ln = NN; n = nx; }
  else         { chx = chxQ; wid = widQ; out = outQ; Ln = MQ; n = nx - NN; }
  __shared__ float dwc[EC];
  __shared__ int sw[5];
  int tid = threadIdx.x;
  if (tid < 5) {
    int nn = n + tid - 2;
    sw[tid] = (nn >= 0 && nn < Ln) ? wid[(size_t)b * Ln + nn] : -1;
  }
  __syncthreads();
  for (int ch = tid; ch < EC; ch += 64) {
    float r[5];
#pragma unroll
    for (int k = 0; k < 5; ++k) {
      int nn = n + k - 2;
      float v = 0.f;
      if (nn >= 0 && nn < Ln) {
        if (ch < 64) v = chx[((size_t)b * 64 + ch) * Ln + nn];
        else v = wtab[(size_t)sw[k] * 300 + (ch - 64)];
      }
      r[k] = v;
    }
    float acc = db[ch];
#pragma unroll
    for (int k = 0; k < 5; ++k) acc += r[k] * dw[ch * 5 + k];
    dwc[ch] = acc;
  }
  __syncthreads();
  int o = tid;
  float acc = pb[o];
  for (int c0 = 0; c0 < EC; c0 += 4) {
    float w4[4];
#pragma unroll
    for (int j = 0; j < 4; ++j) w4[j] = pwT[(c0 + j) * 64 + o];
#pragma unroll
    for (int j = 0; j < 4; ++j) acc += w4[j] * dwc[c0 + j];
  }
  out[((size_t)b * 64 + o) * Ln + n] = acc;
}

// ---------------- merged C+Q highway --------------------------------------
__global__ void k_highway(const float* __restrict__ inxC, const float* __restrict__ inxQ,
                          const float* __restrict__ lwT, const float* __restrict__ lb,
                          const float* __restrict__ gwT, const float* __restrict__ gb,
                          float* __restrict__ outC, float* __restrict__ outQ) {
  int nx = blockIdx.x, b = blockIdx.y;
  const float* inx; float* out; int Ln, n;
  if (nx < NN) { inx = inxC; out = outC; Ln = NN; n = nx; }
  else         { inx = inxQ; out = outQ; Ln = MQ; n = nx - NN; }
  __shared__ float x[64], xn[64];
  int o = threadIdx.x;
  x[o] = inx[((size_t)b * 64 + o) * Ln + n];
  __syncthreads();
  for (int layer = 0; layer < 2; ++layer) {
    const float* lwr = lwT + layer * 4096;
    const float* gwr = gwT + layer * 4096;
    float gl = gb[layer * 64 + o], nl = lb[layer * 64 + o];
    for (int d0 = 0; d0 < 64; d0 += 8) {
      float g8[8], l8[8];
#pragma unroll
      for (int j = 0; j < 8; ++j) { g8[j] = gwr[(d0 + j) * 64 + o]; l8[j] = lwr[(d0 + j) * 64 + o]; }
#pragma unroll
      for (int j = 0; j < 8; ++j) { gl += g8[j] * x[d0 + j]; nl += l8[j] * x[d0 + j]; }
    }
    float g = 1.f / (1.f + __expf(-gl));
    float r = fmaxf(nl, 0.f);
    xn[o] = g * r + (1.f - g) * x[o];
    __syncthreads();
    x[o] = xn[o];
    __syncthreads();
  }
  out[((size_t)b * 64 + o) * Ln + n] = x[o];
}

// ---------------- context-query attention ---------------------------------
__global__ __launch_bounds__(256) void k_cqS(const float* __restrict__ C,
                                             const float* __restrict__ Q,
                                             const float* __restrict__ w,
                                             float* __restrict__ S,
                                             float* __restrict__ rmax,
                                             float* __restrict__ rsum) {
  int b = blockIdx.x, nt = blockIdx.y * 64;
  __shared__ float sQ[4096], sC[4096], ct[64], qt[64], swb[192];
  const float* Cb = C + (size_t)b * 64 * 256;
  const float* Qb = Q + (size_t)b * 4096;
  const float* wb = w + (size_t)b * 192;
  if (threadIdx.x < 192) swb[threadIdx.x] = wb[threadIdx.x];
  for (int i = threadIdx.x; i < 4096; i += 256) {
    int d = i >> 6, m = i & 63;
    sQ[i] = Qb[d * 64 + m];
    sC[i] = Cb[d * 256 + nt + m];
  }
  __syncthreads();
  if (threadIdx.x < 64) {
    int j = threadIdx.x;
    float a = 0.f, c2 = 0.f;
    for (int d = 0; d < 64; ++d) {
      a += swb[64 + d] * sC[d * 64 + j];
      c2 += swb[d] * sQ[d * 64 + j];
    }
    ct[j] = a; qt[j] = c2;
  }
  __syncthreads();
  int m = threadIdx.x & 63, wv = threadIdx.x >> 6;
  for (int it = 0; it < 16; ++it) {
    int nl = wv + it * 4;
    float acc = ct[nl] + qt[m];
    for (int d = 0; d < 64; ++d)
      acc += sC[d * 64 + nl] * swb[128 + d] * sQ[d * 64 + m];
    S[((size_t)b * 256 + nt + nl) * 64 + m] = acc;
    float mx = acc;
#pragma unroll
    for (int o = 32; o > 0; o >>= 1) mx = fmaxf(mx, __shfl_xor(mx, o));
    float p = __expf(acc - mx);
#pragma unroll
    for (int o = 32; o > 0; o >>= 1) p += __shfl_xor(p, o);
    if (m == 0) { rmax[b * 256 + nt + nl] = mx; rsum[b * 256 + nt + nl] = p; }
  }
}

__global__ void k_cqcol(const float* __restrict__ S, float* __restrict__ cmax,
                        float* __restrict__ csum) {
  int b = blockIdx.x, m = threadIdx.x;
  const float* Sb = S + (size_t)b * 256 * 64;
  float mx = -1e30f;
  for (int n = 0; n < 256; ++n) mx = fmaxf(mx, Sb[n * 64 + m]);
  float s = 0.f;
  for (int n = 0; n < 256; ++n) s += __expf(Sb[n * 64 + m] - mx);
  cmax[b * 64 + m] = mx; csum[b * 64 + m] = s;
}

__global__ __launch_bounds__(256) void k_cqA(
    const float* __restrict__ C, const float* __restrict__ Q,
    const float* __restrict__ S, const float* __restrict__ rmax,
    const float* __restrict__ rsum, float* __restrict__ Xcat) {
  int b = blockIdx.x, nt = blockIdx.y * 64;
  __shared__ float sQ[4096];
  __shared__ float sP[64 * 65];
  const float* Qb = Q + (size_t)b * 4096;
  for (int i = threadIdx.x; i < 4096; i += 256) sQ[i] = Qb[i];
  for (int i = threadIdx.x; i < 4096; i += 256) {
    int nl = i >> 6, m = i & 63;
    int n = nt + nl;
    sP[nl * 65 + m] = __expf(S[((size_t)b * 256 + n) * 64 + m] - rmax[b * 256 + n]) / rsum[b * 256 + n];
  }
  __syncthreads();
  int nl = threadIdx.x & 63, dg = threadIdx.x >> 6;
  int n = nt + nl;
  for (int j = 0; j < 16; ++j) {
    int d = dg * 16 + j;
    float acc = 0.f;
    for (int m = 0; m < 64; ++m) acc += sQ[d * 64 + m] * sP[nl * 65 + m];
    float cv = C[((size_t)b * 64 + d) * 256 + n];
    Xcat[((size_t)b * 256 + d) * 256 + n] = cv;
    Xcat[((size_t)b * 256 + 64 + d) * 256 + n] = acc;
    Xcat[((size_t)b * 256 + 128 + d) * 256 + n] = cv * acc;
  }
}

// CS2[d,m] = sum_n C[d,n] * S2[n,m]
__global__ __launch_bounds__(256) void k_cqCS2(
    const float* __restrict__ C, const float* __restrict__ S,
    const float* __restrict__ cmax, const float* __restrict__ csum,
    float* __restrict__ CS2) {
  int b = blockIdx.x;
  __shared__ float sP[4096], sC[4096];
  int m = threadIdx.x & 63, dg = threadIdx.x >> 6;
  float acc[16];
#pragma unroll
  for (int j = 0; j < 16; ++j) acc[j] = 0.f;
  for (int nt = 0; nt < 4; ++nt) {
    __syncthreads();
    for (int i = threadIdx.x; i < 4096; i += 256) {
      int nl = i >> 6, mm = i & 63;
      int n = nt * 64 + nl;
      sP[i] = __expf(S[((size_t)b * 256 + n) * 64 + mm] - cmax[b * 64 + mm]) / csum[b * 64 + mm];
      int d = i >> 6, nn = i & 63;
      sC[i] = C[((size_t)b * 64 + d) * 256 + nt * 64 + nn];
    }
    __syncthreads();
    for (int nl = 0; nl < 64; ++nl) {
      float p = sP[nl * 64 + m];
#pragma unroll
      for (int j = 0; j < 16; ++j) acc[j] += sC[(dg * 16 + j) * 64 + nl] * p;
    }
  }
  for (int j = 0; j < 16; ++j)
    CS2[((size_t)b * 64 + dg * 16 + j) * 64 + m] = acc[j];
}

// Bm[d,k] = sum_m CS2[d,m] * S1[k,m]
__global__ __launch_bounds__(256) void k_cqBm(
    const float* __restrict__ C, const float* __restrict__ CS2,
    const float* __restrict__ S, const float* __restrict__ rmax,
    const float* __restrict__ rsum, float* __restrict__ Xcat) {
  int b = blockIdx.x, kt = blockIdx.y * 64;
  __shared__ float sW[4096];
  __shared__ float sP[64 * 65];
  for (int i = threadIdx.x; i < 4096; i += 256) sW[i] = CS2[(size_t)b * 4096 + i];
  for (int i = threadIdx.x; i < 4096; i += 256) {
    int kl = i >> 6, m = i & 63;
    int k = kt + kl;
    sP[kl * 65 + m] = __expf(S[((size_t)b * 256 + k) * 64 + m] - rmax[b * 256 + k]) / rsum[b * 256 + k];
  }
  __syncthreads();
  int kl = threadIdx.x & 63, dg = threadIdx.x >> 6;
  int k = kt + kl;
  for (int j = 0; j < 16; ++j) {
    int d = dg * 16 + j;
    float acc = 0.f;
    for (int m = 0; m < 64; ++m) acc += sW[d * 64 + m] * sP[kl * 65 + m];
    float cv = C[((size_t)b * 64 + d) * 256 + k];
    Xcat[((size_t)b * 256 + 192 + d) * 256 + k] = cv * acc;
  }
}

// ---- both pointers in one launch: grid (B, 2) ----------------------------
__global__ void k_pointer2(const float* __restrict__ M0, const float* __restrict__ M1,
                           const float* __restrict__ M2, const float* __restrict__ w0,
                           const float* __restrict__ w1, float* __restrict__ out) {
  int b = blockIdx.x, sel = blockIdx.y, n = threadIdx.x;
  const float* wb = (sel ? w1 : w0) + b * 128;
  const float* Mb = sel ? M2 : M1;
  float y = 0.f;
  for (int d = 0; d < 64; ++d) {
    y += wb[d] * M0[((size_t)b * 64 + d) * 256 + n];
    y += wb[64 + d] * Mb[((size_t)b * 64 + d) * 256 + n];
  }
  __shared__ float wred[4], wsum[4];
  int lane = n & 63, wid = n >> 6;
  float mx = y;
#pragma unroll
  for (int o = 32; o > 0; o >>= 1) mx = fmaxf(mx, __shfl_xor(mx, o));
  if (lane == 0) wred[wid] = mx;
  __syncthreads();
  mx = fmaxf(fmaxf(wred[0], wred[1]), fmaxf(wred[2], wred[3]));
  float e = __expf(y - mx);
  float s = e;
#pragma unroll
  for (int o = 32; o > 0; o >>= 1) s += __shfl_xor(s, o);
  if (lane == 0) wsum[wid] = s;
  __syncthreads();
  s = wsum[0] + wsum[1] + wsum[2] + wsum[3];
  out[sel * 6144 + b * 256 + n] = e / s;
}

// ===========================================================================
extern "C" void kernel_launch(void* const* d_in, const int* in_sizes, int n_in,
                              void* d_out, int out_size, void* d_ws, size_t ws_size,
                              hipStream_t stream) {
  const float* word_table = (const float*)d_in[0];
  const float* char_table = (const float*)d_in[1];
  const float* e2dw = (const float*)d_in[2];
  const float* e2db = (const float*)d_in[3];
  const float* e2pw = (const float*)d_in[4];
  const float* e2pb = (const float*)d_in[5];
  const float* e1dw = (const float*)d_in[6];
  const float* e1db = (const float*)d_in[7];
  const float* e1pw = (const float*)d_in[8];
  const float* e1pb = (const float*)d_in[9];
  const float* hlw = (const float*)d_in[10];
  const float* hlb = (const float*)d_in[11];
  const float* hgw = (const float*)d_in[12];
  const float* hgb = (const float*)d_in[13];
  const float *enc_dw[5], *enc_pw[5], *enc_wq[5], *enc_wk[5], *enc_wv[5], *enc_wo[5], *enc_w[5];
  for (int p = 0; p < 5; ++p) {
    enc_dw[p] = (const float*)d_in[14 + 7 * p + 0];
    enc_pw[p] = (const float*)d_in[14 + 7 * p + 1];
    enc_wq[p] = (const float*)d_in[14 + 7 * p + 2];
    enc_wk[p] = (const float*)d_in[14 + 7 * p + 3];
    enc_wv[p] = (const float*)d_in[14 + 7 * p + 4];
    enc_wo[p] = (const float*)d_in[14 + 7 * p + 5];
    enc_w[p]  = (const float*)d_in[14 + 7 * p + 6];
  }
  const float* cq_w  = (const float*)d_in[49];
  const float* rs_dw = (const float*)d_in[50];
  const float* rs_pw = (const float*)d_in[51];
  const float* p_w0  = (const float*)d_in[52];
  const float* p_w1  = (const float*)d_in[53];
  const int* Cwid = (const int*)d_in[54];
  const int* Ccid = (const int*)d_in[55];
  const int* Qwid = (const int*)d_in[56];
  const int* Qcid = (const int*)d_in[57];
  float* out = (float*)d_out;

  // ---- workspace (floats), ~12.3 MB --------------------------------------
  float* ws = (float*)d_ws;
  float* postab = ws;                  // 16384
  float* U    = ws + 16384;            // 393216  (att out / fconv ping-pong)
  float* Xcat = ws + 409600;           // 1572864 ; M2 aliases; emb scratch
  float* CX   = ws + 1982464;          // 393216  ; M0 aliases
  float* Sb   = ws + 2375680;          // 393216  ; M1 aliases
  float* QX   = ws + 2768896;          // 98304
  float* CS2  = ws + 2867200;          // 98304
  float* rmax = ws + 2965504;          // 6144
  float* rsum = ws + 2971648;          // 6144
  float* cmax = ws + 2977792;          // 1536
  float* csum = ws + 2979328;          // 1536
  float* P0   = ws + 2980864;          // 12288
  float* P1   = ws + 2993152;          // 12288
  float* pwT  = ws + 3005440;          // 12800
  float* e1pwT= ws + 3018240;          // 23296
  float* hlwT = ws + 3041536;          // 8192
  float* hgwT = ws + 3049728;          // 8192
  float* dwT  = ws + 3057920;          // 5000 -> ends 3062920
  float* M0 = CX; float* M1 = Sb; float* M2 = Xcat;
  float* E1C = Xcat;              // 393216
  float* E1Q = Xcat + 393216;     // 98304
  float* E2C = Xcat + 491520;     // 393216
  float* E2Q = Xcat + 884736;     // 98304 -> 983040 < 1572864
  (void)out_size; (void)in_sizes; (void)n_in; (void)ws_size;

  auto run_enc = [&](float* X, const float* src, int L, int cnum, int K, int p, int reps) {
    int NB = B * 64 / 4;
    if (src)
      hipLaunchKernelGGL((k_posadd_stats<true>), dim3(NB), dim3(256), 0, stream, X, src, postab, P0, L);
    else
      hipLaunchKernelGGL((k_posadd_stats<false>), dim3(NB), dim3(256), 0, stream, X, (const float*)nullptr, postab, P0, L);
    for (int rep = 0; rep < reps; ++rep) {
      float* pin = P0; float* pout = P1;
      float* Xi = X; float* Xo = U;     // ping-pong (cnum even -> ends in X)
      for (int i = 0; i < cnum; ++i) {
        if (K == 7)
          hipLaunchKernelGGL((k_fconv<7>), dim3(B, L / 64), dim3(512), 0, stream,
                             (const float*)Xi, Xo, enc_dw[p] + i * 64 * 7,
                             enc_pw[p] + (size_t)i * 4096, pin, pout, L);
        else
          hipLaunchKernelGGL((k_fconv<5>), dim3(B, L / 64), dim3(512), 0, stream,
                             (const float*)Xi, Xo, enc_dw[p] + i * 64 * 5,
                             enc_pw[p] + (size_t)i * 4096, pin, pout, L);
        { float* t = pin; pin = pout; pout = t; }
        { float* t = Xi; Xi = Xo; Xo = t; }
      }
      k_att<<<dim3(HH, B), 512, 0, stream>>>(X, pin, enc_wq[p], enc_wk[p], enc_wv[p], U, L);
      hipLaunchKernelGGL((k_matmul2<false, false, true, false>), dim3(B, L / 64), dim3(512), 0, stream,
                         U, enc_wo[p], (const float*)X, X, (const float*)nullptr, pout,
                         (const float*)nullptr, L);
      if (rep + 1 < reps)
        hipLaunchKernelGGL((k_matmul2<true, true, true, true>), dim3(B, L / 64), dim3(512), 0, stream,
                           X, enc_w[p], (const float*)X, X, pout, P0, (const float*)postab, L);
      else
        hipLaunchKernelGGL((k_matmul2<true, true, false, false>), dim3(B, L / 64), dim3(512), 0, stream,
                           X, enc_w[p], (const float*)X, X, pout, (float*)nullptr,
                           (const float*)nullptr, L);
    }
  };

  k_postab<<<64, 256, 0, stream>>>(postab);
  k_wT<<<225, 256, 0, stream>>>(e2pw, e1pw, hlw, hgw, e2dw, pwT, e1pwT, hlwT, hgwT, dwT);
  // ---- embeddings (C and Q merged per stage) ----
  k_charembed<<<dim3(NN + MQ, B), 256, 0, stream>>>(Ccid, Qcid, char_table, dwT, e2db, pwT, e2pb, E1C, E1Q);
  k_embconv<<<dim3(NN + MQ, B), 64, 0, stream>>>(E1C, E1Q, Cwid, Qwid, word_table, e1dw, e1db, e1pwT, e1pb, E2C, E2Q);
  k_highway<<<dim3(NN + MQ, B), 64, 0, stream>>>(E2C, E2Q, hlwT, hlb, hgwT, hgb, CX, QX);
  // ---- embedding encoders ----
  run_enc(CX, nullptr, 256, 4, 7, 0, 1);
  run_enc(QX, nullptr, 64, 4, 7, 1, 1);
  // ---- context-query attention ----
  k_cqS<<<dim3(B, 4), 256, 0, stream>>>(CX, QX, cq_w, Sb, rmax, rsum);
  k_cqcol<<<B, 64, 0, stream>>>(Sb, cmax, csum);
  k_cqA<<<dim3(B, 4), 256, 0, stream>>>(CX, QX, Sb, rmax, rsum, Xcat);
  k_cqCS2<<<B, 256, 0, stream>>>(CX, Sb, cmax, csum, CS2);
  k_cqBm<<<dim3(B, 4), 256, 0, stream>>>(CX, CS2, Sb, rmax, rsum, Xcat);
  // ---- resize -> M0 ----
  k_resize<<<dim3(B, 4), 256, 0, stream>>>(Xcat, rs_dw, rs_pw, M0);
  // ---- model encoders ----
  run_enc(M0, nullptr, 256, 2, 5, 2, 7);
  run_enc(M1, M0, 256, 2, 5, 3, 7);
  run_enc(M2, M1, 256, 2, 5, 4, 7);
  // ---- pointers ----
  k_pointer2<<<dim3(B, 2), 256, 0, stream>>>(M0, M1, M2, p_w0, p_w1, out);
}

// Round 20
// 2430.929 us; speedup vs baseline: 1.5810x; 1.0463x over previous
//
#include <hip/hip_runtime.h>
#include <math.h>

constexpr int B = 24, HH = 8;
constexpr int NN = 256, MQ = 64;
constexpr int EC = 364;

#define PI_2 1.5707963267948966f

// stats partials layout: parts[row][4][2], row = b*64+d
__device__ __forceinline__ void combine_stats(const float* __restrict__ parts,
                                              int row, int NT, float Lf,
                                              float& mu, float& inv) {
  float s = 0.f, q = 0.f;
  for (int t = 0; t < NT; ++t) {
    s += parts[((size_t)row * 4 + t) * 2];
    q += parts[((size_t)row * 4 + t) * 2 + 1];
  }
  mu = s / Lf;
  float var = (q - s * mu) / (Lf - 1.f);
  if (var < 0.f) var = 0.f;
  inv = 1.f / (sqrtf(var) + 1e-6f);
}

// ---- merged prologue: postab + weight transposes -------------------------
__global__ void k_prep(float* __restrict__ tab,
                       const float* __restrict__ e2pw, const float* __restrict__ e1pw,
                       const float* __restrict__ hlw, const float* __restrict__ hgw,
                       const float* __restrict__ e2dw,
                       float* __restrict__ pwT, float* __restrict__ e1pwT,
                       float* __restrict__ hlwT, float* __restrict__ hgwT,
                       float* __restrict__ dwT) {
  int blk = blockIdx.x;
  if (blk < 64) {
    int d = blk, l = threadIdx.x;
    float fr = ((d & 1) == 0) ? powf(10000.f, -(float)d / 64.f)
                              : -powf(10000.f, -(float)(d - 1) / 64.f);
    float ph = (d & 1) ? PI_2 : 0.f;
    tab[d * 256 + l] = sinf(sinf((float)l * fr + ph));
    return;
  }
  int i = (blk - 64) * 256 + threadIdx.x;
  if (i < 12800) {
    int ce = i >> 6, o = i & 63;
    pwT[i] = e2pw[o * 200 + ce];
    return;
  }
  i -= 12800;
  if (i < 23296) {
    int c = i >> 6, o = i & 63;
    e1pwT[i] = e1pw[o * EC + c];
    return;
  }
  i -= 23296;
  if (i < 8192) {
    int layer = i >> 12, rem = i & 4095;
    int d = rem >> 6, o = rem & 63;
    hlwT[i] = hlw[layer * 4096 + o * 64 + d];
    return;
  }
  i -= 8192;
  if (i < 8192) {
    int layer = i >> 12, rem = i & 4095;
    int d = rem >> 6, o = rem & 63;
    hgwT[i] = hgw[layer * 4096 + o * 64 + d];
    return;
  }
  i -= 8192;
  if (i < 5000) {
    int t = i / 200, ce = i % 200;
    dwT[i] = e2dw[ce * 25 + t];
  }
}

// ---- posadd + stats; grid y: 0=C(L=256), 1=Q(L=64) -----------------------
template<bool COPY>
__global__ void k_posadd_stats(float* __restrict__ XC, const float* __restrict__ srcC,
                               float* __restrict__ XQ, const float* __restrict__ tab,
                               float* __restrict__ partsC, float* __restrict__ partsQ) {
  int which = blockIdx.y;
  float* X = which ? XQ : XC;
  float* parts = which ? partsQ : partsC;
  int L = which ? 64 : 256;
  int row = blockIdx.x * 4 + (threadIdx.x >> 6);
  int lane = threadIdx.x & 63;
  int d = row & 63;
  float* xr = X + (size_t)row * L;
  const float* sr = (COPY && !which) ? (srcC + (size_t)row * L) : xr;
  int NT = L >> 6;
  for (int t = 0; t < NT; ++t) {
    int l = t * 64 + lane;
    float v = sr[l] + tab[d * 256 + l];
    xr[l] = v;
    float s = v, q = v * v;
#pragma unroll
    for (int o = 32; o > 0; o >>= 1) { s += __shfl_xor(s, o); q += __shfl_xor(q, o); }
    if (lane == 0) {
      parts[((size_t)row * 4 + t) * 2] = s;
      parts[((size_t)row * 4 + t) * 2 + 1] = q;
    }
  }
}

// ---- fused conv block; grid y: 0..3 = C tiles, 4 = Q ---------------------
template<int K>
__global__ __launch_bounds__(512) void k_fconv(
    const float* __restrict__ XiC, float* __restrict__ XoC,
    const float* __restrict__ XiQ, float* __restrict__ XoQ,
    const float* __restrict__ dwC, const float* __restrict__ pwC,
    const float* __restrict__ dwQ, const float* __restrict__ pwQ,
    const float* __restrict__ pinC, float* __restrict__ poutC,
    const float* __restrict__ pinQ, float* __restrict__ poutQ) {
  constexpr int H = K / 2, SW = 64 + 2 * H;
  __shared__ float smu[64], sinv[64];
  __shared__ float sN[64 * SW];
  __shared__ float sD[64 * 65];
  __shared__ __align__(16) float sWt[4096];
  int b = blockIdx.x, t = blockIdx.y;
  const float *Xin, *dw, *pw, *pin; float *Xout, *pout; int L, tile;
  if (t < 4) { Xin = XiC; Xout = XoC; dw = dwC; pw = pwC; pin = pinC; pout = poutC; L = 256; tile = t; }
  else       { Xin = XiQ; Xout = XoQ; dw = dwQ; pw = pwQ; pin = pinQ; pout = poutQ; L = 64;  tile = 0; }
  int lt = tile * 64;
  int tid = threadIdx.x;
  int NT = L >> 6;
  if (tid < 64) combine_stats(pin, b * 64 + tid, NT, (float)L, smu[tid], sinv[tid]);
  for (int i = tid; i < 1024; i += 512)
    ((float4*)sWt)[i] = ((const float4*)pw)[i];
  const float* Xb = Xin + (size_t)b * 64 * L;
  int l = tid & 63, og = tid >> 6;
  float rres[8];
#pragma unroll
  for (int j = 0; j < 8; ++j)
    rres[j] = Xb[(size_t)(og * 8 + j) * L + lt + l];
  __syncthreads();
  for (int i = tid; i < 64 * SW; i += 512) {
    int c = i / SW, jj = i % SW;
    int gl = lt + jj - H;
    sN[i] = (gl >= 0 && gl < L) ? (Xb[(size_t)c * L + gl] - smu[c]) * sinv[c] : 0.f;
  }
  __syncthreads();
  for (int i = tid; i < 4096; i += 512) {
    int c = i >> 6, ll = i & 63;
    float acc = 0.f;
#pragma unroll
    for (int k = 0; k < K; ++k) acc += sN[c * SW + ll + k] * dw[c * K + k];
    sD[c * 65 + ll] = acc;
  }
  __syncthreads();
  float acc[8];
#pragma unroll
  for (int j = 0; j < 8; ++j) acc[j] = 0.f;
  for (int c = 0; c < 64; ++c) {
    float av = sD[c * 65 + l];
#pragma unroll
    for (int j = 0; j < 8; ++j) acc[j] += sWt[(og * 8 + j) * 64 + c] * av;
  }
  __syncthreads();
  float* Ob = Xout + (size_t)b * 64 * L;
#pragma unroll
  for (int j = 0; j < 8; ++j) {
    int o = og * 8 + j;
    float v = rres[j] + fmaxf(acc[j], 0.f);
    Ob[(size_t)o * L + lt + l] = v;
    sD[o * 65 + l] = v;
  }
  __syncthreads();
  if (tid < 64) {
    int o = tid;
    float s = 0.f, q = 0.f;
    for (int l2 = 0; l2 < 64; ++l2) { float v = sD[o * 65 + l2]; s += v; q += v * v; }
    pout[((size_t)(b * 64 + o) * 4 + tile) * 2] = s;
    pout[((size_t)(b * 64 + o) * 4 + tile) * 2 + 1] = q;
  }
}

// ---- 64x64 matmul; grid y: 0..3 = C tiles, 4 = Q -------------------------
template<bool NORM, bool RELU, bool STATS, bool ADDTAB>
__global__ __launch_bounds__(512) void k_matmul2(
    const float* __restrict__ AC, const float* __restrict__ WC,
    const float* __restrict__ resC, float* __restrict__ outC2,
    const float* __restrict__ pinC, float* __restrict__ poutC,
    const float* __restrict__ AQ, const float* __restrict__ WQ,
    const float* __restrict__ resQ, float* __restrict__ outQ2,
    const float* __restrict__ pinQ, float* __restrict__ poutQ,
    const float* __restrict__ tab) {
  __shared__ float sA[64 * 65];
  __shared__ __align__(16) float sW[4096];
  __shared__ float smu[64], sinv[64];
  int b = blockIdx.x, t = blockIdx.y;
  const float *A, *W, *res, *pin; float *outp, *pout; int L, tile;
  if (t < 4) { A = AC; W = WC; res = resC; outp = outC2; pin = pinC; pout = poutC; L = 256; tile = t; }
  else       { A = AQ; W = WQ; res = resQ; outp = outQ2; pin = pinQ; pout = poutQ; L = 64;  tile = 0; }
  int lt = tile * 64;
  int tid = threadIdx.x;
  int NT = L >> 6;
  if (NORM && tid < 64) combine_stats(pin, b * 64 + tid, NT, (float)L, smu[tid], sinv[tid]);
  const float* Wb = W + (size_t)b * 4096;
  for (int i = tid; i < 1024; i += 512)
    ((float4*)sW)[i] = ((const float4*)Wb)[i];
  int l = tid & 63, og = tid >> 6;
  float rres[8], rtab[8];
#pragma unroll
  for (int j = 0; j < 8; ++j) {
    int o = og * 8 + j;
    rres[j] = res[((size_t)b * 64 + o) * L + lt + l];
    if (ADDTAB) rtab[j] = tab[o * 256 + lt + l];
  }
  if (NORM) __syncthreads();
  const float* Ab = A + (size_t)b * 64 * L;
  for (int i = tid; i < 1024; i += 512) {
    int c = i >> 4, lq = (i & 15) * 4;
    float4 v = *(const float4*)(Ab + (size_t)c * L + lt + lq);
    if (NORM) {
      float mu = smu[c], iv = sinv[c];
      v.x = (v.x - mu) * iv; v.y = (v.y - mu) * iv;
      v.z = (v.z - mu) * iv; v.w = (v.w - mu) * iv;
    }
    sA[c * 65 + lq] = v.x; sA[c * 65 + lq + 1] = v.y;
    sA[c * 65 + lq + 2] = v.z; sA[c * 65 + lq + 3] = v.w;
  }
  __syncthreads();
  float acc[8];
#pragma unroll
  for (int j = 0; j < 8; ++j) acc[j] = 0.f;
  for (int c = 0; c < 64; ++c) {
    float av = sA[c * 65 + l];
#pragma unroll
    for (int j = 0; j < 8; ++j) acc[j] += sW[(og * 8 + j) * 64 + c] * av;
  }
  if (STATS) __syncthreads();
#pragma unroll
  for (int j = 0; j < 8; ++j) {
    int o = og * 8 + j;
    float v = acc[j];
    if (RELU) v = fmaxf(v, 0.f);
    v += rres[j];
    if (ADDTAB) v += rtab[j];
    outp[((size_t)b * 64 + o) * L + lt + l] = v;
    if (STATS) sA[o * 65 + l] = v;
  }
  if (STATS) {
    __syncthreads();
    if (tid < 64) {
      int o = tid;
      float s = 0.f, q = 0.f;
      for (int l2 = 0; l2 < 64; ++l2) { float v = sA[o * 65 + l2]; s += v; q += v * v; }
      pout[((size_t)(b * 64 + o) * 4 + tile) * 2] = s;
      pout[((size_t)(b * 64 + o) * 4 + tile) * 2 + 1] = q;
    }
  }
}

// ---- fused resize: M0[b,o,l] = sum_c pw[o,c] * dw5(Xcat)[b,c,l] ----------
__global__ __launch_bounds__(256) void k_resize(
    const float* __restrict__ Xcat, const float* __restrict__ dw,
    const float* __restrict__ pw, float* __restrict__ out) {
  __shared__ float sA[64 * 64];
  int b = blockIdx.x, lt = blockIdx.y * 64;
  int l = threadIdx.x & 63, og = threadIdx.x >> 6;
  float acc[16];
#pragma unroll
  for (int j = 0; j < 16; ++j) acc[j] = 0.f;
  for (int c0 = 0; c0 < 256; c0 += 64) {
    __syncthreads();
    for (int i = threadIdx.x; i < 4096; i += 256) {
      int c = (i >> 6) + c0, ll = (i & 63) + lt;
      const float* xr = Xcat + ((size_t)b * 256 + c) * 256;
      float a = 0.f;
#pragma unroll
      for (int k = 0; k < 5; ++k) {
        int p = ll + k - 2;
        if (p >= 0 && p < 256) a += xr[p] * dw[c * 5 + k];
      }
      sA[i] = a;
    }
    __syncthreads();
    for (int c = 0; c < 64; ++c) {
      float av = sA[c * 64 + l];
#pragma unroll
      for (int j = 0; j < 16; ++j)
        acc[j] += pw[(size_t)(og * 16 + j) * 256 + c0 + c] * av;
    }
  }
#pragma unroll
  for (int j = 0; j < 16; ++j)
    out[((size_t)b * 64 + og * 16 + j) * 256 + lt + l] = acc[j];
}

// ---- self-attention; grid y: 0..23 = C (L=256), 24..47 = Q (L=64) --------
__global__ __launch_bounds__(512) void k_att(
    const float* __restrict__ XC, const float* __restrict__ partsC,
    const float* __restrict__ wqC, const float* __restrict__ wkC,
    const float* __restrict__ wvC, float* __restrict__ hcC,
    const float* __restrict__ XQ, const float* __restrict__ partsQ,
    const float* __restrict__ wqQ, const float* __restrict__ wkQ,
    const float* __restrict__ wvQ, float* __restrict__ hcQ) {
  int h = blockIdx.x, b2 = blockIdx.y;
  const float *X, *parts, *wq, *wk, *wv; float* hc; int L, b;
  if (b2 < B) { X = XC; parts = partsC; wq = wqC; wk = wkC; wv = wvC; hc = hcC; L = 256; b = b2; }
  else        { X = XQ; parts = partsQ; wq = wqQ; wk = wkQ; wv = wvQ; hc = hcQ; L = 64;  b = b2 - B; }
  __shared__ float smu[64], sinv[64];
  __shared__ float sX[64 * 65];      // staging; reused as pacc[512][8]
  __shared__ float sQ[2048], sK8[2048], sV[2048];
  __shared__ float swq[512], swk[512], swv[512];  // later: pmx, psum
  int tid = threadIdx.x;
  int NT = L >> 6;
  if (tid < 64) combine_stats(parts, b * 64 + tid, NT, (float)L, smu[tid], sinv[tid]);
  size_t woff = (size_t)(h * B + b) * 512;
  swq[tid] = wq[woff + tid];
  swk[tid] = wk[woff + tid];
  swv[tid] = wv[woff + tid];
  __syncthreads();
  const float* Xb = X + (size_t)b * 64 * L;
  for (int lt = 0; lt < L; lt += 64) {
    for (int i = tid; i < 4096; i += 512) {
      int d = i >> 6, l = i & 63;
      sX[d * 65 + l] = (Xb[(size_t)d * L + lt + l] - smu[d]) * sinv[d];
    }
    __syncthreads();
    {
      int k = tid >> 6, l = tid & 63;
      float aq = 0.f, ak = 0.f, av = 0.f;
      for (int d = 0; d < 64; ++d) {
        float x = sX[d * 65 + l];
        aq += swq[k * 64 + d] * x;
        ak += swk[k * 64 + d] * x;
        av += swv[k * 64 + d] * x;
      }
      sQ[k * L + lt + l] = aq; sK8[k * L + lt + l] = ak; sV[k * L + lt + l] = av;
    }
    __syncthreads();
  }
  const float scale = 0.35355339059327373f;  // 1/sqrt(8)
  int m = tid & 255, half = tid >> 8;
  int L2 = L >> 1;
  float mx = -1e30f, sum = 0.f, acc[8];
#pragma unroll
  for (int v = 0; v < 8; ++v) acc[v] = 0.f;
  if (m < L) {
    float kc[8];
#pragma unroll
    for (int k = 0; k < 8; ++k) kc[k] = sK8[k * L + m];
    int l0 = half * L2, l1 = l0 + L2;
    for (int l = l0; l < l1; ++l) {
      float s = 0.f;
#pragma unroll
      for (int k = 0; k < 8; ++k) s += sQ[k * L + l] * kc[k];
      s *= scale;
      if (s <= mx) {
        float p = __expf(s - mx);
        sum += p;
#pragma unroll
        for (int v = 0; v < 8; ++v) acc[v] += p * sV[v * L + l];
      } else {
        float corr = __expf(mx - s);
        sum = sum * corr + 1.f;
#pragma unroll
        for (int v = 0; v < 8; ++v) acc[v] = acc[v] * corr + sV[v * L + l];
        mx = s;
      }
    }
  }
  swq[tid] = mx;
  swk[tid] = sum;
  float* pacc = sX;
#pragma unroll
  for (int v = 0; v < 8; ++v) pacc[tid * 8 + v] = acc[v];
  __syncthreads();
  if (half == 0 && m < L) {
    float m0 = swq[m], m1 = swq[256 + m];
    float mT = fmaxf(m0, m1);
    float c0 = __expf(m0 - mT), c1 = __expf(m1 - mT);
    float s = swk[m] * c0 + swk[256 + m] * c1;
    float is = 1.f / s;
#pragma unroll
    for (int v = 0; v < 8; ++v) {
      float a = pacc[m * 8 + v] * c0 + pacc[(256 + m) * 8 + v] * c1;
      hc[((size_t)b * 64 + h * 8 + v) * L + m] = a * is;
    }
  }
}

// ---- merged C+Q char embed: register-staged taps + hoisted pwT -----------
__global__ __launch_bounds__(256) void k_charembed(
    const int* __restrict__ cidC, const int* __restrict__ cidQ,
    const float* __restrict__ ctab, const float* __restrict__ dwT,
    const float* __restrict__ db, const float* __restrict__ pwT,
    const float* __restrict__ pb,
    float* __restrict__ outC, float* __restrict__ outQ) {
  int nx = blockIdx.x, b = blockIdx.y;
  const int* cid; float* out; int Ln, n;
  if (nx < NN) { cid = cidC; out = outC; Ln = NN; n = nx; }
  else         { cid = cidQ; out = outQ; Ln = MQ; n = nx - NN; }
  __shared__ float dwo[16 * 200];   // [cn][ce]
  __shared__ int sid[5][16];
  __shared__ float red[256];
  int tid = threadIdx.x;
  if (tid < 80) {
    int kn = tid / 16, cn = tid % 16;
    int nn = n + kn - 2;
    sid[kn][cn] = (nn >= 0 && nn < Ln) ? cid[((size_t)b * Ln + nn) * 16 + cn] : -1;
  }
  __syncthreads();
  for (int i = tid; i < 16 * 200; i += 256) {
    int cn = i / 200, ce = i % 200;
    float r[25];
#pragma unroll
    for (int kn = 0; kn < 5; ++kn) {
#pragma unroll
      for (int kc = 0; kc < 5; ++kc) {
        int cc = cn + kc - 2;
        int id = (cc >= 0 && cc < 16) ? sid[kn][cc] : -1;
        r[kn * 5 + kc] = (id >= 0) ? ctab[(size_t)id * 200 + ce] : 0.f;
      }
    }
    float acc = db[ce];
#pragma unroll
    for (int t = 0; t < 25; ++t) acc += r[t] * dwT[t * 200 + ce];
    dwo[cn * 200 + ce] = acc;
  }
  __syncthreads();
  int o = tid & 63, q = tid >> 6;
  float acc4[4];
#pragma unroll
  for (int k = 0; k < 4; ++k) acc4[k] = pb[o];
  for (int c0 = 0; c0 < 200; c0 += 8) {
    float w8[8];
#pragma unroll
    for (int j = 0; j < 8; ++j) w8[j] = pwT[(c0 + j) * 64 + o];
#pragma unroll
    for (int k = 0; k < 4; ++k) {
      const float* dr = dwo + (q + k * 4) * 200 + c0;
#pragma unroll
      for (int j = 0; j < 8; ++j) acc4[k] += w8[j] * dr[j];
    }
  }
  float mx = -1e30f;
#pragma unroll
  for (int k = 0; k < 4; ++k) mx = fmaxf(mx, acc4[k]);
  red[tid] = mx;
  __syncthreads();
  if (q == 0) {
    mx = fmaxf(fmaxf(red[o], red[64 + o]), fmaxf(red[128 + o], red[192 + o]));
    out[((size_t)b * 64 + o) * Ln + n] = fmaxf(mx, 0.f);
  }
}

// ---- merged C+Q embconv + highway (fused, no E2 round-trip) --------------
__global__ void k_embhw(const float* __restrict__ chxC, const float* __restrict__ chxQ,
                        const int* __restrict__ widC, const int* __restrict__ widQ,
                        const float* __restrict__ wtab, const float* __restrict__ dw,
                        const float* __restrict__ db, const float* __restrict__ pwT,
                        const float* __restrict__ pb,
                        const float* __restrict__ lwT, const float* __restrict__ lb,
                        const float* __restrict__ gwT, const float* __restrict__ gb,
                        float* __restrict__ outC, float* __restrict__ outQ) {
  int nx = blockIdx.x, b = blockIdx.y;
  const float* chx; const int* wid; float* out; int Ln, n;
  if (nx < NN) { chx = chxC; wid = widC; out = outC; Ln = NN; n = nx; }
  else         { chx = chxQ; wid = widQ; out = outQ; Ln = MQ; n = nx - NN; }
  __shared__ float dwc[EC];
  __shared__ int sw[5];
  __shared__ float x[64], xn[64];
  int tid = threadIdx.x;
  if (tid < 5) {
    int nn = n + tid - 2;
    sw[tid] = (nn >= 0 && nn < Ln) ? wid[(size_t)b * Ln + nn] : -1;
  }
  __syncthreads();
  for (int ch = tid; ch < EC; ch += 64) {
    float r[5];
#pragma unroll
    for (int k = 0; k < 5; ++k) {
      int nn = n + k - 2;
      float v = 0.f;
      if (nn >= 0 && nn < Ln) {
        if (ch < 64) v = chx[((size_t)b * 64 + ch) * Ln + nn];
        else v = wtab[(size_t)sw[k] * 300 + (ch - 64)];
      }
      r[k] = v;
    }
    float acc = db[ch];
#pragma unroll
    for (int k = 0; k < 5; ++k) acc += r[k] * dw[ch * 5 + k];
    dwc[ch] = acc;
  }
  __syncthreads();
  int o = tid;
  float acc = pb[o];
  for (int c0 = 0; c0 < EC; c0 += 4) {
    float w4[4];
#pragma unroll
    for (int j = 0; j < 4; ++j) w4[j] = pwT[(c0 + j) * 64 + o];
#pragma unroll
    for (int j = 0; j < 4; ++j) acc += w4[j] * dwc[c0 + j];
  }
  // highway (in-block, bit-identical to separate kernel)
  x[o] = acc;
  __syncthreads();
  for (int layer = 0; layer < 2; ++layer) {
    const float* lwr = lwT + layer * 4096;
    const float* gwr = gwT + layer * 4096;
    float gl = gb[layer * 64 + o], nl = lb[layer * 64 + o];
    for (int d0 = 0; d0 < 64; d0 += 8) {
      float g8[8], l8[8];
#pragma unroll
      for (int j = 0; j < 8; ++j) { g8[j] = gwr[(d0 + j) * 64 + o]; l8[j] = lwr[(d0 + j) * 64 + o]; }
#pragma unroll
      for (int j = 0; j < 8; ++j) { gl += g8[j] * x[d0 + j]; nl += l8[j] * x[d0 + j]; }
    }
    float g = 1.f / (1.f + __expf(-gl));
    float r = fmaxf(nl, 0.f);
    xn[o] = g * r + (1.f - g) * x[o];
    __syncthreads();
    x[o] = xn[o];
    __syncthreads();
  }
  out[((size_t)b * 64 + o) * Ln + n] = x[o];
}

// ---------------- context-query attention ---------------------------------
__global__ __launch_bounds__(256) void k_cqS(const float* __restrict__ C,
                                             const float* __restrict__ Q,
                                             const float* __restrict__ w,
                                             float* __restrict__ S,
                                             float* __restrict__ rmax,
                                             float* __restrict__ rsum) {
  int b = blockIdx.x, nt = blockIdx.y * 64;
  __shared__ float sQ[4096], sC[4096], ct[64], qt[64], swb[192];
  const float* Cb = C + (size_t)b * 64 * 256;
  const float* Qb = Q + (size_t)b * 4096;
  const float* wb = w + (size_t)b * 192;
  if (threadIdx.x < 192) swb[threadIdx.x] = wb[threadIdx.x];
  for (int i = threadIdx.x; i < 4096; i += 256) {
    int d = i >> 6, m = i & 63;
    sQ[i] = Qb[d * 64 + m];
    sC[i] = Cb[d * 256 + nt + m];
  }
  __syncthreads();
  if (threadIdx.x < 64) {
    int j = threadIdx.x;
    float a = 0.f, c2 = 0.f;
    for (int d = 0; d < 64; ++d) {
      a += swb[64 + d] * sC[d * 64 + j];
      c2 += swb[d] * sQ[d * 64 + j];
    }
    ct[j] = a; qt[j] = c2;
  }
  __syncthreads();
  int m = threadIdx.x & 63, wv = threadIdx.x >> 6;
  for (int it = 0; it < 16; ++it) {
    int nl = wv + it * 4;
    float acc = ct[nl] + qt[m];
    for (int d = 0; d < 64; ++d)
      acc += sC[d * 64 + nl] * swb[128 + d] * sQ[d * 64 + m];
    S[((size_t)b * 256 + nt + nl) * 64 + m] = acc;
    float mx = acc;
#pragma unroll
    for (int o = 32; o > 0; o >>= 1) mx = fmaxf(mx, __shfl_xor(mx, o));
    float p = __expf(acc - mx);
#pragma unroll
    for (int o = 32; o > 0; o >>= 1) p += __shfl_xor(p, o);
    if (m == 0) { rmax[b * 256 + nt + nl] = mx; rsum[b * 256 + nt + nl] = p; }
  }
}

__global__ void k_cqcol(const float* __restrict__ S, float* __restrict__ cmax,
                        float* __restrict__ csum) {
  int b = blockIdx.x, m = threadIdx.x;
  const float* Sb = S + (size_t)b * 256 * 64;
  float mx = -1e30f;
  for (int n = 0; n < 256; ++n) mx = fmaxf(mx, Sb[n * 64 + m]);
  float s = 0.f;
  for (int n = 0; n < 256; ++n) s += __expf(Sb[n * 64 + m] - mx);
  cmax[b * 64 + m] = mx; csum[b * 64 + m] = s;
}

// ---- merged cqA (y=0..3) + cqCS2 (y=4) -----------------------------------
__global__ __launch_bounds__(256) void k_cqA_CS2(
    const float* __restrict__ C, const float* __restrict__ Q,
    const float* __restrict__ S, const float* __restrict__ rmax,
    const float* __restrict__ rsum, const float* __restrict__ cmax,
    const float* __restrict__ csum, float* __restrict__ Xcat,
    float* __restrict__ CS2) {
  __shared__ float sh[8256];
  int b = blockIdx.x, t = blockIdx.y;
  int tid = threadIdx.x;
  if (t < 4) {
    // cqA: sQ = sh[0..4095], sP = sh[4096..] stride 65
    float* sQ = sh; float* sP = sh + 4096;
    int nt = t * 64;
    const float* Qb = Q + (size_t)b * 4096;
    for (int i = tid; i < 4096; i += 256) sQ[i] = Qb[i];
    for (int i = tid; i < 4096; i += 256) {
      int nl = i >> 6, m = i & 63;
      int n = nt + nl;
      sP[nl * 65 + m] = __expf(S[((size_t)b * 256 + n) * 64 + m] - rmax[b * 256 + n]) / rsum[b * 256 + n];
    }
    __syncthreads();
    int nl = tid & 63, dg = tid >> 6;
    int n = nt + nl;
    for (int j = 0; j < 16; ++j) {
      int d = dg * 16 + j;
      float acc = 0.f;
      for (int m = 0; m < 64; ++m) acc += sQ[d * 64 + m] * sP[nl * 65 + m];
      float cv = C[((size_t)b * 64 + d) * 256 + n];
      Xcat[((size_t)b * 256 + d) * 256 + n] = cv;
      Xcat[((size_t)b * 256 + 64 + d) * 256 + n] = acc;
      Xcat[((size_t)b * 256 + 128 + d) * 256 + n] = cv * acc;
    }
  } else {
    // cqCS2: sP = sh[0..4095], sC = sh[4096..8191]
    float* sP = sh; float* sC = sh + 4096;
    int m = tid & 63, dg = tid >> 6;
    float acc[16];
#pragma unroll
    for (int j = 0; j < 16; ++j) acc[j] = 0.f;
    for (int nt = 0; nt < 4; ++nt) {
      __syncthreads();
      for (int i = tid; i < 4096; i += 256) {
        int nl = i >> 6, mm = i & 63;
        int n = nt * 64 + nl;
        sP[i] = __expf(S[((size_t)b * 256 + n) * 64 + mm] - cmax[b * 64 + mm]) / csum[b * 64 + mm];
        int d = i >> 6, nn = i & 63;
        sC[i] = C[((size_t)b * 64 + d) * 256 + nt * 64 + nn];
      }
      __syncthreads();
      for (int nl = 0; nl < 64; ++nl) {
        float p = sP[nl * 64 + m];
#pragma unroll
        for (int j = 0; j < 16; ++j) acc[j] += sC[(dg * 16 + j) * 64 + nl] * p;
      }
    }
    for (int j = 0; j < 16; ++j)
      CS2[((size_t)b * 64 + dg * 16 + j) * 64 + m] = acc[j];
  }
}

// Bm[d,k] = sum_m CS2[d,m] * S1[k,m]
__global__ __launch_bounds__(256) void k_cqBm(
    const float* __restrict__ C, const float* __restrict__ CS2,
    const float* __restrict__ S, const float* __restrict__ rmax,
    const float* __restrict__ rsum, float* __restrict__ Xcat) {
  int b = blockIdx.x, kt = blockIdx.y * 64;
  __shared__ float sW[4096];
  __shared__ float sP[64 * 65];
  for (int i = threadIdx.x; i < 4096; i += 256) sW[i] = CS2[(size_t)b * 4096 + i];
  for (int i = threadIdx.x; i < 4096; i += 256) {
    int kl = i >> 6, m = i & 63;
    int k = kt + kl;
    sP[kl * 65 + m] = __expf(S[((size_t)b * 256 + k) * 64 + m] - rmax[b * 256 + k]) / rsum[b * 256 + k];
  }
  __syncthreads();
  int kl = threadIdx.x & 63, dg = threadIdx.x >> 6;
  int k = kt + kl;
  for (int j = 0; j < 16; ++j) {
    int d = dg * 16 + j;
    float acc = 0.f;
    for (int m = 0; m < 64; ++m) acc += sW[d * 64 + m] * sP[kl * 65 + m];
    float cv = C[((size_t)b * 64 + d) * 256 + k];
    Xcat[((size_t)b * 256 + 192 + d) * 256 + k] = cv * acc;
  }
}

// ---- both pointers in one launch: grid (B, 2) ----------------------------
__global__ void k_pointer2(const float* __restrict__ M0, const float* __restrict__ M1,
                           const float* __restrict__ M2, const float* __restrict__ w0,
                           const float* __restrict__ w1, float* __restrict__ out) {
  int b = blockIdx.x, sel = blockIdx.y, n = threadIdx.x;
  const float* wb = (sel ? w1 : w0) + b * 128;
  const float* Mb = sel ? M2 : M1;
  float y = 0.f;
  for (int d = 0; d < 64; ++d) {
    y += wb[d] * M0[((size_t)b * 64 + d) * 256 + n];
    y += wb[64 + d] * Mb[((size_t)b * 64 + d) * 256 + n];
  }
  __shared__ float wred[4], wsum[4];
  int lane = n & 63, wid = n >> 6;
  float mx = y;
#pragma unroll
  for (int o = 32; o > 0; o >>= 1) mx = fmaxf(mx, __shfl_xor(mx, o));
  if (lane == 0) wred[wid] = mx;
  __syncthreads();
  mx = fmaxf(fmaxf(wred[0], wred[1]), fmaxf(wred[2], wred[3]));
  float e = __expf(y - mx);
  float s = e;
#pragma unroll
  for (int o = 32; o > 0; o >>= 1) s += __shfl_xor(s, o);
  if (lane == 0) wsum[wid] = s;
  __syncthreads();
  s = wsum[0] + wsum[1] + wsum[2] + wsum[3];
  out[sel * 6144 + b * 256 + n] = e / s;
}

// ===========================================================================
extern "C" void kernel_launch(void* const* d_in, const int* in_sizes, int n_in,
                              void* d_out, int out_size, void* d_ws, size_t ws_size,
                              hipStream_t stream) {
  const float* word_table = (const float*)d_in[0];
  const float* char_table = (const float*)d_in[1];
  const float* e2dw = (const float*)d_in[2];
  const float* e2db = (const float*)d_in[3];
  const float* e2pw = (const float*)d_in[4];
  const float* e2pb = (const float*)d_in[5];
  const float* e1dw = (const float*)d_in[6];
  const float* e1db = (const float*)d_in[7];
  const float* e1pw = (const float*)d_in[8];
  const float* e1pb = (const float*)d_in[9];
  const float* hlw = (const float*)d_in[10];
  const float* hlb = (const float*)d_in[11];
  const float* hgw = (const float*)d_in[12];
  const float* hgb = (const float*)d_in[13];
  const float *enc_dw[5], *enc_pw[5], *enc_wq[5], *enc_wk[5], *enc_wv[5], *enc_wo[5], *enc_w[5];
  for (int p = 0; p < 5; ++p) {
    enc_dw[p] = (const float*)d_in[14 + 7 * p + 0];
    enc_pw[p] = (const float*)d_in[14 + 7 * p + 1];
    enc_wq[p] = (const float*)d_in[14 + 7 * p + 2];
    enc_wk[p] = (const float*)d_in[14 + 7 * p + 3];
    enc_wv[p] = (const float*)d_in[14 + 7 * p + 4];
    enc_wo[p] = (const float*)d_in[14 + 7 * p + 5];
    enc_w[p]  = (const float*)d_in[14 + 7 * p + 6];
  }
  const float* cq_w  = (const float*)d_in[49];
  const float* rs_dw = (const float*)d_in[50];
  const float* rs_pw = (const float*)d_in[51];
  const float* p_w0  = (const float*)d_in[52];
  const float* p_w1  = (const float*)d_in[53];
  const int* Cwid = (const int*)d_in[54];
  const int* Ccid = (const int*)d_in[55];
  const int* Qwid = (const int*)d_in[56];
  const int* Qcid = (const int*)d_in[57];
  float* out = (float*)d_out;

  // ---- workspace (floats), ~12.75 MB -------------------------------------
  float* ws = (float*)d_ws;
  float* postab = ws;                  // 16384
  float* U    = ws + 16384;            // 393216  (C att out / fconv ping-pong)
  float* Xcat = ws + 409600;           // 1572864 ; M2 aliases; emb scratch
  float* CX   = ws + 1982464;          // 393216  ; M0 aliases
  float* Sb   = ws + 2375680;          // 393216  ; M1 aliases
  float* QX   = ws + 2768896;          // 98304
  float* CS2  = ws + 2867200;          // 98304
  float* rmax = ws + 2965504;          // 6144
  float* rsum = ws + 2971648;          // 6144
  float* cmax = ws + 2977792;          // 1536
  float* csum = ws + 2979328;          // 1536
  float* P0   = ws + 2980864;          // 12288
  float* P1   = ws + 2993152;          // 12288
  float* pwT  = ws + 3005440;          // 12800
  float* e1pwT= ws + 3018240;          // 23296
  float* hlwT = ws + 3041536;          // 8192
  float* hgwT = ws + 3049728;          // 8192
  float* dwT  = ws + 3057920;          // 5000
  float* P0Q  = ws + 3062920;          // 12288
  float* P1Q  = ws + 3075208;          // 12288
  float* UQ   = ws + 3087496;          // 98304 -> ends 3185800
  float* M0 = CX; float* M1 = Sb; float* M2 = Xcat;
  float* E1C = Xcat;              // 393216
  float* E1Q = Xcat + 393216;     // 98304
  (void)out_size; (void)in_sizes; (void)n_in; (void)ws_size;

  // model-stack encoder (C-path only): grid y = 4 tiles
  auto run_enc = [&](float* X, const float* src, int p, int reps) {
    if (src)
      hipLaunchKernelGGL((k_posadd_stats<true>), dim3(384, 1), dim3(256), 0, stream,
                         X, src, (float*)nullptr, postab, P0, (float*)nullptr);
    else
      hipLaunchKernelGGL((k_posadd_stats<false>), dim3(384, 1), dim3(256), 0, stream,
                         X, (const float*)nullptr, (float*)nullptr, postab, P0, (float*)nullptr);
    for (int rep = 0; rep < reps; ++rep) {
      float* pin = P0; float* pout = P1;
      float* Xi = X; float* Xo = U;
      for (int i = 0; i < 2; ++i) {
        hipLaunchKernelGGL((k_fconv<5>), dim3(B, 4), dim3(512), 0, stream,
                           (const float*)Xi, Xo, (const float*)nullptr, (float*)nullptr,
                           enc_dw[p] + i * 64 * 5, enc_pw[p] + (size_t)i * 4096,
                           (const float*)nullptr, (const float*)nullptr,
                           pin, pout, (const float*)nullptr, (float*)nullptr);
        { float* t = pin; pin = pout; pout = t; }
        { float* t = Xi; Xi = Xo; Xo = t; }
      }
      k_att<<<dim3(HH, B), 512, 0, stream>>>(X, pin, enc_wq[p], enc_wk[p], enc_wv[p], U,
                                             (const float*)nullptr, (const float*)nullptr,
                                             (const float*)nullptr, (const float*)nullptr,
                                             (const float*)nullptr, (float*)nullptr);
      hipLaunchKernelGGL((k_matmul2<false, false, true, false>), dim3(B, 4), dim3(512), 0, stream,
                         (const float*)U, enc_wo[p], (const float*)X, X, (const float*)nullptr, pout,
                         (const float*)nullptr, (const float*)nullptr, (const float*)nullptr,
                         (float*)nullptr, (const float*)nullptr, (float*)nullptr,
                         (const float*)nullptr);
      if (rep + 1 < reps)
        hipLaunchKernelGGL((k_matmul2<true, true, true, true>), dim3(B, 4), dim3(512), 0, stream,
                           (const float*)X, enc_w[p], (const float*)X, X, pout, P0,
                           (const float*)nullptr, (const float*)nullptr, (const float*)nullptr,
                           (float*)nullptr, (const float*)nullptr, (float*)nullptr,
                           (const float*)postab);
      else
        hipLaunchKernelGGL((k_matmul2<true, true, false, false>), dim3(B, 4), dim3(512), 0, stream,
                           (const float*)X, enc_w[p], (const float*)X, X, pout, (float*)nullptr,
                           (const float*)nullptr, (const float*)nullptr, (const float*)nullptr,
                           (float*)nullptr, (const float*)nullptr, (float*)nullptr,
                           (const float*)nullptr);
    }
  };

  k_prep<<<289, 256, 0, stream>>>(postab, e2pw, e1pw, hlw, hgw, e2dw,
                                  pwT, e1pwT, hlwT, hgwT, dwT);
  // ---- embeddings ----
  k_charembed<<<dim3(NN + MQ, B), 256, 0, stream>>>(Ccid, Qcid, char_table, dwT, e2db, pwT, e2pb, E1C, E1Q);
  k_embhw<<<dim3(NN + MQ, B), 64, 0, stream>>>(E1C, E1Q, Cwid, Qwid, word_table, e1dw, e1db,
                                               e1pwT, e1pb, hlwT, hlb, hgwT, hgb, CX, QX);
  // ---- embedding encoders (C and Q merged; cnum=4, K=7, reps=1) ----
  {
    hipLaunchKernelGGL((k_posadd_stats<false>), dim3(384, 2), dim3(256), 0, stream,
                       CX, (const float*)nullptr, QX, postab, P0, P0Q);
    float *pinC = P0, *poutC = P1, *pinQ = P0Q, *poutQ = P1Q;
    float *XiC = CX, *XoC = U, *XiQ = QX, *XoQ = UQ;
    for (int i = 0; i < 4; ++i) {
      hipLaunchKernelGGL((k_fconv<7>), dim3(B, 5), dim3(512), 0, stream,
                         (const float*)XiC, XoC, (const float*)XiQ, XoQ,
                         enc_dw[0] + i * 64 * 7, enc_pw[0] + (size_t)i * 4096,
                         enc_dw[1] + i * 64 * 7, enc_pw[1] + (size_t)i * 4096,
                         pinC, poutC, pinQ, poutQ);
      { float* t = pinC; pinC = poutC; poutC = t; }
      { float* t = pinQ; pinQ = poutQ; poutQ = t; }
      { float* t = XiC; XiC = XoC; XoC = t; }
      { float* t = XiQ; XiQ = XoQ; XoQ = t; }
    }
    // cnum=4 even -> state in CX/QX; pinC/pinQ hold current stats
    k_att<<<dim3(HH, 2 * B), 512, 0, stream>>>(CX, pinC, enc_wq[0], enc_wk[0], enc_wv[0], U,
                                               QX, pinQ, enc_wq[1], enc_wk[1], enc_wv[1], UQ);
    hipLaunchKernelGGL((k_matmul2<false, false, true, false>), dim3(B, 5), dim3(512), 0, stream,
                       (const float*)U, enc_wo[0], (const float*)CX, CX, (const float*)nullptr, poutC,
                       (const float*)UQ, enc_wo[1], (const float*)QX, QX, (const float*)nullptr, poutQ,
                       (const float*)nullptr);
    hipLaunchKernelGGL((k_matmul2<true, true, false, false>), dim3(B, 5), dim3(512), 0, stream,
                       (const float*)CX, enc_w[0], (const float*)CX, CX, poutC, (float*)nullptr,
                       (const float*)QX, enc_w[1], (const float*)QX, QX, poutQ, (float*)nullptr,
                       (const float*)nullptr);
  }
  // ---- context-query attention ----
  k_cqS<<<dim3(B, 4), 256, 0, stream>>>(CX, QX, cq_w, Sb, rmax, rsum);
  k_cqcol<<<B, 64, 0, stream>>>(Sb, cmax, csum);
  k_cqA_CS2<<<dim3(B, 5), 256, 0, stream>>>(CX, QX, Sb, rmax, rsum, cmax, csum, Xcat, CS2);
  k_cqBm<<<dim3(B, 4), 256, 0, stream>>>(CX, CS2, Sb, rmax, rsum, Xcat);
  // ---- resize -> M0 ----
  k_resize<<<dim3(B, 4), 256, 0, stream>>>(Xcat, rs_dw, rs_pw, M0);
  // ---- model encoders ----
  run_enc(M0, nullptr, 2, 7);
  run_enc(M1, M0, 3, 7);
  run_enc(M2, M1, 4, 7);
  // ---- pointers ----
  k_pointer2<<<dim3(B, 2), 256, 0, stream>>>(M0, M1, M2, p_w0, p_w1, out);
}

// Round 21
// 2230.081 us; speedup vs baseline: 1.7234x; 1.0901x over previous
//
#include <hip/hip_runtime.h>
#include <math.h>

constexpr int B = 24, HH = 8;
constexpr int NN = 256, MQ = 64;
constexpr int EC = 364;

#define PI_2 1.5707963267948966f

// stats partials layout: parts[row][4][2], row = b*64+d
__device__ __forceinline__ void combine_stats(const float* __restrict__ parts,
                                              int row, int NT, float Lf,
                                              float& mu, float& inv) {
  float s = 0.f, q = 0.f;
  for (int t = 0; t < NT; ++t) {
    s += parts[((size_t)row * 4 + t) * 2];
    q += parts[((size_t)row * 4 + t) * 2 + 1];
  }
  mu = s / Lf;
  float var = (q - s * mu) / (Lf - 1.f);
  if (var < 0.f) var = 0.f;
  inv = 1.f / (sqrtf(var) + 1e-6f);
}

// ---- merged prologue: postab + weight transposes -------------------------
__global__ void k_prep(float* __restrict__ tab,
                       const float* __restrict__ e2pw, const float* __restrict__ e1pw,
                       const float* __restrict__ hlw, const float* __restrict__ hgw,
                       const float* __restrict__ e2dw,
                       float* __restrict__ pwT, float* __restrict__ e1pwT,
                       float* __restrict__ hlwT, float* __restrict__ hgwT,
                       float* __restrict__ dwT) {
  int blk = blockIdx.x;
  if (blk < 64) {
    int d = blk, l = threadIdx.x;
    float fr = ((d & 1) == 0) ? powf(10000.f, -(float)d / 64.f)
                              : -powf(10000.f, -(float)(d - 1) / 64.f);
    float ph = (d & 1) ? PI_2 : 0.f;
    tab[d * 256 + l] = sinf(sinf((float)l * fr + ph));
    return;
  }
  int i = (blk - 64) * 256 + threadIdx.x;
  if (i < 12800) {
    int ce = i >> 6, o = i & 63;
    pwT[i] = e2pw[o * 200 + ce];
    return;
  }
  i -= 12800;
  if (i < 23296) {
    int c = i >> 6, o = i & 63;
    e1pwT[i] = e1pw[o * EC + c];
    return;
  }
  i -= 23296;
  if (i < 8192) {
    int layer = i >> 12, rem = i & 4095;
    int d = rem >> 6, o = rem & 63;
    hlwT[i] = hlw[layer * 4096 + o * 64 + d];
    return;
  }
  i -= 8192;
  if (i < 8192) {
    int layer = i >> 12, rem = i & 4095;
    int d = rem >> 6, o = rem & 63;
    hgwT[i] = hgw[layer * 4096 + o * 64 + d];
    return;
  }
  i -= 8192;
  if (i < 5000) {
    int t = i / 200, ce = i % 200;
    dwT[i] = e2dw[ce * 25 + t];
  }
}

// ---- posadd + stats; grid y: 0=C(L=256), 1=Q(L=64) -----------------------
__global__ void k_posadd_stats(float* __restrict__ XC, float* __restrict__ XQ,
                               const float* __restrict__ tab,
                               float* __restrict__ partsC, float* __restrict__ partsQ) {
  int which = blockIdx.y;
  float* X = which ? XQ : XC;
  float* parts = which ? partsQ : partsC;
  int L = which ? 64 : 256;
  int row = blockIdx.x * 4 + (threadIdx.x >> 6);
  int lane = threadIdx.x & 63;
  int d = row & 63;
  float* xr = X + (size_t)row * L;
  int NT = L >> 6;
  for (int t = 0; t < NT; ++t) {
    int l = t * 64 + lane;
    float v = xr[l] + tab[d * 256 + l];
    xr[l] = v;
    float s = v, q = v * v;
#pragma unroll
    for (int o = 32; o > 0; o >>= 1) { s += __shfl_xor(s, o); q += __shfl_xor(q, o); }
    if (lane == 0) {
      parts[((size_t)row * 4 + t) * 2] = s;
      parts[((size_t)row * 4 + t) * 2 + 1] = q;
    }
  }
}

// ---- fused conv block; 1024 thr; grid y: 0..3 = C tiles, 4 = Q -----------
template<int K>
__global__ __launch_bounds__(1024) void k_fconv(
    const float* __restrict__ XiC, float* __restrict__ XoC,
    const float* __restrict__ XiQ, float* __restrict__ XoQ,
    const float* __restrict__ dwC, const float* __restrict__ pwC,
    const float* __restrict__ dwQ, const float* __restrict__ pwQ,
    const float* __restrict__ pinC, float* __restrict__ poutC,
    const float* __restrict__ pinQ, float* __restrict__ poutQ) {
  constexpr int H = K / 2, SW = 64 + 2 * H;
  __shared__ float smu[64], sinv[64];
  __shared__ float sN[64 * SW];
  __shared__ float sD[64 * 65];
  __shared__ __align__(16) float sWt[4096];
  int b = blockIdx.x, t = blockIdx.y;
  const float *Xin, *dw, *pw, *pin; float *Xout, *pout; int L, tile;
  if (t < 4) { Xin = XiC; Xout = XoC; dw = dwC; pw = pwC; pin = pinC; pout = poutC; L = 256; tile = t; }
  else       { Xin = XiQ; Xout = XoQ; dw = dwQ; pw = pwQ; pin = pinQ; pout = poutQ; L = 64;  tile = 0; }
  int lt = tile * 64;
  int tid = threadIdx.x;
  int NT = L >> 6;
  if (tid < 64) combine_stats(pin, b * 64 + tid, NT, (float)L, smu[tid], sinv[tid]);
  for (int i = tid; i < 1024; i += 1024)
    ((float4*)sWt)[i] = ((const float4*)pw)[i];
  const float* Xb = Xin + (size_t)b * 64 * L;
  int l = tid & 63, og = tid >> 6;   // og in 0..15
  float rres[4];
#pragma unroll
  for (int j = 0; j < 4; ++j)
    rres[j] = Xb[(size_t)(og * 4 + j) * L + lt + l];
  __syncthreads();
  for (int i = tid; i < 64 * SW; i += 1024) {
    int c = i / SW, jj = i % SW;
    int gl = lt + jj - H;
    sN[i] = (gl >= 0 && gl < L) ? (Xb[(size_t)c * L + gl] - smu[c]) * sinv[c] : 0.f;
  }
  __syncthreads();
  for (int i = tid; i < 4096; i += 1024) {
    int c = i >> 6, ll = i & 63;
    float acc = 0.f;
#pragma unroll
    for (int k = 0; k < K; ++k) acc += sN[c * SW + ll + k] * dw[c * K + k];
    sD[c * 65 + ll] = acc;
  }
  __syncthreads();
  float acc[4];
#pragma unroll
  for (int j = 0; j < 4; ++j) acc[j] = 0.f;
  for (int c = 0; c < 64; ++c) {
    float av = sD[c * 65 + l];
#pragma unroll
    for (int j = 0; j < 4; ++j) acc[j] += sWt[(og * 4 + j) * 64 + c] * av;
  }
  __syncthreads();
  float* Ob = Xout + (size_t)b * 64 * L;
#pragma unroll
  for (int j = 0; j < 4; ++j) {
    int o = og * 4 + j;
    float v = rres[j] + fmaxf(acc[j], 0.f);
    Ob[(size_t)o * L + lt + l] = v;
    sD[o * 65 + l] = v;
  }
  __syncthreads();
  if (tid < 64) {
    int o = tid;
    float s = 0.f, q = 0.f;
    for (int l2 = 0; l2 < 64; ++l2) { float v = sD[o * 65 + l2]; s += v; q += v * v; }
    pout[((size_t)(b * 64 + o) * 4 + tile) * 2] = s;
    pout[((size_t)(b * 64 + o) * 4 + tile) * 2 + 1] = q;
  }
}

// ---- 64x64 matmul; 1024 thr; grid y: 0..3 = C tiles, 4 = Q ---------------
// DUAL: outp=v (plain), outNextC=v+tab, stats over v+tab.
template<bool NORM, bool RELU, bool STATS, bool ADDTAB, bool DUAL>
__global__ __launch_bounds__(1024) void k_matmul2(
    const float* __restrict__ AC, const float* __restrict__ WC,
    const float* __restrict__ resC, float* __restrict__ outC2,
    const float* __restrict__ pinC, float* __restrict__ poutC,
    const float* __restrict__ AQ, const float* __restrict__ WQ,
    const float* __restrict__ resQ, float* __restrict__ outQ2,
    const float* __restrict__ pinQ, float* __restrict__ poutQ,
    float* __restrict__ outNextC, const float* __restrict__ tab) {
  __shared__ float sA[64 * 65];
  __shared__ __align__(16) float sW[4096];
  __shared__ float smu[64], sinv[64];
  int b = blockIdx.x, t = blockIdx.y;
  const float *A, *W, *res, *pin; float *outp, *pout; int L, tile;
  if (t < 4) { A = AC; W = WC; res = resC; outp = outC2; pin = pinC; pout = poutC; L = 256; tile = t; }
  else       { A = AQ; W = WQ; res = resQ; outp = outQ2; pin = pinQ; pout = poutQ; L = 64;  tile = 0; }
  int lt = tile * 64;
  int tid = threadIdx.x;
  int NT = L >> 6;
  if (NORM && tid < 64) combine_stats(pin, b * 64 + tid, NT, (float)L, smu[tid], sinv[tid]);
  const float* Wb = W + (size_t)b * 4096;
  for (int i = tid; i < 1024; i += 1024)
    ((float4*)sW)[i] = ((const float4*)Wb)[i];
  int l = tid & 63, og = tid >> 6;   // og in 0..15
  float rres[4], rtab[4];
#pragma unroll
  for (int j = 0; j < 4; ++j) {
    int o = og * 4 + j;
    rres[j] = res[((size_t)b * 64 + o) * L + lt + l];
    if (ADDTAB || DUAL) rtab[j] = tab[o * 256 + lt + l];
  }
  if (NORM) __syncthreads();
  const float* Ab = A + (size_t)b * 64 * L;
  for (int i = tid; i < 1024; i += 1024) {
    int c = i >> 4, lq = (i & 15) * 4;
    float4 v = *(const float4*)(Ab + (size_t)c * L + lt + lq);
    if (NORM) {
      float mu = smu[c], iv = sinv[c];
      v.x = (v.x - mu) * iv; v.y = (v.y - mu) * iv;
      v.z = (v.z - mu) * iv; v.w = (v.w - mu) * iv;
    }
    sA[c * 65 + lq] = v.x; sA[c * 65 + lq + 1] = v.y;
    sA[c * 65 + lq + 2] = v.z; sA[c * 65 + lq + 3] = v.w;
  }
  __syncthreads();
  float acc[4];
#pragma unroll
  for (int j = 0; j < 4; ++j) acc[j] = 0.f;
  for (int c = 0; c < 64; ++c) {
    float av = sA[c * 65 + l];
#pragma unroll
    for (int j = 0; j < 4; ++j) acc[j] += sW[(og * 4 + j) * 64 + c] * av;
  }
  if (STATS) __syncthreads();
#pragma unroll
  for (int j = 0; j < 4; ++j) {
    int o = og * 4 + j;
    float v = acc[j];
    if (RELU) v = fmaxf(v, 0.f);
    v += rres[j];
    if (DUAL) {
      float vn = v + rtab[j];
      outp[((size_t)b * 64 + o) * L + lt + l] = v;
      outNextC[((size_t)b * 64 + o) * L + lt + l] = vn;
      if (STATS) sA[o * 65 + l] = vn;
    } else {
      if (ADDTAB) v += rtab[j];
      outp[((size_t)b * 64 + o) * L + lt + l] = v;
      if (STATS) sA[o * 65 + l] = v;
    }
  }
  if (STATS) {
    __syncthreads();
    if (tid < 64) {
      int o = tid;
      float s = 0.f, q = 0.f;
      for (int l2 = 0; l2 < 64; ++l2) { float v = sA[o * 65 + l2]; s += v; q += v * v; }
      pout[((size_t)(b * 64 + o) * 4 + tile) * 2] = s;
      pout[((size_t)(b * 64 + o) * 4 + tile) * 2 + 1] = q;
    }
  }
}

// ---- fused resize + tab + stats: M0 = pw.dw5(Xcat) + tab -----------------
__global__ __launch_bounds__(256) void k_resize(
    const float* __restrict__ Xcat, const float* __restrict__ dw,
    const float* __restrict__ pw, const float* __restrict__ tab,
    float* __restrict__ out, float* __restrict__ parts) {
  __shared__ float sA[64 * 65];
  int b = blockIdx.x, lt = blockIdx.y * 64;
  int l = threadIdx.x & 63, og = threadIdx.x >> 6;
  float acc[16];
#pragma unroll
  for (int j = 0; j < 16; ++j) acc[j] = 0.f;
  for (int c0 = 0; c0 < 256; c0 += 64) {
    __syncthreads();
    for (int i = threadIdx.x; i < 4096; i += 256) {
      int c = (i >> 6) + c0, ll = (i & 63) + lt;
      const float* xr = Xcat + ((size_t)b * 256 + c) * 256;
      float a = 0.f;
#pragma unroll
      for (int k = 0; k < 5; ++k) {
        int p = ll + k - 2;
        if (p >= 0 && p < 256) a += xr[p] * dw[c * 5 + k];
      }
      sA[(i >> 6) * 65 + (i & 63)] = a;
    }
    __syncthreads();
    for (int c = 0; c < 64; ++c) {
      float av = sA[c * 65 + l];
#pragma unroll
      for (int j = 0; j < 16; ++j)
        acc[j] += pw[(size_t)(og * 16 + j) * 256 + c0 + c] * av;
    }
  }
  __syncthreads();
#pragma unroll
  for (int j = 0; j < 16; ++j) {
    int o = og * 16 + j;
    float v = acc[j] + tab[o * 256 + lt + l];
    out[((size_t)b * 64 + o) * 256 + lt + l] = v;
    sA[o * 65 + l] = v;
  }
  __syncthreads();
  if (threadIdx.x < 64) {
    int o = threadIdx.x;
    float s = 0.f, q = 0.f;
    for (int l2 = 0; l2 < 64; ++l2) { float v = sA[o * 65 + l2]; s += v; q += v * v; }
    parts[((size_t)(b * 64 + o) * 4 + blockIdx.y) * 2] = s;
    parts[((size_t)(b * 64 + o) * 4 + blockIdx.y) * 2 + 1] = q;
  }
}

// ---- self-attention; grid y: 0..23 = C (L=256), 24..47 = Q (L=64) --------
__global__ __launch_bounds__(512) void k_att(
    const float* __restrict__ XC, const float* __restrict__ partsC,
    const float* __restrict__ wqC, const float* __restrict__ wkC,
    const float* __restrict__ wvC, float* __restrict__ hcC,
    const float* __restrict__ XQ, const float* __restrict__ partsQ,
    const float* __restrict__ wqQ, const float* __restrict__ wkQ,
    const float* __restrict__ wvQ, float* __restrict__ hcQ) {
  int h = blockIdx.x, b2 = blockIdx.y;
  const float *X, *parts, *wq, *wk, *wv; float* hc; int L, b;
  if (b2 < B) { X = XC; parts = partsC; wq = wqC; wk = wkC; wv = wvC; hc = hcC; L = 256; b = b2; }
  else        { X = XQ; parts = partsQ; wq = wqQ; wk = wkQ; wv = wvQ; hc = hcQ; L = 64;  b = b2 - B; }
  __shared__ float smu[64], sinv[64];
  __shared__ float sX[64 * 65];
  __shared__ float sQ[2048], sK8[2048], sV[2048];
  __shared__ float swq[512], swk[512], swv[512];
  int tid = threadIdx.x;
  int NT = L >> 6;
  if (tid < 64) combine_stats(parts, b * 64 + tid, NT, (float)L, smu[tid], sinv[tid]);
  size_t woff = (size_t)(h * B + b) * 512;
  swq[tid] = wq[woff + tid];
  swk[tid] = wk[woff + tid];
  swv[tid] = wv[woff + tid];
  __syncthreads();
  const float* Xb = X + (size_t)b * 64 * L;
  for (int lt = 0; lt < L; lt += 64) {
    for (int i = tid; i < 4096; i += 512) {
      int d = i >> 6, l = i & 63;
      sX[d * 65 + l] = (Xb[(size_t)d * L + lt + l] - smu[d]) * sinv[d];
    }
    __syncthreads();
    {
      int k = tid >> 6, l = tid & 63;
      float aq = 0.f, ak = 0.f, av = 0.f;
      for (int d = 0; d < 64; ++d) {
        float x = sX[d * 65 + l];
        aq += swq[k * 64 + d] * x;
        ak += swk[k * 64 + d] * x;
        av += swv[k * 64 + d] * x;
      }
      sQ[k * L + lt + l] = aq; sK8[k * L + lt + l] = ak; sV[k * L + lt + l] = av;
    }
    __syncthreads();
  }
  const float scale = 0.35355339059327373f;  // 1/sqrt(8)
  int m = tid & 255, half = tid >> 8;
  int L2 = L >> 1;
  float mx = -1e30f, sum = 0.f, acc[8];
#pragma unroll
  for (int v = 0; v < 8; ++v) acc[v] = 0.f;
  if (m < L) {
    float kc[8];
#pragma unroll
    for (int k = 0; k < 8; ++k) kc[k] = sK8[k * L + m];
    int l0 = half * L2, l1 = l0 + L2;
    for (int l = l0; l < l1; ++l) {
      float s = 0.f;
#pragma unroll
      for (int k = 0; k < 8; ++k) s += sQ[k * L + l] * kc[k];
      s *= scale;
      if (s <= mx) {
        float p = __expf(s - mx);
        sum += p;
#pragma unroll
        for (int v = 0; v < 8; ++v) acc[v] += p * sV[v * L + l];
      } else {
        float corr = __expf(mx - s);
        sum = sum * corr + 1.f;
#pragma unroll
        for (int v = 0; v < 8; ++v) acc[v] = acc[v] * corr + sV[v * L + l];
        mx = s;
      }
    }
  }
  swq[tid] = mx;
  swk[tid] = sum;
  float* pacc = sX;
#pragma unroll
  for (int v = 0; v < 8; ++v) pacc[tid * 8 + v] = acc[v];
  __syncthreads();
  if (half == 0 && m < L) {
    float m0 = swq[m], m1 = swq[256 + m];
    float mT = fmaxf(m0, m1);
    float c0 = __expf(m0 - mT), c1 = __expf(m1 - mT);
    float s = swk[m] * c0 + swk[256 + m] * c1;
    float is = 1.f / s;
#pragma unroll
    for (int v = 0; v < 8; ++v) {
      float a = pacc[m * 8 + v] * c0 + pacc[(256 + m) * 8 + v] * c1;
      hc[((size_t)b * 64 + h * 8 + v) * L + m] = a * is;
    }
  }
}

// ---- merged C+Q char embed: register-staged taps + hoisted pwT -----------
__global__ __launch_bounds__(256) void k_charembed(
    const int* __restrict__ cidC, const int* __restrict__ cidQ,
    const float* __restrict__ ctab, const float* __restrict__ dwT,
    const float* __restrict__ db, const float* __restrict__ pwT,
    const float* __restrict__ pb,
    float* __restrict__ outC, float* __restrict__ outQ) {
  int nx = blockIdx.x, b = blockIdx.y;
  const int* cid; float* out; int Ln, n;
  if (nx < NN) { cid = cidC; out = outC; Ln = NN; n = nx; }
  else         { cid = cidQ; out = outQ; Ln = MQ; n = nx - NN; }
  __shared__ float dwo[16 * 200];
  __shared__ int sid[5][16];
  __shared__ float red[256];
  int tid = threadIdx.x;
  if (tid < 80) {
    int kn = tid / 16, cn = tid % 16;
    int nn = n + kn - 2;
    sid[kn][cn] = (nn >= 0 && nn < Ln) ? cid[((size_t)b * Ln + nn) * 16 + cn] : -1;
  }
  __syncthreads();
  for (int i = tid; i < 16 * 200; i += 256) {
    int cn = i / 200, ce = i % 200;
    float r[25];
#pragma unroll
    for (int kn = 0; kn < 5; ++kn) {
#pragma unroll
      for (int kc = 0; kc < 5; ++kc) {
        int cc = cn + kc - 2;
        int id = (cc >= 0 && cc < 16) ? sid[kn][cc] : -1;
        r[kn * 5 + kc] = (id >= 0) ? ctab[(size_t)id * 200 + ce] : 0.f;
      }
    }
    float acc = db[ce];
#pragma unroll
    for (int t = 0; t < 25; ++t) acc += r[t] * dwT[t * 200 + ce];
    dwo[cn * 200 + ce] = acc;
  }
  __syncthreads();
  int o = tid & 63, q = tid >> 6;
  float acc4[4];
#pragma unroll
  for (int k = 0; k < 4; ++k) acc4[k] = pb[o];
  for (int c0 = 0; c0 < 200; c0 += 8) {
    float w8[8];
#pragma unroll
    for (int j = 0; j < 8; ++j) w8[j] = pwT[(c0 + j) * 64 + o];
#pragma unroll
    for (int k = 0; k < 4; ++k) {
      const float* dr = dwo + (q + k * 4) * 200 + c0;
#pragma unroll
      for (int j = 0; j < 8; ++j) acc4[k] += w8[j] * dr[j];
    }
  }
  float mx = -1e30f;
#pragma unroll
  for (int k = 0; k < 4; ++k) mx = fmaxf(mx, acc4[k]);
  red[tid] = mx;
  __syncthreads();
  if (q == 0) {
    mx = fmaxf(fmaxf(red[o], red[64 + o]), fmaxf(red[128 + o], red[192 + o]));
    out[((size_t)b * 64 + o) * Ln + n] = fmaxf(mx, 0.f);
  }
}

// ---- merged C+Q embconv + highway ----------------------------------------
__global__ void k_embhw(const float* __restrict__ chxC, const float* __restrict__ chxQ,
                        const int* __restrict__ widC, const int* __restrict__ widQ,
                        const float* __restrict__ wtab, const float* __restrict__ dw,
                        const float* __restrict__ db, const float* __restrict__ pwT,
                        const float* __restrict__ pb,
                        const float* __restrict__ lwT, const float* __restrict__ lb,
                        const float* __restrict__ gwT, const float* __restrict__ gb,
                        float* __restrict__ outC, float* __restrict__ outQ) {
  int nx = blockIdx.x, b = blockIdx.y;
  const float* chx; const int* wid; float* out; int Ln, n;
  if (nx < NN) { chx = chxC; wid = widC; out = outC; Ln = NN; n = nx; }
  else         { chx = chxQ; wid = widQ; out = outQ; Ln = MQ; n = nx - NN; }
  __shared__ float dwc[EC];
  __shared__ int sw[5];
  __shared__ float x[64], xn[64];
  int tid = threadIdx.x;
  if (tid < 5) {
    int nn = n + tid - 2;
    sw[tid] = (nn >= 0 && nn < Ln) ? wid[(size_t)b * Ln + nn] : -1;
  }
  __syncthreads();
  for (int ch = tid; ch < EC; ch += 64) {
    float r[5];
#pragma unroll
    for (int k = 0; k < 5; ++k) {
      int nn = n + k - 2;
      float v = 0.f;
      if (nn >= 0 && nn < Ln) {
        if (ch < 64) v = chx[((size_t)b * 64 + ch) * Ln + nn];
        else v = wtab[(size_t)sw[k] * 300 + (ch - 64)];
      }
      r[k] = v;
    }
    float acc = db[ch];
#pragma unroll
    for (int k = 0; k < 5; ++k) acc += r[k] * dw[ch * 5 + k];
    dwc[ch] = acc;
  }
  __syncthreads();
  int o = tid;
  float acc = pb[o];
  for (int c0 = 0; c0 < EC; c0 += 4) {
    float w4[4];
#pragma unroll
    for (int j = 0; j < 4; ++j) w4[j] = pwT[(c0 + j) * 64 + o];
#pragma unroll
    for (int j = 0; j < 4; ++j) acc += w4[j] * dwc[c0 + j];
  }
  x[o] = acc;
  __syncthreads();
  for (int layer = 0; layer < 2; ++layer) {
    const float* lwr = lwT + layer * 4096;
    const float* gwr = gwT + layer * 4096;
    float gl = gb[layer * 64 + o], nl = lb[layer * 64 + o];
    for (int d0 = 0; d0 < 64; d0 += 8) {
      float g8[8], l8[8];
#pragma unroll
      for (int j = 0; j < 8; ++j) { g8[j] = gwr[(d0 + j) * 64 + o]; l8[j] = lwr[(d0 + j) * 64 + o]; }
#pragma unroll
      for (int j = 0; j < 8; ++j) { gl += g8[j] * x[d0 + j]; nl += l8[j] * x[d0 + j]; }
    }
    float g = 1.f / (1.f + __expf(-gl));
    float r = fmaxf(nl, 0.f);
    xn[o] = g * r + (1.f - g) * x[o];
    __syncthreads();
    x[o] = xn[o];
    __syncthreads();
  }
  out[((size_t)b * 64 + o) * Ln + n] = x[o];
}

// ---------------- context-query attention ---------------------------------
__global__ __launch_bounds__(256) void k_cqS(const float* __restrict__ C,
                                             const float* __restrict__ Q,
                                             const float* __restrict__ w,
                                             float* __restrict__ S,
                                             float* __restrict__ rmax,
                                             float* __restrict__ rsum) {
  int b = blockIdx.x, nt = blockIdx.y * 64;
  __shared__ float sQ[4096], sC[4096], ct[64], qt[64], swb[192];
  const float* Cb = C + (size_t)b * 64 * 256;
  const float* Qb = Q + (size_t)b * 4096;
  const float* wb = w + (size_t)b * 192;
  if (threadIdx.x < 192) swb[threadIdx.x] = wb[threadIdx.x];
  for (int i = threadIdx.x; i < 4096; i += 256) {
    int d = i >> 6, m = i & 63;
    sQ[i] = Qb[d * 64 + m];
    sC[i] = Cb[d * 256 + nt + m];
  }
  __syncthreads();
  if (threadIdx.x < 64) {
    int j = threadIdx.x;
    float a = 0.f, c2 = 0.f;
    for (int d = 0; d < 64; ++d) {
      a += swb[64 + d] * sC[d * 64 + j];
      c2 += swb[d] * sQ[d * 64 + j];
    }
    ct[j] = a; qt[j] = c2;
  }
  __syncthreads();
  int m = threadIdx.x & 63, wv = threadIdx.x >> 6;
  for (int it = 0; it < 16; ++it) {
    int nl = wv + it * 4;
    float acc = ct[nl] + qt[m];
    for (int d = 0; d < 64; ++d)
      acc += sC[d * 64 + nl] * swb[128 + d] * sQ[d * 64 + m];
    S[((size_t)b * 256 + nt + nl) * 64 + m] = acc;
    float mx = acc;
#pragma unroll
    for (int o = 32; o > 0; o >>= 1) mx = fmaxf(mx, __shfl_xor(mx, o));
    float p = __expf(acc - mx);
#pragma unroll
    for (int o = 32; o > 0; o >>= 1) p += __shfl_xor(p, o);
    if (m == 0) { rmax[b * 256 + nt + nl] = mx; rsum[b * 256 + nt + nl] = p; }
  }
}

__global__ void k_cqcol(const float* __restrict__ S, float* __restrict__ cmax,
                        float* __restrict__ csum) {
  int b = blockIdx.x, m = threadIdx.x;
  const float* Sb = S + (size_t)b * 256 * 64;
  float mx = -1e30f;
  for (int n = 0; n < 256; ++n) mx = fmaxf(mx, Sb[n * 64 + m]);
  float s = 0.f;
  for (int n = 0; n < 256; ++n) s += __expf(Sb[n * 64 + m] - mx);
  cmax[b * 64 + m] = mx; csum[b * 64 + m] = s;
}

// ---- merged cqA (y=0..3) + cqCS2 (y=4) -----------------------------------
__global__ __launch_bounds__(256) void k_cqA_CS2(
    const float* __restrict__ C, const float* __restrict__ Q,
    const float* __restrict__ S, const float* __restrict__ rmax,
    const float* __restrict__ rsum, const float* __restrict__ cmax,
    const float* __restrict__ csum, float* __restrict__ Xcat,
    float* __restrict__ CS2) {
  __shared__ float sh[8256];
  int b = blockIdx.x, t = blockIdx.y;
  int tid = threadIdx.x;
  if (t < 4) {
    float* sQ = sh; float* sP = sh + 4096;
    int nt = t * 64;
    const float* Qb = Q + (size_t)b * 4096;
    for (int i = tid; i < 4096; i += 256) sQ[i] = Qb[i];
    for (int i = tid; i < 4096; i += 256) {
      int nl = i >> 6, m = i & 63;
      int n = nt + nl;
      sP[nl * 65 + m] = __expf(S[((size_t)b * 256 + n) * 64 + m] - rmax[b * 256 + n]) / rsum[b * 256 + n];
    }
    __syncthreads();
    int nl = tid & 63, dg = tid >> 6;
    int n = nt + nl;
    for (int j = 0; j < 16; ++j) {
      int d = dg * 16 + j;
      float acc = 0.f;
      for (int m = 0; m < 64; ++m) acc += sQ[d * 64 + m] * sP[nl * 65 + m];
      float cv = C[((size_t)b * 64 + d) * 256 + n];
      Xcat[((size_t)b * 256 + d) * 256 + n] = cv;
      Xcat[((size_t)b * 256 + 64 + d) * 256 + n] = acc;
      Xcat[((size_t)b * 256 + 128 + d) * 256 + n] = cv * acc;
    }
  } else {
    float* sP = sh; float* sC = sh + 4096;
    int m = tid & 63, dg = tid >> 6;
    float acc[16];
#pragma unroll
    for (int j = 0; j < 16; ++j) acc[j] = 0.f;
    for (int nt = 0; nt < 4; ++nt) {
      __syncthreads();
      for (int i = tid; i < 4096; i += 256) {
        int nl = i >> 6, mm = i & 63;
        int n = nt * 64 + nl;
        sP[i] = __expf(S[((size_t)b * 256 + n) * 64 + mm] - cmax[b * 64 + mm]) / csum[b * 64 + mm];
        int d = i >> 6, nn = i & 63;
        sC[i] = C[((size_t)b * 64 + d) * 256 + nt * 64 + nn];
      }
      __syncthreads();
      for (int nl = 0; nl < 64; ++nl) {
        float p = sP[nl * 64 + m];
#pragma unroll
        for (int j = 0; j < 16; ++j) acc[j] += sC[(dg * 16 + j) * 64 + nl] * p;
      }
    }
    for (int j = 0; j < 16; ++j)
      CS2[((size_t)b * 64 + dg * 16 + j) * 64 + m] = acc[j];
  }
}

// Bm[d,k] = sum_m CS2[d,m] * S1[k,m]
__global__ __launch_bounds__(256) void k_cqBm(
    const float* __restrict__ C, const float* __restrict__ CS2,
    const float* __restrict__ S, const float* __restrict__ rmax,
    const float* __restrict__ rsum, float* __restrict__ Xcat) {
  int b = blockIdx.x, kt = blockIdx.y * 64;
  __shared__ float sW[4096];
  __shared__ float sP[64 * 65];
  for (int i = threadIdx.x; i < 4096; i += 256) sW[i] = CS2[(size_t)b * 4096 + i];
  for (int i = threadIdx.x; i < 4096; i += 256) {
    int kl = i >> 6, m = i & 63;
    int k = kt + kl;
    sP[kl * 65 + m] = __expf(S[((size_t)b * 256 + k) * 64 + m] - rmax[b * 256 + k]) / rsum[b * 256 + k];
  }
  __syncthreads();
  int kl = threadIdx.x & 63, dg = threadIdx.x >> 6;
  int k = kt + kl;
  for (int j = 0; j < 16; ++j) {
    int d = dg * 16 + j;
    float acc = 0.f;
    for (int m = 0; m < 64; ++m) acc += sW[d * 64 + m] * sP[kl * 65 + m];
    float cv = C[((size_t)b * 64 + d) * 256 + k];
    Xcat[((size_t)b * 256 + 192 + d) * 256 + k] = cv * acc;
  }
}

// ---- both pointers in one launch: grid (B, 2) ----------------------------
__global__ void k_pointer2(const float* __restrict__ M0, const float* __restrict__ M1,
                           const float* __restrict__ M2, const float* __restrict__ w0,
                           const float* __restrict__ w1, float* __restrict__ out) {
  int b = blockIdx.x, sel = blockIdx.y, n = threadIdx.x;
  const float* wb = (sel ? w1 : w0) + b * 128;
  const float* Mb = sel ? M2 : M1;
  float y = 0.f;
  for (int d = 0; d < 64; ++d) {
    y += wb[d] * M0[((size_t)b * 64 + d) * 256 + n];
    y += wb[64 + d] * Mb[((size_t)b * 64 + d) * 256 + n];
  }
  __shared__ float wred[4], wsum[4];
  int lane = n & 63, wid = n >> 6;
  float mx = y;
#pragma unroll
  for (int o = 32; o > 0; o >>= 1) mx = fmaxf(mx, __shfl_xor(mx, o));
  if (lane == 0) wred[wid] = mx;
  __syncthreads();
  mx = fmaxf(fmaxf(wred[0], wred[1]), fmaxf(wred[2], wred[3]));
  float e = __expf(y - mx);
  float s = e;
#pragma unroll
  for (int o = 32; o > 0; o >>= 1) s += __shfl_xor(s, o);
  if (lane == 0) wsum[wid] = s;
  __syncthreads();
  s = wsum[0] + wsum[1] + wsum[2] + wsum[3];
  out[sel * 6144 + b * 256 + n] = e / s;
}

// ===========================================================================
extern "C" void kernel_launch(void* const* d_in, const int* in_sizes, int n_in,
                              void* d_out, int out_size, void* d_ws, size_t ws_size,
                              hipStream_t stream) {
  const float* word_table = (const float*)d_in[0];
  const float* char_table = (const float*)d_in[1];
  const float* e2dw = (const float*)d_in[2];
  const float* e2db = (const float*)d_in[3];
  const float* e2pw = (const float*)d_in[4];
  const float* e2pb = (const float*)d_in[5];
  const float* e1dw = (const float*)d_in[6];
  const float* e1db = (const float*)d_in[7];
  const float* e1pw = (const float*)d_in[8];
  const float* e1pb = (const float*)d_in[9];
  const float* hlw = (const float*)d_in[10];
  const float* hlb = (const float*)d_in[11];
  const float* hgw = (const float*)d_in[12];
  const float* hgb = (const float*)d_in[13];
  const float *enc_dw[5], *enc_pw[5], *enc_wq[5], *enc_wk[5], *enc_wv[5], *enc_wo[5], *enc_w[5];
  for (int p = 0; p < 5; ++p) {
    enc_dw[p] = (const float*)d_in[14 + 7 * p + 0];
    enc_pw[p] = (const float*)d_in[14 + 7 * p + 1];
    enc_wq[p] = (const float*)d_in[14 + 7 * p + 2];
    enc_wk[p] = (const float*)d_in[14 + 7 * p + 3];
    enc_wv[p] = (const float*)d_in[14 + 7 * p + 4];
    enc_wo[p] = (const float*)d_in[14 + 7 * p + 5];
    enc_w[p]  = (const float*)d_in[14 + 7 * p + 6];
  }
  const float* cq_w  = (const float*)d_in[49];
  const float* rs_dw = (const float*)d_in[50];
  const float* rs_pw = (const float*)d_in[51];
  const float* p_w0  = (const float*)d_in[52];
  const float* p_w1  = (const float*)d_in[53];
  const int* Cwid = (const int*)d_in[54];
  const int* Ccid = (const int*)d_in[55];
  const int* Qwid = (const int*)d_in[56];
  const int* Qcid = (const int*)d_in[57];
  float* out = (float*)d_out;

  // ---- workspace (floats), ~12.75 MB -------------------------------------
  float* ws = (float*)d_ws;
  float* postab = ws;                  // 16384
  float* U    = ws + 16384;            // 393216
  float* Xcat = ws + 409600;           // 1572864 ; M2 aliases; emb scratch
  float* CX   = ws + 1982464;          // 393216  ; M0 aliases
  float* Sb   = ws + 2375680;          // 393216  ; M1 aliases
  float* QX   = ws + 2768896;          // 98304
  float* CS2  = ws + 2867200;          // 98304
  float* rmax = ws + 2965504;          // 6144
  float* rsum = ws + 2971648;          // 6144
  float* cmax = ws + 2977792;          // 1536
  float* csum = ws + 2979328;          // 1536
  float* P0   = ws + 2980864;          // 12288
  float* P1   = ws + 2993152;          // 12288
  float* pwT  = ws + 3005440;          // 12800
  float* e1pwT= ws + 3018240;          // 23296
  float* hlwT = ws + 3041536;          // 8192
  float* hgwT = ws + 3049728;          // 8192
  float* dwT  = ws + 3057920;          // 5000
  float* P0Q  = ws + 3062920;          // 12288
  float* P1Q  = ws + 3075208;          // 12288
  float* UQ   = ws + 3087496;          // 98304 -> ends 3185800
  float* M0 = CX; float* M1 = Sb; float* M2 = Xcat;
  float* E1C = Xcat;              // 393216
  float* E1Q = Xcat + 393216;     // 98304
  (void)out_size; (void)in_sizes; (void)n_in; (void)ws_size;

  // model-stack encoder: stats pre-seeded in P0, X pre-seeded (posadd-free)
  auto run_enc = [&](float* X, float* Xnext, int p) {
    for (int rep = 0; rep < 7; ++rep) {
      float* pin = P0; float* pout = P1;
      float* Xi = X; float* Xo = U;
      for (int i = 0; i < 2; ++i) {
        hipLaunchKernelGGL((k_fconv<5>), dim3(B, 4), dim3(1024), 0, stream,
                           (const float*)Xi, Xo, (const float*)nullptr, (float*)nullptr,
                           enc_dw[p] + i * 64 * 5, enc_pw[p] + (size_t)i * 4096,
                           (const float*)nullptr, (const float*)nullptr,
                           pin, pout, (const float*)nullptr, (float*)nullptr);
        { float* t = pin; pin = pout; pout = t; }
        { float* t = Xi; Xi = Xo; Xo = t; }
      }
      k_att<<<dim3(HH, B), 512, 0, stream>>>(X, pin, enc_wq[p], enc_wk[p], enc_wv[p], U,
                                             (const float*)nullptr, (const float*)nullptr,
                                             (const float*)nullptr, (const float*)nullptr,
                                             (const float*)nullptr, (float*)nullptr);
      hipLaunchKernelGGL((k_matmul2<false, false, true, false, false>), dim3(B, 4), dim3(1024), 0, stream,
                         (const float*)U, enc_wo[p], (const float*)X, X, (const float*)nullptr, pout,
                         (const float*)nullptr, (const float*)nullptr, (const float*)nullptr,
                         (float*)nullptr, (const float*)nullptr, (float*)nullptr,
                         (float*)nullptr, (const float*)nullptr);
      if (rep < 6)
        hipLaunchKernelGGL((k_matmul2<true, true, true, true, false>), dim3(B, 4), dim3(1024), 0, stream,
                           (const float*)X, enc_w[p], (const float*)X, X, pout, P0,
                           (const float*)nullptr, (const float*)nullptr, (const float*)nullptr,
                           (float*)nullptr, (const float*)nullptr, (float*)nullptr,
                           (float*)nullptr, (const float*)postab);
      else if (Xnext)
        hipLaunchKernelGGL((k_matmul2<true, true, true, false, true>), dim3(B, 4), dim3(1024), 0, stream,
                           (const float*)X, enc_w[p], (const float*)X, X, pout, P0,
                           (const float*)nullptr, (const float*)nullptr, (const float*)nullptr,
                           (float*)nullptr, (const float*)nullptr, (float*)nullptr,
                           Xnext, (const float*)postab);
      else
        hipLaunchKernelGGL((k_matmul2<true, true, false, false, false>), dim3(B, 4), dim3(1024), 0, stream,
                           (const float*)X, enc_w[p], (const float*)X, X, pout, (float*)nullptr,
                           (const float*)nullptr, (const float*)nullptr, (const float*)nullptr,
                           (float*)nullptr, (const float*)nullptr, (float*)nullptr,
                           (float*)nullptr, (const float*)nullptr);
    }
  };

  k_prep<<<289, 256, 0, stream>>>(postab, e2pw, e1pw, hlw, hgw, e2dw,
                                  pwT, e1pwT, hlwT, hgwT, dwT);
  // ---- embeddings ----
  k_charembed<<<dim3(NN + MQ, B), 256, 0, stream>>>(Ccid, Qcid, char_table, dwT, e2db, pwT, e2pb, E1C, E1Q);
  k_embhw<<<dim3(NN + MQ, B), 64, 0, stream>>>(E1C, E1Q, Cwid, Qwid, word_table, e1dw, e1db,
                                               e1pwT, e1pb, hlwT, hlb, hgwT, hgb, CX, QX);
  // ---- embedding encoders (C and Q merged; cnum=4, K=7) ----
  {
    k_posadd_stats<<<dim3(384, 2), 256, 0, stream>>>(CX, QX, postab, P0, P0Q);
    float *pinC = P0, *poutC = P1, *pinQ = P0Q, *poutQ = P1Q;
    float *XiC = CX, *XoC = U, *XiQ = QX, *XoQ = UQ;
    for (int i = 0; i < 4; ++i) {
      hipLaunchKernelGGL((k_fconv<7>), dim3(B, 5), dim3(1024), 0, stream,
                         (const float*)XiC, XoC, (const float*)XiQ, XoQ,
                         enc_dw[0] + i * 64 * 7, enc_pw[0] + (size_t)i * 4096,
                         enc_dw[1] + i * 64 * 7, enc_pw[1] + (size_t)i * 4096,
                         pinC, poutC, pinQ, poutQ);
      { float* t = pinC; pinC = poutC; poutC = t; }
      { float* t = pinQ; pinQ = poutQ; poutQ = t; }
      { float* t = XiC; XiC = XoC; XoC = t; }
      { float* t = XiQ; XiQ = XoQ; XoQ = t; }
    }
    k_att<<<dim3(HH, 2 * B), 512, 0, stream>>>(CX, pinC, enc_wq[0], enc_wk[0], enc_wv[0], U,
                                               QX, pinQ, enc_wq[1], enc_wk[1], enc_wv[1], UQ);
    hipLaunchKernelGGL((k_matmul2<false, false, true, false, false>), dim3(B, 5), dim3(1024), 0, stream,
                       (const float*)U, enc_wo[0], (const float*)CX, CX, (const float*)nullptr, poutC,
                       (const float*)UQ, enc_wo[1], (const float*)QX, QX, (const float*)nullptr, poutQ,
                       (float*)nullptr, (const float*)nullptr);
    hipLaunchKernelGGL((k_matmul2<true, true, false, false, false>), dim3(B, 5), dim3(1024), 0, stream,
                       (const float*)CX, enc_w[0], (const float*)CX, CX, poutC, (float*)nullptr,
                       (const float*)QX, enc_w[1], (const float*)QX, QX, poutQ, (float*)nullptr,
                       (float*)nullptr, (const float*)nullptr);
  }
  // ---- context-query attention ----
  k_cqS<<<dim3(B, 4), 256, 0, stream>>>(CX, QX, cq_w, Sb, rmax, rsum);
  k_cqcol<<<B, 64, 0, stream>>>(Sb, cmax, csum);
  k_cqA_CS2<<<dim3(B, 5), 256, 0, stream>>>(CX, QX, Sb, rmax, rsum, cmax, csum, Xcat, CS2);
  k_cqBm<<<dim3(B, 4), 256, 0, stream>>>(CX, CS2, Sb, rmax, rsum, Xcat);
  // ---- resize -> M0 (+tab +stats; replaces M0 posadd) ----
  k_resize<<<dim3(B, 4), 256, 0, stream>>>(Xcat, rs_dw, rs_pw, postab, M0, P0);
  // ---- model encoders (stack transitions fused into last FF) ----
  run_enc(M0, M1, 2);
  run_enc(M1, M2, 3);
  run_enc(M2, nullptr, 4);
  // ---- pointers ----
  k_pointer2<<<dim3(B, 2), 256, 0, stream>>>(M0, M1, M2, p_w0, p_w1, out);
}

// Round 22
// 1998.777 us; speedup vs baseline: 1.9229x; 1.1157x over previous
//
#include <hip/hip_runtime.h>
#include <math.h>

constexpr int B = 24, HH = 8;
constexpr int NN = 256, MQ = 64;
constexpr int EC = 364;

#define PI_2 1.5707963267948966f

// stats partials layout: parts[row][4][2], row = b*64+d
__device__ __forceinline__ void combine_stats(const float* __restrict__ parts,
                                              int row, int NT, float Lf,
                                              float& mu, float& inv) {
  float s = 0.f, q = 0.f;
  for (int t = 0; t < NT; ++t) {
    s += parts[((size_t)row * 4 + t) * 2];
    q += parts[((size_t)row * 4 + t) * 2 + 1];
  }
  mu = s / Lf;
  float var = (q - s * mu) / (Lf - 1.f);
  if (var < 0.f) var = 0.f;
  inv = 1.f / (sqrtf(var) + 1e-6f);
}

// ---- merged prologue: postab + weight transposes -------------------------
__global__ void k_prep(float* __restrict__ tab,
                       const float* __restrict__ e2pw, const float* __restrict__ e1pw,
                       const float* __restrict__ hlw, const float* __restrict__ hgw,
                       const float* __restrict__ e2dw,
                       float* __restrict__ pwT, float* __restrict__ e1pwT,
                       float* __restrict__ hlwT, float* __restrict__ hgwT,
                       float* __restrict__ dwT) {
  int blk = blockIdx.x;
  if (blk < 64) {
    int d = blk, l = threadIdx.x;
    float fr = ((d & 1) == 0) ? powf(10000.f, -(float)d / 64.f)
                              : -powf(10000.f, -(float)(d - 1) / 64.f);
    float ph = (d & 1) ? PI_2 : 0.f;
    tab[d * 256 + l] = sinf(sinf((float)l * fr + ph));
    return;
  }
  int i = (blk - 64) * 256 + threadIdx.x;
  if (i < 12800) {
    int ce = i >> 6, o = i & 63;
    pwT[i] = e2pw[o * 200 + ce];
    return;
  }
  i -= 12800;
  if (i < 23296) {
    int c = i >> 6, o = i & 63;
    e1pwT[i] = e1pw[o * EC + c];
    return;
  }
  i -= 23296;
  if (i < 8192) {
    int layer = i >> 12, rem = i & 4095;
    int d = rem >> 6, o = rem & 63;
    hlwT[i] = hlw[layer * 4096 + o * 64 + d];
    return;
  }
  i -= 8192;
  if (i < 8192) {
    int layer = i >> 12, rem = i & 4095;
    int d = rem >> 6, o = rem & 63;
    hgwT[i] = hgw[layer * 4096 + o * 64 + d];
    return;
  }
  i -= 8192;
  if (i < 5000) {
    int t = i / 200, ce = i % 200;
    dwT[i] = e2dw[ce * 25 + t];
  }
}

// ---- posadd + stats; grid y: 0=C(L=256), 1=Q(L=64) -----------------------
__global__ void k_posadd_stats(float* __restrict__ XC, float* __restrict__ XQ,
                               const float* __restrict__ tab,
                               float* __restrict__ partsC, float* __restrict__ partsQ) {
  int which = blockIdx.y;
  float* X = which ? XQ : XC;
  float* parts = which ? partsQ : partsC;
  int L = which ? 64 : 256;
  int row = blockIdx.x * 4 + (threadIdx.x >> 6);
  int lane = threadIdx.x & 63;
  int d = row & 63;
  float* xr = X + (size_t)row * L;
  int NT = L >> 6;
  for (int t = 0; t < NT; ++t) {
    int l = t * 64 + lane;
    float v = xr[l] + tab[d * 256 + l];
    xr[l] = v;
    float s = v, q = v * v;
#pragma unroll
    for (int o = 32; o > 0; o >>= 1) { s += __shfl_xor(s, o); q += __shfl_xor(q, o); }
    if (lane == 0) {
      parts[((size_t)row * 4 + t) * 2] = s;
      parts[((size_t)row * 4 + t) * 2 + 1] = q;
    }
  }
}

// ---- fused conv block; 1024 thr; grid y: 0..3 = C tiles, 4 = Q -----------
template<int K>
__global__ __launch_bounds__(1024) void k_fconv(
    const float* __restrict__ XiC, float* __restrict__ XoC,
    const float* __restrict__ XiQ, float* __restrict__ XoQ,
    const float* __restrict__ dwC, const float* __restrict__ pwC,
    const float* __restrict__ dwQ, const float* __restrict__ pwQ,
    const float* __restrict__ pinC, float* __restrict__ poutC,
    const float* __restrict__ pinQ, float* __restrict__ poutQ) {
  constexpr int H = K / 2, SW = 64 + 2 * H;
  __shared__ float smu[64], sinv[64];
  __shared__ float sN[64 * SW];
  __shared__ float sD[64 * 65];
  __shared__ __align__(16) float sWt[4096];
  int b = blockIdx.x, t = blockIdx.y;
  const float *Xin, *dw, *pw, *pin; float *Xout, *pout; int L, tile;
  if (t < 4) { Xin = XiC; Xout = XoC; dw = dwC; pw = pwC; pin = pinC; pout = poutC; L = 256; tile = t; }
  else       { Xin = XiQ; Xout = XoQ; dw = dwQ; pw = pwQ; pin = pinQ; pout = poutQ; L = 64;  tile = 0; }
  int lt = tile * 64;
  int tid = threadIdx.x;
  int NT = L >> 6;
  if (tid < 64) combine_stats(pin, b * 64 + tid, NT, (float)L, smu[tid], sinv[tid]);
  for (int i = tid; i < 1024; i += 1024)
    ((float4*)sWt)[i] = ((const float4*)pw)[i];
  const float* Xb = Xin + (size_t)b * 64 * L;
  int l = tid & 63, og = tid >> 6;
  float rres[4];
#pragma unroll
  for (int j = 0; j < 4; ++j)
    rres[j] = Xb[(size_t)(og * 4 + j) * L + lt + l];
  __syncthreads();
  for (int i = tid; i < 64 * SW; i += 1024) {
    int c = i / SW, jj = i % SW;
    int gl = lt + jj - H;
    sN[i] = (gl >= 0 && gl < L) ? (Xb[(size_t)c * L + gl] - smu[c]) * sinv[c] : 0.f;
  }
  __syncthreads();
  for (int i = tid; i < 4096; i += 1024) {
    int c = i >> 6, ll = i & 63;
    float acc = 0.f;
#pragma unroll
    for (int k = 0; k < K; ++k) acc += sN[c * SW + ll + k] * dw[c * K + k];
    sD[c * 65 + ll] = acc;
  }
  __syncthreads();
  float acc[4];
#pragma unroll
  for (int j = 0; j < 4; ++j) acc[j] = 0.f;
  for (int c = 0; c < 64; ++c) {
    float av = sD[c * 65 + l];
#pragma unroll
    for (int j = 0; j < 4; ++j) acc[j] += sWt[(og * 4 + j) * 64 + c] * av;
  }
  __syncthreads();
  float* Ob = Xout + (size_t)b * 64 * L;
#pragma unroll
  for (int j = 0; j < 4; ++j) {
    int o = og * 4 + j;
    float v = rres[j] + fmaxf(acc[j], 0.f);
    Ob[(size_t)o * L + lt + l] = v;
    sD[o * 65 + l] = v;
  }
  __syncthreads();
  if (tid < 64) {
    int o = tid;
    float s = 0.f, q = 0.f;
    for (int l2 = 0; l2 < 64; ++l2) { float v = sD[o * 65 + l2]; s += v; q += v * v; }
    pout[((size_t)(b * 64 + o) * 4 + tile) * 2] = s;
    pout[((size_t)(b * 64 + o) * 4 + tile) * 2 + 1] = q;
  }
}

// ---- 64x64 matmul; 1024 thr; grid y: 0..3 = C tiles, 4 = Q ---------------
template<bool NORM, bool RELU, bool STATS, bool ADDTAB, bool DUAL>
__global__ __launch_bounds__(1024) void k_matmul2(
    const float* __restrict__ AC, const float* __restrict__ WC,
    const float* __restrict__ resC, float* __restrict__ outC2,
    const float* __restrict__ pinC, float* __restrict__ poutC,
    const float* __restrict__ AQ, const float* __restrict__ WQ,
    const float* __restrict__ resQ, float* __restrict__ outQ2,
    const float* __restrict__ pinQ, float* __restrict__ poutQ,
    float* __restrict__ outNextC, const float* __restrict__ tab) {
  __shared__ float sA[64 * 65];
  __shared__ __align__(16) float sW[4096];
  __shared__ float smu[64], sinv[64];
  int b = blockIdx.x, t = blockIdx.y;
  const float *A, *W, *res, *pin; float *outp, *pout; int L, tile;
  if (t < 4) { A = AC; W = WC; res = resC; outp = outC2; pin = pinC; pout = poutC; L = 256; tile = t; }
  else       { A = AQ; W = WQ; res = resQ; outp = outQ2; pin = pinQ; pout = poutQ; L = 64;  tile = 0; }
  int lt = tile * 64;
  int tid = threadIdx.x;
  int NT = L >> 6;
  if (NORM && tid < 64) combine_stats(pin, b * 64 + tid, NT, (float)L, smu[tid], sinv[tid]);
  const float* Wb = W + (size_t)b * 4096;
  for (int i = tid; i < 1024; i += 1024)
    ((float4*)sW)[i] = ((const float4*)Wb)[i];
  int l = tid & 63, og = tid >> 6;
  float rres[4], rtab[4];
#pragma unroll
  for (int j = 0; j < 4; ++j) {
    int o = og * 4 + j;
    rres[j] = res[((size_t)b * 64 + o) * L + lt + l];
    if (ADDTAB || DUAL) rtab[j] = tab[o * 256 + lt + l];
  }
  if (NORM) __syncthreads();
  const float* Ab = A + (size_t)b * 64 * L;
  for (int i = tid; i < 1024; i += 1024) {
    int c = i >> 4, lq = (i & 15) * 4;
    float4 v = *(const float4*)(Ab + (size_t)c * L + lt + lq);
    if (NORM) {
      float mu = smu[c], iv = sinv[c];
      v.x = (v.x - mu) * iv; v.y = (v.y - mu) * iv;
      v.z = (v.z - mu) * iv; v.w = (v.w - mu) * iv;
    }
    sA[c * 65 + lq] = v.x; sA[c * 65 + lq + 1] = v.y;
    sA[c * 65 + lq + 2] = v.z; sA[c * 65 + lq + 3] = v.w;
  }
  __syncthreads();
  float acc[4];
#pragma unroll
  for (int j = 0; j < 4; ++j) acc[j] = 0.f;
  for (int c = 0; c < 64; ++c) {
    float av = sA[c * 65 + l];
#pragma unroll
    for (int j = 0; j < 4; ++j) acc[j] += sW[(og * 4 + j) * 64 + c] * av;
  }
  if (STATS) __syncthreads();
#pragma unroll
  for (int j = 0; j < 4; ++j) {
    int o = og * 4 + j;
    float v = acc[j];
    if (RELU) v = fmaxf(v, 0.f);
    v += rres[j];
    if (DUAL) {
      float vn = v + rtab[j];
      outp[((size_t)b * 64 + o) * L + lt + l] = v;
      outNextC[((size_t)b * 64 + o) * L + lt + l] = vn;
      if (STATS) sA[o * 65 + l] = vn;
    } else {
      if (ADDTAB) v += rtab[j];
      outp[((size_t)b * 64 + o) * L + lt + l] = v;
      if (STATS) sA[o * 65 + l] = v;
    }
  }
  if (STATS) {
    __syncthreads();
    if (tid < 64) {
      int o = tid;
      float s = 0.f, q = 0.f;
      for (int l2 = 0; l2 < 64; ++l2) { float v = sA[o * 65 + l2]; s += v; q += v * v; }
      pout[((size_t)(b * 64 + o) * 4 + tile) * 2] = s;
      pout[((size_t)(b * 64 + o) * 4 + tile) * 2 + 1] = q;
    }
  }
}

// ---- fused resize + tab + stats: M0 = pw.dw5(Xcat) + tab -----------------
__global__ __launch_bounds__(256) void k_resize(
    const float* __restrict__ Xcat, const float* __restrict__ dw,
    const float* __restrict__ pw, const float* __restrict__ tab,
    float* __restrict__ out, float* __restrict__ parts) {
  __shared__ float sA[64 * 65];
  int b = blockIdx.x, lt = blockIdx.y * 64;
  int l = threadIdx.x & 63, og = threadIdx.x >> 6;
  float acc[16];
#pragma unroll
  for (int j = 0; j < 16; ++j) acc[j] = 0.f;
  for (int c0 = 0; c0 < 256; c0 += 64) {
    __syncthreads();
    for (int i = threadIdx.x; i < 4096; i += 256) {
      int c = (i >> 6) + c0, ll = (i & 63) + lt;
      const float* xr = Xcat + ((size_t)b * 256 + c) * 256;
      float a = 0.f;
#pragma unroll
      for (int k = 0; k < 5; ++k) {
        int p = ll + k - 2;
        if (p >= 0 && p < 256) a += xr[p] * dw[c * 5 + k];
      }
      sA[(i >> 6) * 65 + (i & 63)] = a;
    }
    __syncthreads();
    for (int c = 0; c < 64; ++c) {
      float av = sA[c * 65 + l];
#pragma unroll
      for (int j = 0; j < 16; ++j)
        acc[j] += pw[(size_t)(og * 16 + j) * 256 + c0 + c] * av;
    }
  }
  __syncthreads();
#pragma unroll
  for (int j = 0; j < 16; ++j) {
    int o = og * 16 + j;
    float v = acc[j] + tab[o * 256 + lt + l];
    out[((size_t)b * 64 + o) * 256 + lt + l] = v;
    sA[o * 65 + l] = v;
  }
  __syncthreads();
  if (threadIdx.x < 64) {
    int o = threadIdx.x;
    float s = 0.f, q = 0.f;
    for (int l2 = 0; l2 < 64; ++l2) { float v = sA[o * 65 + l2]; s += v; q += v * v; }
    parts[((size_t)(b * 64 + o) * 4 + blockIdx.y) * 2] = s;
    parts[((size_t)(b * 64 + o) * 4 + blockIdx.y) * 2 + 1] = q;
  }
}

// ---- self-attention; 1024 thr; 4-way split softmax; grid y: C then Q -----
__global__ __launch_bounds__(1024) void k_att(
    const float* __restrict__ XC, const float* __restrict__ partsC,
    const float* __restrict__ wqC, const float* __restrict__ wkC,
    const float* __restrict__ wvC, float* __restrict__ hcC,
    const float* __restrict__ XQ, const float* __restrict__ partsQ,
    const float* __restrict__ wqQ, const float* __restrict__ wkQ,
    const float* __restrict__ wvQ, float* __restrict__ hcQ) {
  int h = blockIdx.x, b2 = blockIdx.y;
  const float *X, *parts, *wq, *wk, *wv; float* hc; int L, b;
  if (b2 < B) { X = XC; parts = partsC; wq = wqC; wk = wkC; wv = wvC; hc = hcC; L = 256; b = b2; }
  else        { X = XQ; parts = partsQ; wq = wqQ; wk = wkQ; wv = wvQ; hc = hcQ; L = 64;  b = b2 - B; }
  __shared__ float smu[64], sinv[64];
  __shared__ float sX[64 * 65];          // staging; later pacc (<=4160 floats)
  __shared__ float sQ[2048], sK8[2048], sV[2048];
  __shared__ float swq[512], swk[512], swv[512];
  __shared__ float pmx[1024], psum[1024];
  int tid = threadIdx.x;
  int NT = L >> 6;
  if (tid < 64) combine_stats(parts, b * 64 + tid, NT, (float)L, smu[tid], sinv[tid]);
  size_t woff = (size_t)(h * B + b) * 512;
  if (tid < 512) {
    swq[tid] = wq[woff + tid];
    swk[tid] = wk[woff + tid];
    swv[tid] = wv[woff + tid];
  }
  __syncthreads();
  const float* Xb = X + (size_t)b * 64 * L;
  for (int lt = 0; lt < L; lt += 64) {
    for (int i = tid; i < 4096; i += 1024) {
      int d = i >> 6, l = i & 63;
      sX[d * 65 + l] = (Xb[(size_t)d * L + lt + l] - smu[d]) * sinv[d];
    }
    __syncthreads();
    if (tid < 512) {
      int k = tid >> 6, l = tid & 63;
      float aq = 0.f, ak = 0.f, av = 0.f;
      for (int d = 0; d < 64; ++d) {
        float x = sX[d * 65 + l];
        aq += swq[k * 64 + d] * x;
        ak += swk[k * 64 + d] * x;
        av += swv[k * 64 + d] * x;
      }
      sQ[k * L + lt + l] = aq; sK8[k * L + lt + l] = ak; sV[k * L + lt + l] = av;
    }
    __syncthreads();
  }
  const float scale = 0.35355339059327373f;  // 1/sqrt(8)
  int m = tid & 255, qt = tid >> 8;          // quarter 0..3
  int L4 = L >> 2;
  float mx = -1e30f, sum = 0.f, acc[8];
#pragma unroll
  for (int v = 0; v < 8; ++v) acc[v] = 0.f;
  if (m < L) {
    float kc[8];
#pragma unroll
    for (int k = 0; k < 8; ++k) kc[k] = sK8[k * L + m];
    int l0 = qt * L4, l1 = l0 + L4;
    for (int l = l0; l < l1; ++l) {
      float s = 0.f;
#pragma unroll
      for (int k = 0; k < 8; ++k) s += sQ[k * L + l] * kc[k];
      s *= scale;
      if (s <= mx) {
        float p = __expf(s - mx);
        sum += p;
#pragma unroll
        for (int v = 0; v < 8; ++v) acc[v] += p * sV[v * L + l];
      } else {
        float corr = __expf(mx - s);
        sum = sum * corr + 1.f;
#pragma unroll
        for (int v = 0; v < 8; ++v) acc[v] = acc[v] * corr + sV[v * L + l];
        mx = s;
      }
    }
  }
  float* pacc = sX;   // reuse (staging done)
  // stage 1: quarters 1,3 publish; 0,2 merge  (q0<-q1, q2<-q3)
  pmx[tid] = mx;
  psum[tid] = sum;
  __syncthreads();    // ensure sX reads done before overwrite
  if (qt & 1) {
#pragma unroll
    for (int v = 0; v < 8; ++v) pacc[(((qt >> 1) << 8) + m) * 8 + v] = acc[v];
  }
  __syncthreads();
  if (!(qt & 1) && m < L) {
    float m1 = pmx[tid + 256], s1 = psum[tid + 256];
    float mT = fmaxf(mx, m1);
    float c0 = __expf(mx - mT), c1 = __expf(m1 - mT);
    sum = sum * c0 + s1 * c1;
#pragma unroll
    for (int v = 0; v < 8; ++v)
      acc[v] = acc[v] * c0 + pacc[(((qt >> 1) << 8) + m) * 8 + v] * c1;
    mx = mT;
  }
  __syncthreads();
  // stage 2: quarter 2 publishes; quarter 0 merges + writes
  if (qt == 2) {
    pmx[512 + m] = mx;
    psum[512 + m] = sum;
#pragma unroll
    for (int v = 0; v < 8; ++v) pacc[m * 8 + v] = acc[v];
  }
  __syncthreads();
  if (qt == 0 && m < L) {
    float m1 = pmx[512 + m], s1 = psum[512 + m];
    float mT = fmaxf(mx, m1);
    float c0 = __expf(mx - mT), c1 = __expf(m1 - mT);
    float s = sum * c0 + s1 * c1;
    float is = 1.f / s;
#pragma unroll
    for (int v = 0; v < 8; ++v) {
      float a = acc[v] * c0 + pacc[m * 8 + v] * c1;
      hc[((size_t)b * 64 + h * 8 + v) * L + m] = a * is;
    }
  }
}

// ---- merged C+Q char embed: reg-staged taps + float4 LDS phase 2 ---------
__global__ __launch_bounds__(256) void k_charembed(
    const int* __restrict__ cidC, const int* __restrict__ cidQ,
    const float* __restrict__ ctab, const float* __restrict__ dwT,
    const float* __restrict__ db, const float* __restrict__ pwT,
    const float* __restrict__ pb,
    float* __restrict__ outC, float* __restrict__ outQ) {
  int nx = blockIdx.x, b = blockIdx.y;
  const int* cid; float* out; int Ln, n;
  if (nx < NN) { cid = cidC; out = outC; Ln = NN; n = nx; }
  else         { cid = cidQ; out = outQ; Ln = MQ; n = nx - NN; }
  __shared__ __align__(16) float dwo[16 * 200];
  __shared__ int sid[5][16];
  __shared__ float red[256];
  int tid = threadIdx.x;
  if (tid < 80) {
    int kn = tid / 16, cn = tid % 16;
    int nn = n + kn - 2;
    sid[kn][cn] = (nn >= 0 && nn < Ln) ? cid[((size_t)b * Ln + nn) * 16 + cn] : -1;
  }
  __syncthreads();
  for (int i = tid; i < 16 * 200; i += 256) {
    int cn = i / 200, ce = i % 200;
    float r[25];
#pragma unroll
    for (int kn = 0; kn < 5; ++kn) {
#pragma unroll
      for (int kc = 0; kc < 5; ++kc) {
        int cc = cn + kc - 2;
        int id = (cc >= 0 && cc < 16) ? sid[kn][cc] : -1;
        r[kn * 5 + kc] = (id >= 0) ? ctab[(size_t)id * 200 + ce] : 0.f;
      }
    }
    float acc = db[ce];
#pragma unroll
    for (int t = 0; t < 25; ++t) acc += r[t] * dwT[t * 200 + ce];
    dwo[cn * 200 + ce] = acc;
  }
  __syncthreads();
  int o = tid & 63, q = tid >> 6;
  float acc4[4];
#pragma unroll
  for (int k = 0; k < 4; ++k) acc4[k] = pb[o];
  for (int c0 = 0; c0 < 200; c0 += 8) {
    float w8[8];
#pragma unroll
    for (int j = 0; j < 8; ++j) w8[j] = pwT[(c0 + j) * 64 + o];
#pragma unroll
    for (int k = 0; k < 4; ++k) {
      const float* dr = dwo + (q + k * 4) * 200 + c0;
      float4 a0 = *(const float4*)dr;
      float4 a1 = *(const float4*)(dr + 4);
      acc4[k] += w8[0] * a0.x; acc4[k] += w8[1] * a0.y;
      acc4[k] += w8[2] * a0.z; acc4[k] += w8[3] * a0.w;
      acc4[k] += w8[4] * a1.x; acc4[k] += w8[5] * a1.y;
      acc4[k] += w8[6] * a1.z; acc4[k] += w8[7] * a1.w;
    }
  }
  float mx = -1e30f;
#pragma unroll
  for (int k = 0; k < 4; ++k) mx = fmaxf(mx, acc4[k]);
  red[tid] = mx;
  __syncthreads();
  if (q == 0) {
    mx = fmaxf(fmaxf(red[o], red[64 + o]), fmaxf(red[128 + o], red[192 + o]));
    out[((size_t)b * 64 + o) * Ln + n] = fmaxf(mx, 0.f);
  }
}

// ---- merged C+Q embconv + highway ----------------------------------------
__global__ void k_embhw(const float* __restrict__ chxC, const float* __restrict__ chxQ,
                        const int* __restrict__ widC, const int* __restrict__ widQ,
                        const float* __restrict__ wtab, const float* __restrict__ dw,
                        const float* __restrict__ db, const float* __restrict__ pwT,
                        const float* __restrict__ pb,
                        const float* __restrict__ lwT, const float* __restrict__ lb,
                        const float* __restrict__ gwT, const float* __restrict__ gb,
                        float* __restrict__ outC, float* __restrict__ outQ) {
  int nx = blockIdx.x, b = blockIdx.y;
  const float* chx; const int* wid; float* out; int Ln, n;
  if (nx < NN) { chx = chxC; wid = widC; out = outC; Ln = NN; n = nx; }
  else         { chx = chxQ; wid = widQ; out = outQ; Ln = MQ; n = nx - NN; }
  __shared__ float dwc[EC];
  __shared__ int sw[5];
  __shared__ float x[64], xn[64];
  int tid = threadIdx.x;
  if (tid < 5) {
    int nn = n + tid - 2;
    sw[tid] = (nn >= 0 && nn < Ln) ? wid[(size_t)b * Ln + nn] : -1;
  }
  __syncthreads();
  for (int ch = tid; ch < EC; ch += 64) {
    float r[5];
#pragma unroll
    for (int k = 0; k < 5; ++k) {
      int nn = n + k - 2;
      float v = 0.f;
      if (nn >= 0 && nn < Ln) {
        if (ch < 64) v = chx[((size_t)b * 64 + ch) * Ln + nn];
        else v = wtab[(size_t)sw[k] * 300 + (ch - 64)];
      }
      r[k] = v;
    }
    float acc = db[ch];
#pragma unroll
    for (int k = 0; k < 5; ++k) acc += r[k] * dw[ch * 5 + k];
    dwc[ch] = acc;
  }
  __syncthreads();
  int o = tid;
  float acc = pb[o];
  for (int c0 = 0; c0 < EC; c0 += 4) {
    float w4[4];
#pragma unroll
    for (int j = 0; j < 4; ++j) w4[j] = pwT[(c0 + j) * 64 + o];
#pragma unroll
    for (int j = 0; j < 4; ++j) acc += w4[j] * dwc[c0 + j];
  }
  x[o] = acc;
  __syncthreads();
  for (int layer = 0; layer < 2; ++layer) {
    const float* lwr = lwT + layer * 4096;
    const float* gwr = gwT + layer * 4096;
    float gl = gb[layer * 64 + o], nl = lb[layer * 64 + o];
    for (int d0 = 0; d0 < 64; d0 += 8) {
      float g8[8], l8[8];
#pragma unroll
      for (int j = 0; j < 8; ++j) { g8[j] = gwr[(d0 + j) * 64 + o]; l8[j] = lwr[(d0 + j) * 64 + o]; }
#pragma unroll
      for (int j = 0; j < 8; ++j) { gl += g8[j] * x[d0 + j]; nl += l8[j] * x[d0 + j]; }
    }
    float g = 1.f / (1.f + __expf(-gl));
    float r = fmaxf(nl, 0.f);
    xn[o] = g * r + (1.f - g) * x[o];
    __syncthreads();
    x[o] = xn[o];
    __syncthreads();
  }
  out[((size_t)b * 64 + o) * Ln + n] = x[o];
}

// ---------------- context-query attention ---------------------------------
__global__ __launch_bounds__(256) void k_cqS(const float* __restrict__ C,
                                             const float* __restrict__ Q,
                                             const float* __restrict__ w,
                                             float* __restrict__ S,
                                             float* __restrict__ rmax,
                                             float* __restrict__ rsum) {
  int b = blockIdx.x, nt = blockIdx.y * 64;
  __shared__ float sQ[4096], sC[4096], ct[64], qt[64], swb[192];
  const float* Cb = C + (size_t)b * 64 * 256;
  const float* Qb = Q + (size_t)b * 4096;
  const float* wb = w + (size_t)b * 192;
  if (threadIdx.x < 192) swb[threadIdx.x] = wb[threadIdx.x];
  for (int i = threadIdx.x; i < 4096; i += 256) {
    int d = i >> 6, m = i & 63;
    sQ[i] = Qb[d * 64 + m];
    sC[i] = Cb[d * 256 + nt + m];
  }
  __syncthreads();
  if (threadIdx.x < 64) {
    int j = threadIdx.x;
    float a = 0.f, c2 = 0.f;
    for (int d = 0; d < 64; ++d) {
      a += swb[64 + d] * sC[d * 64 + j];
      c2 += swb[d] * sQ[d * 64 + j];
    }
    ct[j] = a; qt[j] = c2;
  }
  __syncthreads();
  int m = threadIdx.x & 63, wv = threadIdx.x >> 6;
  for (int it = 0; it < 16; ++it) {
    int nl = wv + it * 4;
    float acc = ct[nl] + qt[m];
    for (int d = 0; d < 64; ++d)
      acc += sC[d * 64 + nl] * swb[128 + d] * sQ[d * 64 + m];
    S[((size_t)b * 256 + nt + nl) * 64 + m] = acc;
    float mx = acc;
#pragma unroll
    for (int o = 32; o > 0; o >>= 1) mx = fmaxf(mx, __shfl_xor(mx, o));
    float p = __expf(acc - mx);
#pragma unroll
    for (int o = 32; o > 0; o >>= 1) p += __shfl_xor(p, o);
    if (m == 0) { rmax[b * 256 + nt + nl] = mx; rsum[b * 256 + nt + nl] = p; }
  }
}

__global__ void k_cqcol(const float* __restrict__ S, float* __restrict__ cmax,
                        float* __restrict__ csum) {
  int b = blockIdx.x, m = threadIdx.x;
  const float* Sb = S + (size_t)b * 256 * 64;
  float mx = -1e30f;
  for (int n = 0; n < 256; ++n) mx = fmaxf(mx, Sb[n * 64 + m]);
  float s = 0.f;
  for (int n = 0; n < 256; ++n) s += __expf(Sb[n * 64 + m] - mx);
  cmax[b * 64 + m] = mx; csum[b * 64 + m] = s;
}

// ---- merged cqA (y=0..3) + cqCS2 (y=4) -----------------------------------
__global__ __launch_bounds__(256) void k_cqA_CS2(
    const float* __restrict__ C, const float* __restrict__ Q,
    const float* __restrict__ S, const float* __restrict__ rmax,
    const float* __restrict__ rsum, const float* __restrict__ cmax,
    const float* __restrict__ csum, float* __restrict__ Xcat,
    float* __restrict__ CS2) {
  __shared__ float sh[8256];
  int b = blockIdx.x, t = blockIdx.y;
  int tid = threadIdx.x;
  if (t < 4) {
    float* sQ = sh; float* sP = sh + 4096;
    int nt = t * 64;
    const float* Qb = Q + (size_t)b * 4096;
    for (int i = tid; i < 4096; i += 256) sQ[i] = Qb[i];
    for (int i = tid; i < 4096; i += 256) {
      int nl = i >> 6, m = i & 63;
      int n = nt + nl;
      sP[nl * 65 + m] = __expf(S[((size_t)b * 256 + n) * 64 + m] - rmax[b * 256 + n]) / rsum[b * 256 + n];
    }
    __syncthreads();
    int nl = tid & 63, dg = tid >> 6;
    int n = nt + nl;
    for (int j = 0; j < 16; ++j) {
      int d = dg * 16 + j;
      float acc = 0.f;
      for (int m = 0; m < 64; ++m) acc += sQ[d * 64 + m] * sP[nl * 65 + m];
      float cv = C[((size_t)b * 64 + d) * 256 + n];
      Xcat[((size_t)b * 256 + d) * 256 + n] = cv;
      Xcat[((size_t)b * 256 + 64 + d) * 256 + n] = acc;
      Xcat[((size_t)b * 256 + 128 + d) * 256 + n] = cv * acc;
    }
  } else {
    float* sP = sh; float* sC = sh + 4096;
    int m = tid & 63, dg = tid >> 6;
    float acc[16];
#pragma unroll
    for (int j = 0; j < 16; ++j) acc[j] = 0.f;
    for (int nt = 0; nt < 4; ++nt) {
      __syncthreads();
      for (int i = tid; i < 4096; i += 256) {
        int nl = i >> 6, mm = i & 63;
        int n = nt * 64 + nl;
        sP[i] = __expf(S[((size_t)b * 256 + n) * 64 + mm] - cmax[b * 64 + mm]) / csum[b * 64 + mm];
        int d = i >> 6, nn = i & 63;
        sC[i] = C[((size_t)b * 64 + d) * 256 + nt * 64 + nn];
      }
      __syncthreads();
      for (int nl = 0; nl < 64; ++nl) {
        float p = sP[nl * 64 + m];
#pragma unroll
        for (int j = 0; j < 16; ++j) acc[j] += sC[(dg * 16 + j) * 64 + nl] * p;
      }
    }
    for (int j = 0; j < 16; ++j)
      CS2[((size_t)b * 64 + dg * 16 + j) * 64 + m] = acc[j];
  }
}

// Bm[d,k] = sum_m CS2[d,m] * S1[k,m]
__global__ __launch_bounds__(256) void k_cqBm(
    const float* __restrict__ C, const float* __restrict__ CS2,
    const float* __restrict__ S, const float* __restrict__ rmax,
    const float* __restrict__ rsum, float* __restrict__ Xcat) {
  int b = blockIdx.x, kt = blockIdx.y * 64;
  __shared__ float sW[4096];
  __shared__ float sP[64 * 65];
  for (int i = threadIdx.x; i < 4096; i += 256) sW[i] = CS2[(size_t)b * 4096 + i];
  for (int i = threadIdx.x; i < 4096; i += 256) {
    int kl = i >> 6, m = i & 63;
    int k = kt + kl;
    sP[kl * 65 + m] = __expf(S[((size_t)b * 256 + k) * 64 + m] - rmax[b * 256 + k]) / rsum[b * 256 + k];
  }
  __syncthreads();
  int kl = threadIdx.x & 63, dg = threadIdx.x >> 6;
  int k = kt + kl;
  for (int j = 0; j < 16; ++j) {
    int d = dg * 16 + j;
    float acc = 0.f;
    for (int m = 0; m < 64; ++m) acc += sW[d * 64 + m] * sP[kl * 65 + m];
    float cv = C[((size_t)b * 64 + d) * 256 + k];
    Xcat[((size_t)b * 256 + 192 + d) * 256 + k] = cv * acc;
  }
}

// ---- both pointers in one launch: grid (B, 2) ----------------------------
__global__ void k_pointer2(const float* __restrict__ M0, const float* __restrict__ M1,
                           const float* __restrict__ M2, const float* __restrict__ w0,
                           const float* __restrict__ w1, float* __restrict__ out) {
  int b = blockIdx.x, sel = blockIdx.y, n = threadIdx.x;
  const float* wb = (sel ? w1 : w0) + b * 128;
  const float* Mb = sel ? M2 : M1;
  float y = 0.f;
  for (int d = 0; d < 64; ++d) {
    y += wb[d] * M0[((size_t)b * 64 + d) * 256 + n];
    y += wb[64 + d] * Mb[((size_t)b * 64 + d) * 256 + n];
  }
  __shared__ float wred[4], wsum[4];
  int lane = n & 63, wid = n >> 6;
  float mx = y;
#pragma unroll
  for (int o = 32; o > 0; o >>= 1) mx = fmaxf(mx, __shfl_xor(mx, o));
  if (lane == 0) wred[wid] = mx;
  __syncthreads();
  mx = fmaxf(fmaxf(wred[0], wred[1]), fmaxf(wred[2], wred[3]));
  float e = __expf(y - mx);
  float s = e;
#pragma unroll
  for (int o = 32; o > 0; o >>= 1) s += __shfl_xor(s, o);
  if (lane == 0) wsum[wid] = s;
  __syncthreads();
  s = wsum[0] + wsum[1] + wsum[2] + wsum[3];
  out[sel * 6144 + b * 256 + n] = e / s;
}

// ===========================================================================
extern "C" void kernel_launch(void* const* d_in, const int* in_sizes, int n_in,
                              void* d_out, int out_size, void* d_ws, size_t ws_size,
                              hipStream_t stream) {
  const float* word_table = (const float*)d_in[0];
  const float* char_table = (const float*)d_in[1];
  const float* e2dw = (const float*)d_in[2];
  const float* e2db = (const float*)d_in[3];
  const float* e2pw = (const float*)d_in[4];
  const float* e2pb = (const float*)d_in[5];
  const float* e1dw = (const float*)d_in[6];
  const float* e1db = (const float*)d_in[7];
  const float* e1pw = (const float*)d_in[8];
  const float* e1pb = (const float*)d_in[9];
  const float* hlw = (const float*)d_in[10];
  const float* hlb = (const float*)d_in[11];
  const float* hgw = (const float*)d_in[12];
  const float* hgb = (const float*)d_in[13];
  const float *enc_dw[5], *enc_pw[5], *enc_wq[5], *enc_wk[5], *enc_wv[5], *enc_wo[5], *enc_w[5];
  for (int p = 0; p < 5; ++p) {
    enc_dw[p] = (const float*)d_in[14 + 7 * p + 0];
    enc_pw[p] = (const float*)d_in[14 + 7 * p + 1];
    enc_wq[p] = (const float*)d_in[14 + 7 * p + 2];
    enc_wk[p] = (const float*)d_in[14 + 7 * p + 3];
    enc_wv[p] = (const float*)d_in[14 + 7 * p + 4];
    enc_wo[p] = (const float*)d_in[14 + 7 * p + 5];
    enc_w[p]  = (const float*)d_in[14 + 7 * p + 6];
  }
  const float* cq_w  = (const float*)d_in[49];
  const float* rs_dw = (const float*)d_in[50];
  const float* rs_pw = (const float*)d_in[51];
  const float* p_w0  = (const float*)d_in[52];
  const float* p_w1  = (const float*)d_in[53];
  const int* Cwid = (const int*)d_in[54];
  const int* Ccid = (const int*)d_in[55];
  const int* Qwid = (const int*)d_in[56];
  const int* Qcid = (const int*)d_in[57];
  float* out = (float*)d_out;

  // ---- workspace (floats), ~12.75 MB -------------------------------------
  float* ws = (float*)d_ws;
  float* postab = ws;                  // 16384
  float* U    = ws + 16384;            // 393216
  float* Xcat = ws + 409600;           // 1572864 ; M2 aliases; emb scratch
  float* CX   = ws + 1982464;          // 393216  ; M0 aliases
  float* Sb   = ws + 2375680;          // 393216  ; M1 aliases
  float* QX   = ws + 2768896;          // 98304
  float* CS2  = ws + 2867200;          // 98304
  float* rmax = ws + 2965504;          // 6144
  float* rsum = ws + 2971648;          // 6144
  float* cmax = ws + 2977792;          // 1536
  float* csum = ws + 2979328;          // 1536
  float* P0   = ws + 2980864;          // 12288
  float* P1   = ws + 2993152;          // 12288
  float* pwT  = ws + 3005440;          // 12800
  float* e1pwT= ws + 3018240;          // 23296
  float* hlwT = ws + 3041536;          // 8192
  float* hgwT = ws + 3049728;          // 8192
  float* dwT  = ws + 3057920;          // 5000
  float* P0Q  = ws + 3062920;          // 12288
  float* P1Q  = ws + 3075208;          // 12288
  float* UQ   = ws + 3087496;          // 98304 -> ends 3185800
  float* M0 = CX; float* M1 = Sb; float* M2 = Xcat;
  float* E1C = Xcat;              // 393216
  float* E1Q = Xcat + 393216;     // 98304
  (void)out_size; (void)in_sizes; (void)n_in; (void)ws_size;

  auto run_enc = [&](float* X, float* Xnext, int p) {
    for (int rep = 0; rep < 7; ++rep) {
      float* pin = P0; float* pout = P1;
      float* Xi = X; float* Xo = U;
      for (int i = 0; i < 2; ++i) {
        hipLaunchKernelGGL((k_fconv<5>), dim3(B, 4), dim3(1024), 0, stream,
                           (const float*)Xi, Xo, (const float*)nullptr, (float*)nullptr,
                           enc_dw[p] + i * 64 * 5, enc_pw[p] + (size_t)i * 4096,
                           (const float*)nullptr, (const float*)nullptr,
                           pin, pout, (const float*)nullptr, (float*)nullptr);
        { float* t = pin; pin = pout; pout = t; }
        { float* t = Xi; Xi = Xo; Xo = t; }
      }
      k_att<<<dim3(HH, B), 1024, 0, stream>>>(X, pin, enc_wq[p], enc_wk[p], enc_wv[p], U,
                                              (const float*)nullptr, (const float*)nullptr,
                                              (const float*)nullptr, (const float*)nullptr,
                                              (const float*)nullptr, (float*)nullptr);
      hipLaunchKernelGGL((k_matmul2<false, false, true, false, false>), dim3(B, 4), dim3(1024), 0, stream,
                         (const float*)U, enc_wo[p], (const float*)X, X, (const float*)nullptr, pout,
                         (const float*)nullptr, (const float*)nullptr, (const float*)nullptr,
                         (float*)nullptr, (const float*)nullptr, (float*)nullptr,
                         (float*)nullptr, (const float*)nullptr);
      if (rep < 6)
        hipLaunchKernelGGL((k_matmul2<true, true, true, true, false>), dim3(B, 4), dim3(1024), 0, stream,
                           (const float*)X, enc_w[p], (const float*)X, X, pout, P0,
                           (const float*)nullptr, (const float*)nullptr, (const float*)nullptr,
                           (float*)nullptr, (const float*)nullptr, (float*)nullptr,
                           (float*)nullptr, (const float*)postab);
      else if (Xnext)
        hipLaunchKernelGGL((k_matmul2<true, true, true, false, true>), dim3(B, 4), dim3(1024), 0, stream,
                           (const float*)X, enc_w[p], (const float*)X, X, pout, P0,
                           (const float*)nullptr, (const float*)nullptr, (const float*)nullptr,
                           (float*)nullptr, (const float*)nullptr, (float*)nullptr,
                           Xnext, (const float*)postab);
      else
        hipLaunchKernelGGL((k_matmul2<true, true, false, false, false>), dim3(B, 4), dim3(1024), 0, stream,
                           (const float*)X, enc_w[p], (const float*)X, X, pout, (float*)nullptr,
                           (const float*)nullptr, (const float*)nullptr, (const float*)nullptr,
                           (float*)nullptr, (const float*)nullptr, (float*)nullptr,
                           (float*)nullptr, (const float*)nullptr);
    }
  };

  k_prep<<<289, 256, 0, stream>>>(postab, e2pw, e1pw, hlw, hgw, e2dw,
                                  pwT, e1pwT, hlwT, hgwT, dwT);
  // ---- embeddings ----
  k_charembed<<<dim3(NN + MQ, B), 256, 0, stream>>>(Ccid, Qcid, char_table, dwT, e2db, pwT, e2pb, E1C, E1Q);
  k_embhw<<<dim3(NN + MQ, B), 64, 0, stream>>>(E1C, E1Q, Cwid, Qwid, word_table, e1dw, e1db,
                                               e1pwT, e1pb, hlwT, hlb, hgwT, hgb, CX, QX);
  // ---- embedding encoders (C and Q merged; cnum=4, K=7) ----
  {
    k_posadd_stats<<<dim3(384, 2), 256, 0, stream>>>(CX, QX, postab, P0, P0Q);
    float *pinC = P0, *poutC = P1, *pinQ = P0Q, *poutQ = P1Q;
    float *XiC = CX, *XoC = U, *XiQ = QX, *XoQ = UQ;
    for (int i = 0; i < 4; ++i) {
      hipLaunchKernelGGL((k_fconv<7>), dim3(B, 5), dim3(1024), 0, stream,
                         (const float*)XiC, XoC, (const float*)XiQ, XoQ,
                         enc_dw[0] + i * 64 * 7, enc_pw[0] + (size_t)i * 4096,
                         enc_dw[1] + i * 64 * 7, enc_pw[1] + (size_t)i * 4096,
                         pinC, poutC, pinQ, poutQ);
      { float* t = pinC; pinC = poutC; poutC = t; }
      { float* t = pinQ; pinQ = poutQ; poutQ = t; }
      { float* t = XiC; XiC = XoC; XoC = t; }
      { float* t = XiQ; XiQ = XoQ; XoQ = t; }
    }
    k_att<<<dim3(HH, 2 * B), 1024, 0, stream>>>(CX, pinC, enc_wq[0], enc_wk[0], enc_wv[0], U,
                                                QX, pinQ, enc_wq[1], enc_wk[1], enc_wv[1], UQ);
    hipLaunchKernelGGL((k_matmul2<false, false, true, false, false>), dim3(B, 5), dim3(1024), 0, stream,
                       (const float*)U, enc_wo[0], (const float*)CX, CX, (const float*)nullptr, poutC,
                       (const float*)UQ, enc_wo[1], (const float*)QX, QX, (const float*)nullptr, poutQ,
                       (float*)nullptr, (const float*)nullptr);
    hipLaunchKernelGGL((k_matmul2<true, true, false, false, false>), dim3(B, 5), dim3(1024), 0, stream,
                       (const float*)CX, enc_w[0], (const float*)CX, CX, poutC, (float*)nullptr,
                       (const float*)QX, enc_w[1], (const float*)QX, QX, poutQ, (float*)nullptr,
                       (float*)nullptr, (const float*)nullptr);
  }
  // ---- context-query attention ----
  k_cqS<<<dim3(B, 4), 256, 0, stream>>>(CX, QX, cq_w, Sb, rmax, rsum);
  k_cqcol<<<B, 64, 0, stream>>>(Sb, cmax, csum);
  k_cqA_CS2<<<dim3(B, 5), 256, 0, stream>>>(CX, QX, Sb, rmax, rsum, cmax, csum, Xcat, CS2);
  k_cqBm<<<dim3(B, 4), 256, 0, stream>>>(CX, CS2, Sb, rmax, rsum, Xcat);
  // ---- resize -> M0 (+tab +stats) ----
  k_resize<<<dim3(B, 4), 256, 0, stream>>>(Xcat, rs_dw, rs_pw, postab, M0, P0);
  // ---- model encoders (stack transitions fused into last FF) ----
  run_enc(M0, M1, 2);
  run_enc(M1, M2, 3);
  run_enc(M2, nullptr, 4);
  // ---- pointers ----
  k_pointer2<<<dim3(B, 2), 256, 0, stream>>>(M0, M1, M2, p_w0, p_w1, out);
}